// Round 6
// baseline (939.883 us; speedup 1.0000x reference)
//
#include <hip/hip_runtime.h>
#include <math.h>

#define NB 8
#define NC 192
#define NT 2048
#define NHALF 96
#define NP 29
#define OUT_ELEMS (NB*NC*NT)
#define TT 64
#define OT 16
#define ICH 48

__device__ __forceinline__ float softplusf(float v) {
    return (v > 20.0f) ? v : log1pf(expf(v));
}
__device__ __forceinline__ float mishf(float v) {
    return v * tanhf(softplusf(v));
}

// K=3 dilated conv + mish + batchnorm.  in is masked at staging time.
template<int DIL>
__global__ __launch_bounds__(256) void conv3_kernel(
    const float* __restrict__ in, const float* __restrict__ masks,
    const float* __restrict__ w, const float* __restrict__ bias,
    const float* __restrict__ g, const float* __restrict__ bb,
    const float* __restrict__ bm, const float* __restrict__ bv,
    float* __restrict__ outp)
{
    constexpr int COLS = TT + 2*DIL;
    __shared__ float sh[ICH][COLS];
    const int tid = threadIdx.x;
    const int tt  = tid & 63;
    const int og  = tid >> 6;
    const int b   = blockIdx.z;
    const int t0  = blockIdx.x * TT;
    const int o0  = blockIdx.y * OT + og * 4;
    const int o0u = __builtin_amdgcn_readfirstlane(o0);
    const int t   = t0 + tt;
    const float* inb = in + (size_t)b * NC * NT;
    const float* mk  = masks + (size_t)b * NT;
    float acc[4] = {0.f,0.f,0.f,0.f};
    for (int kb = 0; kb < NC/ICH; ++kb) {
        for (int idx = tid; idx < ICH*COLS; idx += 256) {
            int r = idx / COLS, col = idx - r*COLS;
            int tg = t0 - DIL + col;
            float v = 0.f;
            if (tg >= 0 && tg < NT) v = inb[(kb*ICH + r)*NT + tg] * mk[tg];
            sh[r][col] = v;
        }
        __syncthreads();
        #pragma unroll 4
        for (int r = 0; r < ICH; ++r) {
            float h0 = sh[r][tt];
            float h1 = sh[r][tt + DIL];
            float h2 = sh[r][tt + 2*DIL];
            const float* wr = w + ((size_t)o0u*NC + kb*ICH + r)*3;
            #pragma unroll
            for (int j = 0; j < 4; ++j) {
                acc[j] = fmaf(wr[j*NC*3 + 0], h0, acc[j]);
                acc[j] = fmaf(wr[j*NC*3 + 1], h1, acc[j]);
                acc[j] = fmaf(wr[j*NC*3 + 2], h2, acc[j]);
            }
        }
        __syncthreads();
    }
    #pragma unroll
    for (int j = 0; j < 4; ++j) {
        int o = o0u + j;
        float v = acc[j] + bias[o];
        v = mishf(v);
        float sc = g[o] * rsqrtf(bv[o] + 1e-5f);
        v = (v - bm[o]) * sc + bb[o];
        outp[((size_t)b*NC + o)*NT + t] = v;
    }
}

// 1x1 conv.  MODE 0: prenet (out = conv + bias + aux(conditions)).
//            MODE 1: conv2 (out += bnorm(mish(conv + bias))) residual into outp.
template<int IN_CH, int MODE>
__global__ __launch_bounds__(256) void conv1x1_kernel(
    const float* __restrict__ in, const float* __restrict__ aux,
    const float* __restrict__ w, const float* __restrict__ bias,
    const float* __restrict__ g, const float* __restrict__ bb,
    const float* __restrict__ bm, const float* __restrict__ bv,
    float* __restrict__ outp)
{
    __shared__ float sh[ICH][TT];
    const int tid = threadIdx.x;
    const int tt  = tid & 63;
    const int og  = tid >> 6;
    const int b   = blockIdx.z;
    const int t0  = blockIdx.x * TT;
    const int o0  = blockIdx.y * OT + og*4;
    const int o0u = __builtin_amdgcn_readfirstlane(o0);
    const int t   = t0 + tt;
    const float* inb = in + (size_t)b * NC * NT;
    float acc[4] = {0.f,0.f,0.f,0.f};
    for (int kb = 0; kb < IN_CH/ICH; ++kb) {
        for (int idx = tid; idx < ICH*TT; idx += 256) {
            int r = idx >> 6, col = idx & 63;
            sh[r][col] = inb[(kb*ICH + r)*NT + t0 + col];
        }
        __syncthreads();
        #pragma unroll 4
        for (int r = 0; r < ICH; ++r) {
            float h = sh[r][tt];
            const float* wr = w + (size_t)o0u*IN_CH + kb*ICH + r;
            #pragma unroll
            for (int j = 0; j < 4; ++j)
                acc[j] = fmaf(wr[(size_t)j*IN_CH], h, acc[j]);
        }
        __syncthreads();
    }
    #pragma unroll
    for (int j = 0; j < 4; ++j) {
        int o = o0u + j;
        float v = acc[j] + bias[o];
        size_t oi = ((size_t)b*NC + o)*NT + t;
        if constexpr (MODE == 0) {
            outp[oi] = v + aux[oi];
        } else {
            v = mishf(v);
            float sc = g[o]*rsqrtf(bv[o]+1e-5f);
            v = (v - bm[o])*sc + bb[o];
            outp[oi] = outp[oi] + v;
        }
    }
}

// copy x0 channels (0..95) to flipped out channels 191-c, *mask
__global__ __launch_bounds__(256) void copy_flip_kernel(
    const float* __restrict__ x, const float* __restrict__ masks,
    float* __restrict__ outp)
{
    int idx = blockIdx.x*256 + threadIdx.x;
    if (idx >= NB*NHALF*NT) return;
    int t = idx & (NT-1);
    int r = idx >> 11;
    int c = r % NHALF;
    int b = r / NHALF;
    float v = x[((size_t)b*NC + c)*NT + t] * masks[(size_t)b*NT + t];
    outp[((size_t)b*NC + (NC-1 - c))*NT + t] = v;
}

// fused proj GEMM (192 -> 29 per (c,t)) + RQ spline + lad block reduction
__global__ __launch_bounds__(256) void proj_spline_kernel(
    const float* __restrict__ hid, const float* __restrict__ x,
    const float* __restrict__ masks,
    const float* __restrict__ pjw, const float* __restrict__ pjb,
    float* __restrict__ outp, float* __restrict__ partial)
{
    __shared__ float sh[ICH][TT];
    __shared__ float red[256];
    const int tid = threadIdx.x;
    const int tt  = tid & 63;
    const int cg  = tid >> 6;
    const int b   = blockIdx.z;
    const int t0  = blockIdx.x * TT;
    const int c   = blockIdx.y * 4 + cg;
    const int cu  = __builtin_amdgcn_readfirstlane(c);
    const int t   = t0 + tt;
    const float* hb = hid + (size_t)b*NC*NT;
    const float* mk = masks + (size_t)b*NT;

    float acc[NP];
    #pragma unroll
    for (int p = 0; p < NP; ++p) acc[p] = 0.f;

    for (int kb = 0; kb < NC/ICH; ++kb) {
        for (int idx = tid; idx < ICH*TT; idx += 256) {
            int r = idx >> 6, col = idx & 63;
            sh[r][col] = hb[(kb*ICH + r)*NT + t0 + col] * mk[t0 + col];
        }
        __syncthreads();
        #pragma unroll 4
        for (int r = 0; r < ICH; ++r) {
            float h = sh[r][tt];
            const float* wc = pjw + ((size_t)cu*NP)*NC + kb*ICH + r;
            #pragma unroll
            for (int p = 0; p < NP; ++p)
                acc[p] = fmaf(wc[(size_t)p*NC], h, acc[p]);
        }
        __syncthreads();
    }

    const float m = mk[t];
    float pr[NP];
    #pragma unroll
    for (int p = 0; p < NP; ++p) pr[p] = (acc[p] + pjb[cu*NP + p]) * m;

    const float invsq = 0.07216878364870322f;  // 1/sqrt(192)
    float cw[11], ww[10], chh[11], hh[10], dd[11];
    {   // width knots
        float u[10];
        #pragma unroll
        for (int i = 0; i < 10; ++i) u[i] = pr[i] * invsq;
        float mx = u[0];
        #pragma unroll
        for (int i = 1; i < 10; ++i) mx = fmaxf(mx, u[i]);
        float e[10], s = 0.f;
        #pragma unroll
        for (int i = 0; i < 10; ++i) { e[i] = expf(u[i]-mx); s += e[i]; }
        float inv_s = 1.f / s;
        float run = 0.f;
        cw[0] = -5.f;
        #pragma unroll
        for (int i = 0; i < 10; ++i) {
            run += 0.001f + 0.99f * e[i] * inv_s;
            cw[i+1] = 10.f*run - 5.f;
        }
        cw[10] = 5.f;
        #pragma unroll
        for (int i = 0; i < 10; ++i) ww[i] = cw[i+1]-cw[i];
    }
    {   // height knots
        float u[10];
        #pragma unroll
        for (int i = 0; i < 10; ++i) u[i] = pr[10+i] * invsq;
        float mx = u[0];
        #pragma unroll
        for (int i = 1; i < 10; ++i) mx = fmaxf(mx, u[i]);
        float e[10], s = 0.f;
        #pragma unroll
        for (int i = 0; i < 10; ++i) { e[i] = expf(u[i]-mx); s += e[i]; }
        float inv_s = 1.f / s;
        float run = 0.f;
        chh[0] = -5.f;
        #pragma unroll
        for (int i = 0; i < 10; ++i) {
            run += 0.001f + 0.99f * e[i] * inv_s;
            chh[i+1] = 10.f*run - 5.f;
        }
        chh[10] = 5.f;
        #pragma unroll
        for (int i = 0; i < 10; ++i) hh[i] = chh[i+1]-chh[i];
    }
    // derivatives: endpoints are exactly 1.0 (md + softplus(log(exp(1-md)-1)) = 1)
    dd[0] = 1.f; dd[10] = 1.f;
    #pragma unroll
    for (int i = 1; i <= 9; ++i) dd[i] = 0.001f + softplusf(pr[19+i]);

    float x1 = x[((size_t)b*NC + NHALF + c)*NT + t];
    float xc = fminf(fmaxf(x1, -5.f), 5.f);
    int cnt = 0;
    #pragma unroll
    for (int i = 0; i < 11; ++i) cnt += (xc >= cw[i]) ? 1 : 0;
    int idx = cnt - 1;
    idx = idx < 0 ? 0 : (idx > 9 ? 9 : idx);

    // static-index select (keep everything in registers)
    float icw=0.f, iw=1.f, ich=0.f, ih=0.f, d0=1.f, d1=1.f;
    #pragma unroll
    for (int i = 0; i < 10; ++i) {
        if (i == idx) {
            icw = cw[i]; iw = ww[i]; ich = chh[i]; ih = hh[i];
            d0 = dd[i]; d1 = dd[i+1];
        }
    }
    float dlt   = ih / iw;
    float theta = (xc - icw) / iw;
    float t1m   = theta * (1.f - theta);
    float den   = dlt + (d0 + d1 - 2.f*dlt) * t1m;
    float num   = ih * (dlt*theta*theta + d0*t1m);
    float outv  = ich + num / den;
    float omt   = 1.f - theta;
    float dnum  = dlt*dlt*(d1*theta*theta + 2.f*dlt*t1m + d0*omt*omt);
    float lad   = logf(dnum) - 2.f*logf(den);
    bool inside = (x1 >= -5.f) && (x1 <= 5.f);
    float xout  = inside ? outv : x1;
    float ladv  = inside ? lad : 0.f;
    outp[((size_t)b*NC + (NHALF-1 - c))*NT + t] = xout * m;

    red[tid] = ladv * m;
    __syncthreads();
    for (int s2 = 128; s2 > 0; s2 >>= 1) {
        if (tid < s2) red[tid] += red[tid + s2];
        __syncthreads();
    }
    if (tid == 0)
        partial[((size_t)b*gridDim.y + blockIdx.y)*gridDim.x + blockIdx.x] = red[0];
}

__global__ __launch_bounds__(256) void logdet_reduce_kernel(
    const float* __restrict__ partial, float* __restrict__ outp)
{
    __shared__ float red[256];
    const int b = blockIdx.x;
    const int tid = threadIdx.x;
    float s = 0.f;
    for (int i = tid; i < 768; i += 256) s += partial[(size_t)b*768 + i];
    red[tid] = s;
    __syncthreads();
    for (int st = 128; st > 0; st >>= 1) {
        if (tid < st) red[tid] += red[tid + st];
        __syncthreads();
    }
    if (tid == 0) outp[(size_t)OUT_ELEMS + b] = red[0];
}

extern "C" void kernel_launch(void* const* d_in, const int* in_sizes, int n_in,
                              void* d_out, int out_size, void* d_ws, size_t ws_size,
                              hipStream_t stream) {
    const float* x     = (const float*)d_in[0];
    const float* cond  = (const float*)d_in[1];
    const float* masks = (const float*)d_in[2];
    const float* pw    = (const float*)d_in[3];
    const float* pb    = (const float*)d_in[4];
    const float* w1    = (const float*)d_in[5];
    const float* b1    = (const float*)d_in[6];
    const float* g1    = (const float*)d_in[7];
    const float* bb1   = (const float*)d_in[8];
    const float* m1    = (const float*)d_in[9];
    const float* v1    = (const float*)d_in[10];
    const float* w2    = (const float*)d_in[11];
    const float* b2    = (const float*)d_in[12];
    const float* g2    = (const float*)d_in[13];
    const float* bb2   = (const float*)d_in[14];
    const float* m2    = (const float*)d_in[15];
    const float* v2    = (const float*)d_in[16];
    const float* pjw   = (const float*)d_in[17];
    const float* pjb   = (const float*)d_in[18];

    float* out = (float*)d_out;
    float* hid = (float*)d_ws;
    float* tmp = hid + (size_t)NB*NC*NT;
    float* partial = tmp + (size_t)NB*NC*NT;

    dim3 blk(256);
    dim3 grid_c(NT/TT, NC/OT, NB);  // 32 x 12 x 8

    // prenet: hid = W(192x96) x0 + b + conditions
    conv1x1_kernel<96,0><<<grid_c, blk, 0, stream>>>(
        x, cond, pw, pb, nullptr, nullptr, nullptr, nullptr, hid);

    for (int l = 0; l < 3; ++l) {
        const float* w1l = w1 + (size_t)l*NC*NC*3;
        const float* w2l = w2 + (size_t)l*NC*NC;
        if (l == 0)
            conv3_kernel<1><<<grid_c, blk, 0, stream>>>(hid, masks, w1l,
                b1+l*NC, g1+l*NC, bb1+l*NC, m1+l*NC, v1+l*NC, tmp);
        else if (l == 1)
            conv3_kernel<3><<<grid_c, blk, 0, stream>>>(hid, masks, w1l,
                b1+l*NC, g1+l*NC, bb1+l*NC, m1+l*NC, v1+l*NC, tmp);
        else
            conv3_kernel<9><<<grid_c, blk, 0, stream>>>(hid, masks, w1l,
                b1+l*NC, g1+l*NC, bb1+l*NC, m1+l*NC, v1+l*NC, tmp);
        conv1x1_kernel<192,1><<<grid_c, blk, 0, stream>>>(
            tmp, nullptr, w2l, b2+l*NC, g2+l*NC, bb2+l*NC, m2+l*NC, v2+l*NC, hid);
    }

    copy_flip_kernel<<<dim3((NB*NHALF*NT + 255)/256), blk, 0, stream>>>(x, masks, out);

    dim3 grid_s(NT/TT, NHALF/4, NB);  // 32 x 24 x 8
    proj_spline_kernel<<<grid_s, blk, 0, stream>>>(hid, x, masks, pjw, pjb, out, partial);

    logdet_reduce_kernel<<<dim3(NB), blk, 0, stream>>>(partial, out);
}

// Round 7
// 467.041 us; speedup vs baseline: 2.0124x; 2.0124x over previous
//
#include <hip/hip_runtime.h>
#include <math.h>

#define NB 8
#define NC 192
#define NT 2048
#define NHALF 96
#define NP 29
#define OUT_ELEMS (NB*NC*NT)
#define KP 100   // padded activation row: 100 dwords = 200 bf16 (192 used)

typedef short bf16x8 __attribute__((ext_vector_type(8)));
typedef float f32x4 __attribute__((ext_vector_type(4)));
typedef unsigned short u16;
typedef unsigned int u32;

__device__ __forceinline__ u16 f2bf(float f) {
    u32 u = __builtin_bit_cast(u32, f);
    u += 0x7fffu + ((u >> 16) & 1u);
    return (u16)(u >> 16);
}
__device__ __forceinline__ float bf2f(u16 h) {
    u32 u = ((u32)h) << 16;
    return __builtin_bit_cast(float, u);
}
__device__ __forceinline__ float softplusf(float v) {
    return (v > 20.0f) ? v : log1pf(expf(v));
}
__device__ __forceinline__ float mishf(float v) {
    return v * tanhf(softplusf(v));
}

// ---------- weight convert: fp32 -> bf16, w1 permuted to [s][j][o][k] ----------
#define W1N 331776   // 3*192*192*3
#define W2N 110592   // 3*192*192
#define PJN 534528   // 2784*192
__global__ __launch_bounds__(256) void wconv_kernel(
    const float* __restrict__ w1, const float* __restrict__ w2,
    const float* __restrict__ pjw, u16* __restrict__ outw)
{
    int i = blockIdx.x*256 + threadIdx.x;
    if (i >= W1N + W2N + PJN) return;
    float v;
    if (i < W1N) {
        int s = i / 110592, r = i % 110592;
        int j = r / 36864, r2 = r % 36864;
        int o = r2 / 192, k = r2 % 192;
        v = w1[(((size_t)s*192 + o)*192 + k)*3 + j];
    } else if (i < W1N + W2N) {
        v = w2[i - W1N];
    } else {
        v = pjw[i - W1N - W2N];
    }
    outw[i] = f2bf(v);
}

// ---------- prenet: fp32 1x1 conv 96->192, writes TRANSPOSED hidT [b][t][192] ----------
__global__ __launch_bounds__(256) void prenet_kernel(
    const float* __restrict__ x, const float* __restrict__ cond,
    const float* __restrict__ w, const float* __restrict__ bias,
    float* __restrict__ hidT)
{
    __shared__ float sh[48][64];
    const int tid = threadIdx.x;
    const int tt = tid & 63, og = tid >> 6;
    const int b = blockIdx.z;
    const int t0 = blockIdx.x * 64;
    const int o0 = blockIdx.y * 16 + og * 4;
    const int o0u = __builtin_amdgcn_readfirstlane(o0);
    const int t = t0 + tt;
    const float* inb = x + (size_t)b * NC * NT;
    float acc[4] = {0.f,0.f,0.f,0.f};
    for (int kb = 0; kb < 2; ++kb) {
        for (int idx = tid; idx < 48*64; idx += 256) {
            int r = idx >> 6, col = idx & 63;
            sh[r][col] = inb[(kb*48 + r)*NT + t0 + col];
        }
        __syncthreads();
        #pragma unroll 4
        for (int r = 0; r < 48; ++r) {
            float h = sh[r][tt];
            const float* wr = w + (size_t)o0u*96 + kb*48 + r;
            #pragma unroll
            for (int j = 0; j < 4; ++j)
                acc[j] = fmaf(wr[(size_t)j*96], h, acc[j]);
        }
        __syncthreads();
    }
    #pragma unroll
    for (int j = 0; j < 4; ++j) {
        int o = o0u + j;
        float v = acc[j] + bias[o] + cond[((size_t)b*NC + o)*NT + t];
        hidT[((size_t)b*NT + t)*NC + o] = v;
    }
}

// ---------- MFMA GEMM: C[m][t] = sum_k W[m][k] * B[k][t] ----------
// EPI 0: conv3 (3 dilated passes), in=hidT fp32 *mask, out=tmpT bf16, mish+BN
// EPI 1: conv1x1, in=tmpT bf16, out=hidT fp32 += mish+BN (residual)
// EPI 2: proj, in=hidT fp32 *mask, out=P bf16 [m][1024] per unit, (acc+pjb)*mask
template<int DIL, int EPI>
__global__ __launch_bounds__(256) void mfma_gemm_kernel(
    const void* __restrict__ inp, const u16* __restrict__ wA,
    const float* __restrict__ masks, const float* __restrict__ bias,
    const float* __restrict__ g, const float* __restrict__ bb,
    const float* __restrict__ bm, const float* __restrict__ bv,
    void* __restrict__ outp, int unit0)
{
    constexpr int ROWS = 64 + 2*DIL;
    __shared__ u32 sm[ROWS * KP];
    const int tid  = threadIdx.x;
    const int lane = tid & 63;
    const int wid  = tid >> 6;
    const int owave = wid & 1, twave = wid >> 1;

    int b, tg0, tloc0;
    if constexpr (EPI == 2) {
        int unit = unit0 + blockIdx.z;
        b = unit >> 1;
        tloc0 = blockIdx.x * 64;
        tg0 = (unit & 1) * 1024 + tloc0;
    } else {
        b = blockIdx.z;
        tg0 = blockIdx.x * 64;
        tloc0 = tg0;
    }

    // ---- stage B tile into LDS as [row][200 bf16] (row = local t) ----
    if constexpr (EPI == 1) {
        const u32* inU = (const u32*)inp;
        for (int idx = tid; idx < 64*96; idx += 256) {
            int row = idx / 96, kp = idx - row*96;
            sm[row*KP + kp] = inU[((size_t)b*NT + tg0 + row)*96 + kp];
        }
    } else {
        const float* inF = (const float*)inp;
        for (int idx = tid; idx < ROWS*96; idx += 256) {
            int row = idx / 96, kp = idx - row*96;
            int t = tg0 + row - DIL;
            float vx = 0.f, vy = 0.f;
            if (t >= 0 && t < NT) {
                const float* p = inF + ((size_t)b*NT + t)*NC + 2*kp;
                float mv = masks[(size_t)b*NT + t];
                vx = p[0]*mv; vy = p[1]*mv;
            }
            sm[row*KP + kp] = (u32)f2bf(vx) | ((u32)f2bf(vy) << 16);
        }
    }
    __syncthreads();

    f32x4 acc[6][2];
    #pragma unroll
    for (int i = 0; i < 6; ++i) {
        acc[i][0] = f32x4{0.f,0.f,0.f,0.f};
        acc[i][1] = f32x4{0.f,0.f,0.f,0.f};
    }

    constexpr int NPASS = (EPI == 0) ? 3 : 1;
    const int l15 = lane & 15;
    const int kg  = lane >> 4;
    const char* smb = (const char*)sm;

    for (int j = 0; j < NPASS; ++j) {
        const u16* wsl = wA + (size_t)j * 36864;
        const int rbase = twave*32 + l15 + j*DIL;
        for (int kk = 0; kk < 6; ++kk) {
            int k0 = kk*32 + kg*8;
            bf16x8 b0 = *(const bf16x8*)(smb + (size_t)rbase*400 + k0*2);
            bf16x8 b1 = *(const bf16x8*)(smb + (size_t)(rbase+16)*400 + k0*2);
            #pragma unroll
            for (int ot = 0; ot < 6; ++ot) {
                int m = blockIdx.y*192 + owave*96 + ot*16 + l15;
                if constexpr (EPI == 2) m = (m < 2783) ? m : 2783;
                bf16x8 a = *(const bf16x8*)(wsl + (size_t)m*192 + k0);
                acc[ot][0] = __builtin_amdgcn_mfma_f32_16x16x32_bf16(a, b0, acc[ot][0], 0, 0, 0);
                acc[ot][1] = __builtin_amdgcn_mfma_f32_16x16x32_bf16(a, b1, acc[ot][1], 0, 0, 0);
            }
        }
    }

    // ---- epilogue ----
    #pragma unroll
    for (int ot = 0; ot < 6; ++ot) {
        #pragma unroll
        for (int t2 = 0; t2 < 2; ++t2) {
            int tl = twave*32 + t2*16 + l15;
            int o4 = owave*96 + ot*16 + ((lane >> 4) << 2);
            f32x4 A = acc[ot][t2];
            if constexpr (EPI == 2) {
                int m4 = blockIdx.y*192 + o4;
                if (m4 < 2784) {
                    int tgl = tg0 + tl;
                    float mkv = masks[(size_t)b*NT + tgl];
                    f32x4 pb = *(const f32x4*)(bias + m4);
                    u16* P = (u16*)outp + (size_t)blockIdx.z * 2784 * 1024;
                    int tc = tloc0 + tl;
                    #pragma unroll
                    for (int r = 0; r < 4; ++r)
                        P[(size_t)(m4 + r)*1024 + tc] = f2bf((A[r] + pb[r]) * mkv);
                }
            } else {
                int t = tg0 + tl;
                f32x4 bi = *(const f32x4*)(bias + o4);
                f32x4 g4 = *(const f32x4*)(g + o4);
                f32x4 bb4 = *(const f32x4*)(bb + o4);
                f32x4 bm4 = *(const f32x4*)(bm + o4);
                f32x4 bv4 = *(const f32x4*)(bv + o4);
                float vr[4];
                #pragma unroll
                for (int r = 0; r < 4; ++r) {
                    float v = mishf(A[r] + bi[r]);
                    vr[r] = (v - bm4[r]) * (g4[r] * rsqrtf(bv4[r] + 1e-5f)) + bb4[r];
                }
                if constexpr (EPI == 0) {
                    u32 lo = (u32)f2bf(vr[0]) | ((u32)f2bf(vr[1]) << 16);
                    u32 hi = (u32)f2bf(vr[2]) | ((u32)f2bf(vr[3]) << 16);
                    u32* dst = (u32*)((u16*)outp + ((size_t)b*NT + t)*NC + o4);
                    dst[0] = lo; dst[1] = hi;
                } else {
                    float* dst = (float*)outp + ((size_t)b*NT + t)*NC + o4;
                    f32x4 old = *(const f32x4*)dst;
                    f32x4 nv;
                    #pragma unroll
                    for (int r = 0; r < 4; ++r) nv[r] = old[r] + vr[r];
                    *(f32x4*)dst = nv;
                }
            }
        }
    }
}

// ---------- copy x0 channels to flipped out channels, *mask ----------
__global__ __launch_bounds__(256) void copy_flip_kernel(
    const float* __restrict__ x, const float* __restrict__ masks,
    float* __restrict__ outp)
{
    int idx = blockIdx.x*256 + threadIdx.x;
    if (idx >= NB*NHALF*NT) return;
    int t = idx & (NT-1);
    int r = idx >> 11;
    int c = r % NHALF;
    int b = r / NHALF;
    float v = x[((size_t)b*NC + c)*NT + t] * masks[(size_t)b*NT + t];
    outp[((size_t)b*NC + (NC-1 - c))*NT + t] = v;
}

// ---------- RQ spline from P (bf16 [m][1024] per unit) + lad reduction ----------
__global__ __launch_bounds__(256) void spline_kernel(
    const u16* __restrict__ Pbase, const float* __restrict__ x,
    const float* __restrict__ masks, float* __restrict__ outp,
    float* __restrict__ partial, int unit0)
{
    __shared__ float red[256];
    const int tid = threadIdx.x;
    const int tt = tid & 63, cg = tid >> 6;
    const int unit = unit0 + blockIdx.z;
    const int b = unit >> 1, th = unit & 1;
    const int tloc = blockIdx.x*64 + tt;
    const int tg = th*1024 + tloc;
    const int c = blockIdx.y*4 + cg;
    const u16* P = Pbase + (size_t)blockIdx.z * 2784 * 1024;
    const float m = masks[(size_t)b*NT + tg];

    float pr[NP];
    #pragma unroll
    for (int p = 0; p < NP; ++p)
        pr[p] = bf2f(P[(size_t)(c*NP + p)*1024 + tloc]);

    const float invsq = 0.07216878364870322f;  // 1/sqrt(192)
    float cw[11], ww[10], chh[11], hh[10], dd[11];
    {   // width knots
        float u[10];
        #pragma unroll
        for (int i = 0; i < 10; ++i) u[i] = pr[i] * invsq;
        float mx = u[0];
        #pragma unroll
        for (int i = 1; i < 10; ++i) mx = fmaxf(mx, u[i]);
        float e[10], s = 0.f;
        #pragma unroll
        for (int i = 0; i < 10; ++i) { e[i] = expf(u[i]-mx); s += e[i]; }
        float inv_s = 1.f / s;
        float run = 0.f;
        cw[0] = -5.f;
        #pragma unroll
        for (int i = 0; i < 10; ++i) {
            run += 0.001f + 0.99f * e[i] * inv_s;
            cw[i+1] = 10.f*run - 5.f;
        }
        cw[10] = 5.f;
        #pragma unroll
        for (int i = 0; i < 10; ++i) ww[i] = cw[i+1]-cw[i];
    }
    {   // height knots
        float u[10];
        #pragma unroll
        for (int i = 0; i < 10; ++i) u[i] = pr[10+i] * invsq;
        float mx = u[0];
        #pragma unroll
        for (int i = 1; i < 10; ++i) mx = fmaxf(mx, u[i]);
        float e[10], s = 0.f;
        #pragma unroll
        for (int i = 0; i < 10; ++i) { e[i] = expf(u[i]-mx); s += e[i]; }
        float inv_s = 1.f / s;
        float run = 0.f;
        chh[0] = -5.f;
        #pragma unroll
        for (int i = 0; i < 10; ++i) {
            run += 0.001f + 0.99f * e[i] * inv_s;
            chh[i+1] = 10.f*run - 5.f;
        }
        chh[10] = 5.f;
        #pragma unroll
        for (int i = 0; i < 10; ++i) hh[i] = chh[i+1]-chh[i];
    }
    dd[0] = 1.f; dd[10] = 1.f;
    #pragma unroll
    for (int i = 1; i <= 9; ++i) dd[i] = 0.001f + softplusf(pr[19+i]);

    float x1 = x[((size_t)b*NC + NHALF + c)*NT + tg];
    float xc = fminf(fmaxf(x1, -5.f), 5.f);
    int cnt = 0;
    #pragma unroll
    for (int i = 0; i < 11; ++i) cnt += (xc >= cw[i]) ? 1 : 0;
    int idx = cnt - 1;
    idx = idx < 0 ? 0 : (idx > 9 ? 9 : idx);

    float icw=0.f, iw=1.f, ich=0.f, ih=0.f, d0=1.f, d1=1.f;
    #pragma unroll
    for (int i = 0; i < 10; ++i) {
        if (i == idx) {
            icw = cw[i]; iw = ww[i]; ich = chh[i]; ih = hh[i];
            d0 = dd[i]; d1 = dd[i+1];
        }
    }
    float dlt   = ih / iw;
    float theta = (xc - icw) / iw;
    float t1m   = theta * (1.f - theta);
    float den   = dlt + (d0 + d1 - 2.f*dlt) * t1m;
    float num   = ih * (dlt*theta*theta + d0*t1m);
    float outv  = ich + num / den;
    float omt   = 1.f - theta;
    float dnum  = dlt*dlt*(d1*theta*theta + 2.f*dlt*t1m + d0*omt*omt);
    float lad   = logf(dnum) - 2.f*logf(den);
    bool inside = (x1 >= -5.f) && (x1 <= 5.f);
    float xout  = inside ? outv : x1;
    float ladv  = inside ? lad : 0.f;
    outp[((size_t)b*NC + (NHALF-1 - c))*NT + tg] = xout * m;

    red[tid] = ladv * m;
    __syncthreads();
    for (int s2 = 128; s2 > 0; s2 >>= 1) {
        if (tid < s2) red[tid] += red[tid + s2];
        __syncthreads();
    }
    if (tid == 0)
        partial[((size_t)b*24 + blockIdx.y)*32 + (th*16 + blockIdx.x)] = red[0];
}

__global__ __launch_bounds__(256) void logdet_reduce_kernel(
    const float* __restrict__ partial, float* __restrict__ outp)
{
    __shared__ float red[256];
    const int b = blockIdx.x;
    const int tid = threadIdx.x;
    float s = 0.f;
    for (int i = tid; i < 768; i += 256) s += partial[(size_t)b*768 + i];
    red[tid] = s;
    __syncthreads();
    for (int st = 128; st > 0; st >>= 1) {
        if (tid < st) red[tid] += red[tid + st];
        __syncthreads();
    }
    if (tid == 0) outp[(size_t)OUT_ELEMS + b] = red[0];
}

extern "C" void kernel_launch(void* const* d_in, const int* in_sizes, int n_in,
                              void* d_out, int out_size, void* d_ws, size_t ws_size,
                              hipStream_t stream) {
    const float* x     = (const float*)d_in[0];
    const float* cond  = (const float*)d_in[1];
    const float* masks = (const float*)d_in[2];
    const float* pw    = (const float*)d_in[3];
    const float* pb    = (const float*)d_in[4];
    const float* w1    = (const float*)d_in[5];
    const float* b1    = (const float*)d_in[6];
    const float* g1    = (const float*)d_in[7];
    const float* bb1   = (const float*)d_in[8];
    const float* m1    = (const float*)d_in[9];
    const float* v1    = (const float*)d_in[10];
    const float* w2    = (const float*)d_in[11];
    const float* b2    = (const float*)d_in[12];
    const float* g2    = (const float*)d_in[13];
    const float* bb2   = (const float*)d_in[14];
    const float* m2    = (const float*)d_in[15];
    const float* v2    = (const float*)d_in[16];
    const float* pjw   = (const float*)d_in[17];
    const float* pjb   = (const float*)d_in[18];

    float* out = (float*)d_out;
    char* wsb = (char*)d_ws;
    // ws layout: [hidT fp32 12.58MB][wbf bf16 1.95MB][partial 24KB][big: tmpT bf16 / P units]
    float* hidT   = (float*)wsb;
    u16*  wbf     = (u16*)(wsb + 12582912);
    float* partial = (float*)(wsb + 14536704);
    char* big     = wsb + 14561280;

    dim3 blk(256);

    wconv_kernel<<<dim3((W1N+W2N+PJN+255)/256), blk, 0, stream>>>(w1, w2, pjw, wbf);
    prenet_kernel<<<dim3(32,12,8), blk, 0, stream>>>(x, cond, pw, pb, hidT);

    for (int l = 0; l < 3; ++l) {
        const u16* w1l = wbf + (size_t)l*110592;           // [j][o][k] slabs
        const u16* w2l = wbf + W1N + (size_t)l*36864;      // [o][k]
        if (l == 0)
            mfma_gemm_kernel<1,0><<<dim3(32,1,8), blk, 0, stream>>>(
                hidT, w1l, masks, b1+l*NC, g1+l*NC, bb1+l*NC, m1+l*NC, v1+l*NC, big, 0);
        else if (l == 1)
            mfma_gemm_kernel<3,0><<<dim3(32,1,8), blk, 0, stream>>>(
                hidT, w1l, masks, b1+l*NC, g1+l*NC, bb1+l*NC, m1+l*NC, v1+l*NC, big, 0);
        else
            mfma_gemm_kernel<9,0><<<dim3(32,1,8), blk, 0, stream>>>(
                hidT, w1l, masks, b1+l*NC, g1+l*NC, bb1+l*NC, m1+l*NC, v1+l*NC, big, 0);
        mfma_gemm_kernel<0,1><<<dim3(32,1,8), blk, 0, stream>>>(
            big, w2l, masks, b2+l*NC, g2+l*NC, bb2+l*NC, m2+l*NC, v2+l*NC, hidT, 0);
    }

    copy_flip_kernel<<<dim3((NB*NHALF*NT + 255)/256), blk, 0, stream>>>(x, masks, out);

    const u16* pjwbf = wbf + W1N + W2N;
    size_t UNIT = (size_t)2784*1024*2;   // 5,701,632 B per (b, t-half) unit
    size_t availB = (ws_size > 14561280) ? (ws_size - 14561280) : 0;
    int cap = (int)(availB / UNIT);
    if (cap < 1) cap = 1;
    if (cap > 16) cap = 16;
    for (int u0 = 0; u0 < 16; u0 += cap) {
        int n = (16 - u0 < cap) ? (16 - u0) : cap;
        mfma_gemm_kernel<0,2><<<dim3(16,15,n), blk, 0, stream>>>(
            hidT, pjwbf, masks, pjb, nullptr, nullptr, nullptr, nullptr, big, u0);
        spline_kernel<<<dim3(16,24,n), blk, 0, stream>>>(
            (const u16*)big, x, masks, out, partial, u0);
    }

    logdet_reduce_kernel<<<dim3(8), blk, 0, stream>>>(partial, out);
}

// Round 8
// 425.617 us; speedup vs baseline: 2.2083x; 1.0973x over previous
//
#include <hip/hip_runtime.h>
#include <math.h>

#define NB 8
#define NC 192
#define NT 2048
#define NHALF 96
#define NP 29
#define OUT_ELEMS (NB*NC*NT)
#define KP 100   // padded activation row: 100 dwords = 200 bf16 (192 used)

typedef short bf16x8 __attribute__((ext_vector_type(8)));
typedef float f32x4 __attribute__((ext_vector_type(4)));
typedef unsigned short u16;
typedef unsigned int u32;

__device__ __forceinline__ u16 f2bf(float f) {
    u32 u = __builtin_bit_cast(u32, f);
    u += 0x7fffu + ((u >> 16) & 1u);
    return (u16)(u >> 16);
}
__device__ __forceinline__ float softplusf(float v) {
    return (v > 20.0f) ? v : log1pf(expf(v));
}
__device__ __forceinline__ float mishf(float v) {
    return v * tanhf(softplusf(v));
}

// ---------- weight convert ----------
// wbf layout: [w1 permuted [s][j][o][k] : W1N][w2 [s][o][k] : W2N][pjw padded [96c][32p][192k] : PADN]
// pjb_pad: fp32[3072], rows p>=29 zero.
#define W1N 331776   // 3*192*192*3
#define W2N 110592   // 3*192*192
#define PADN 589824  // 3072*192
#define WTOT (W1N+W2N+PADN)
__global__ __launch_bounds__(256) void wconv_kernel(
    const float* __restrict__ w1, const float* __restrict__ w2,
    const float* __restrict__ pjw, const float* __restrict__ pjb,
    u16* __restrict__ outw, float* __restrict__ pjb_pad)
{
    int i = blockIdx.x*256 + threadIdx.x;
    if (i < WTOT) {
        float v;
        if (i < W1N) {
            int s = i / 110592, r = i % 110592;
            int j = r / 36864, r2 = r % 36864;
            int o = r2 / 192, k = r2 % 192;
            v = w1[(((size_t)s*192 + o)*192 + k)*3 + j];
        } else if (i < W1N + W2N) {
            v = w2[i - W1N];
        } else {
            int r = i - W1N - W2N;
            int mp = r / 192, k = r % 192;
            int c = mp >> 5, p = mp & 31;
            v = (p < NP) ? pjw[((size_t)(c*NP + p))*192 + k] : 0.f;
        }
        outw[i] = f2bf(v);
    } else if (i < WTOT + 3072) {
        int mp = i - WTOT;
        int c = mp >> 5, p = mp & 31;
        pjb_pad[mp] = (p < NP) ? pjb[c*NP + p] : 0.f;
    }
}

// ---------- prenet: fp32 1x1 conv 96->192, writes TRANSPOSED hidT [b][t][192] ----------
__global__ __launch_bounds__(256) void prenet_kernel(
    const float* __restrict__ x, const float* __restrict__ cond,
    const float* __restrict__ w, const float* __restrict__ bias,
    float* __restrict__ hidT)
{
    __shared__ float sh[48][64];
    const int tid = threadIdx.x;
    const int tt = tid & 63, og = tid >> 6;
    const int b = blockIdx.z;
    const int t0 = blockIdx.x * 64;
    const int o0 = blockIdx.y * 16 + og * 4;
    const int o0u = __builtin_amdgcn_readfirstlane(o0);
    const int t = t0 + tt;
    const float* inb = x + (size_t)b * NC * NT;
    float acc[4] = {0.f,0.f,0.f,0.f};
    for (int kb = 0; kb < 2; ++kb) {
        for (int idx = tid; idx < 48*64; idx += 256) {
            int r = idx >> 6, col = idx & 63;
            sh[r][col] = inb[(kb*48 + r)*NT + t0 + col];
        }
        __syncthreads();
        #pragma unroll 4
        for (int r = 0; r < 48; ++r) {
            float h = sh[r][tt];
            const float* wr = w + (size_t)o0u*96 + kb*48 + r;
            #pragma unroll
            for (int j = 0; j < 4; ++j)
                acc[j] = fmaf(wr[(size_t)j*96], h, acc[j]);
        }
        __syncthreads();
    }
    #pragma unroll
    for (int j = 0; j < 4; ++j) {
        int o = o0u + j;
        float v = acc[j] + bias[o] + cond[((size_t)b*NC + o)*NT + t];
        hidT[((size_t)b*NT + t)*NC + o] = v;
    }
}

// ---------- MFMA GEMM for residual blocks ----------
// EPI 0: conv3 (3 dilated passes), in=hidT fp32 *mask, out=tmpT bf16, mish+BN
// EPI 1: conv1x1, in=tmpT bf16, out=hidT fp32 += mish+BN (residual)
template<int DIL, int EPI>
__global__ __launch_bounds__(256) void mfma_gemm_kernel(
    const void* __restrict__ inp, const u16* __restrict__ wA,
    const float* __restrict__ masks, const float* __restrict__ bias,
    const float* __restrict__ g, const float* __restrict__ bb,
    const float* __restrict__ bm, const float* __restrict__ bv,
    void* __restrict__ outp)
{
    constexpr int ROWS = 64 + 2*DIL;
    __shared__ u32 sm[ROWS * KP];
    const int tid  = threadIdx.x;
    const int lane = tid & 63;
    const int wid  = tid >> 6;
    const int owave = wid & 1, twave = wid >> 1;
    const int b = blockIdx.z;
    const int tg0 = blockIdx.x * 64;

    if constexpr (EPI == 1) {
        const u32* inU = (const u32*)inp;
        for (int idx = tid; idx < 64*96; idx += 256) {
            int row = idx / 96, kp = idx - row*96;
            sm[row*KP + kp] = inU[((size_t)b*NT + tg0 + row)*96 + kp];
        }
    } else {
        const float* inF = (const float*)inp;
        for (int idx = tid; idx < ROWS*96; idx += 256) {
            int row = idx / 96, kp = idx - row*96;
            int t = tg0 + row - DIL;
            float vx = 0.f, vy = 0.f;
            if (t >= 0 && t < NT) {
                const float* p = inF + ((size_t)b*NT + t)*NC + 2*kp;
                float mv = masks[(size_t)b*NT + t];
                vx = p[0]*mv; vy = p[1]*mv;
            }
            sm[row*KP + kp] = (u32)f2bf(vx) | ((u32)f2bf(vy) << 16);
        }
    }
    __syncthreads();

    f32x4 acc[6][2];
    #pragma unroll
    for (int i = 0; i < 6; ++i) {
        acc[i][0] = f32x4{0.f,0.f,0.f,0.f};
        acc[i][1] = f32x4{0.f,0.f,0.f,0.f};
    }

    constexpr int NPASS = (EPI == 0) ? 3 : 1;
    const int l15 = lane & 15;
    const int kg  = lane >> 4;
    const char* smb = (const char*)sm;

    for (int j = 0; j < NPASS; ++j) {
        const u16* wsl = wA + (size_t)j * 36864;
        const int rbase = twave*32 + l15 + j*DIL;
        for (int kk = 0; kk < 6; ++kk) {
            int k0 = kk*32 + kg*8;
            bf16x8 b0 = *(const bf16x8*)(smb + (size_t)rbase*400 + k0*2);
            bf16x8 b1 = *(const bf16x8*)(smb + (size_t)(rbase+16)*400 + k0*2);
            bf16x8 af[6];
            #pragma unroll
            for (int ot = 0; ot < 6; ++ot) {
                int m = owave*96 + ot*16 + l15;
                af[ot] = *(const bf16x8*)(wsl + (size_t)m*192 + k0);
            }
            #pragma unroll
            for (int ot = 0; ot < 6; ++ot) {
                acc[ot][0] = __builtin_amdgcn_mfma_f32_16x16x32_bf16(af[ot], b0, acc[ot][0], 0, 0, 0);
                acc[ot][1] = __builtin_amdgcn_mfma_f32_16x16x32_bf16(af[ot], b1, acc[ot][1], 0, 0, 0);
            }
        }
    }

    #pragma unroll
    for (int ot = 0; ot < 6; ++ot) {
        #pragma unroll
        for (int t2 = 0; t2 < 2; ++t2) {
            int tl = twave*32 + t2*16 + l15;
            int o4 = owave*96 + ot*16 + (kg << 2);
            f32x4 A = acc[ot][t2];
            int t = tg0 + tl;
            f32x4 bi = *(const f32x4*)(bias + o4);
            f32x4 g4 = *(const f32x4*)(g + o4);
            f32x4 bb4 = *(const f32x4*)(bb + o4);
            f32x4 bm4 = *(const f32x4*)(bm + o4);
            f32x4 bv4 = *(const f32x4*)(bv + o4);
            float vr[4];
            #pragma unroll
            for (int r = 0; r < 4; ++r) {
                float v = mishf(A[r] + bi[r]);
                vr[r] = (v - bm4[r]) * (g4[r] * rsqrtf(bv4[r] + 1e-5f)) + bb4[r];
            }
            if constexpr (EPI == 0) {
                u32 lo = (u32)f2bf(vr[0]) | ((u32)f2bf(vr[1]) << 16);
                u32 hi = (u32)f2bf(vr[2]) | ((u32)f2bf(vr[3]) << 16);
                u32* dst = (u32*)((u16*)outp + ((size_t)b*NT + t)*NC + o4);
                dst[0] = lo; dst[1] = hi;
            } else {
                float* dst = (float*)outp + ((size_t)b*NT + t)*NC + o4;
                f32x4 old = *(const f32x4*)dst;
                f32x4 nv;
                #pragma unroll
                for (int r = 0; r < 4; ++r) nv[r] = old[r] + vr[r];
                *(f32x4*)dst = nv;
            }
        }
    }
}

// ---------- copy x0 channels to flipped out channels, *mask ----------
__global__ __launch_bounds__(256) void copy_flip_kernel(
    const float* __restrict__ x, const float* __restrict__ masks,
    float* __restrict__ outp)
{
    int idx = blockIdx.x*256 + threadIdx.x;
    if (idx >= NB*NHALF*NT) return;
    int t = idx & (NT-1);
    int r = idx >> 11;
    int c = r % NHALF;
    int b = r / NHALF;
    float v = x[((size_t)b*NC + c)*NT + t] * masks[(size_t)b*NT + t];
    outp[((size_t)b*NC + (NC-1 - c))*NT + t] = v;
}

// ---------- fused proj GEMM (padded 3072x192) + RQ spline + lad reduction ----------
// grid (16 t-tiles, 16 m-blocks(=6c each), 16 units(b,th)), block 256
__global__ __launch_bounds__(256) void proj_spline_mfma_kernel(
    const float* __restrict__ hidT, const u16* __restrict__ wpad,
    const float* __restrict__ pjb_pad, const float* __restrict__ x,
    const float* __restrict__ masks, float* __restrict__ outp,
    float* __restrict__ partial)
{
    __shared__ float uls[192*65];   // union: staging (first 6400 u32) then P [192][65]
    __shared__ float red[256];
    u32* sm = (u32*)uls;
    const int tid  = threadIdx.x;
    const int lane = tid & 63;
    const int wid  = tid >> 6;
    const int owave = wid & 1, twave = wid >> 1;
    const int z  = blockIdx.z;
    const int b  = z >> 1, th = z & 1;
    const int tg0 = th*1024 + blockIdx.x*64;

    // stage B tile: 64 t-rows x 192 k, masked, bf16-pairs
    for (int idx = tid; idx < 64*96; idx += 256) {
        int row = idx / 96, kp = idx - row*96;
        int t = tg0 + row;
        const float* p = hidT + ((size_t)b*NT + t)*NC + 2*kp;
        float mv = masks[(size_t)b*NT + t];
        sm[row*KP + kp] = (u32)f2bf(p[0]*mv) | ((u32)f2bf(p[1]*mv) << 16);
    }
    __syncthreads();

    f32x4 acc[6][2];
    #pragma unroll
    for (int i = 0; i < 6; ++i) {
        acc[i][0] = f32x4{0.f,0.f,0.f,0.f};
        acc[i][1] = f32x4{0.f,0.f,0.f,0.f};
    }
    const int l15 = lane & 15;
    const int kg  = lane >> 4;
    const char* smb = (const char*)sm;
    const int mbase = blockIdx.y*192 + owave*96;

    for (int kk = 0; kk < 6; ++kk) {
        int k0 = kk*32 + kg*8;
        bf16x8 b0 = *(const bf16x8*)(smb + (size_t)(twave*32 + l15)*400 + k0*2);
        bf16x8 b1 = *(const bf16x8*)(smb + (size_t)(twave*32 + l15 + 16)*400 + k0*2);
        bf16x8 af[6];
        #pragma unroll
        for (int ot = 0; ot < 6; ++ot)
            af[ot] = *(const bf16x8*)(wpad + (size_t)(mbase + ot*16 + l15)*192 + k0);
        #pragma unroll
        for (int ot = 0; ot < 6; ++ot) {
            acc[ot][0] = __builtin_amdgcn_mfma_f32_16x16x32_bf16(af[ot], b0, acc[ot][0], 0, 0, 0);
            acc[ot][1] = __builtin_amdgcn_mfma_f32_16x16x32_bf16(af[ot], b1, acc[ot][1], 0, 0, 0);
        }
    }
    __syncthreads();   // staging dead; reuse LDS as P

    // P[m_local][t_local] = (acc + pjb_pad) * mask, fp32, stride 65
    #pragma unroll
    for (int ot = 0; ot < 6; ++ot) {
        int o4 = owave*96 + ot*16 + (kg << 2);
        f32x4 pb = *(const f32x4*)(pjb_pad + blockIdx.y*192 + o4);
        #pragma unroll
        for (int t2 = 0; t2 < 2; ++t2) {
            int tl = twave*32 + t2*16 + l15;
            float mkv = masks[(size_t)b*NT + tg0 + tl];
            f32x4 A = acc[ot][t2];
            #pragma unroll
            for (int r = 0; r < 4; ++r)
                uls[(o4 + r)*65 + tl] = (A[r] + pb[r]) * mkv;
        }
    }
    __syncthreads();

    // spline: 6 c-channels x 64 t per block
    float lsum = 0.f;
    for (int idx = tid; idx < 384; idx += 256) {
        int cl = idx >> 6, t = idx & 63;
        int c  = blockIdx.y*6 + cl;
        int tg = tg0 + t;
        float m = masks[(size_t)b*NT + tg];

        float pr[NP];
        #pragma unroll
        for (int p = 0; p < NP; ++p)
            pr[p] = uls[(cl*32 + p)*65 + t];

        const float invsq = 0.07216878364870322f;  // 1/sqrt(192)
        float cw[11], ww[10], chh[11], hh[10], dd[11];
        {   // width knots
            float u[10];
            #pragma unroll
            for (int i = 0; i < 10; ++i) u[i] = pr[i] * invsq;
            float mx = u[0];
            #pragma unroll
            for (int i = 1; i < 10; ++i) mx = fmaxf(mx, u[i]);
            float e[10], s = 0.f;
            #pragma unroll
            for (int i = 0; i < 10; ++i) { e[i] = expf(u[i]-mx); s += e[i]; }
            float inv_s = 1.f / s;
            float run = 0.f;
            cw[0] = -5.f;
            #pragma unroll
            for (int i = 0; i < 10; ++i) {
                run += 0.001f + 0.99f * e[i] * inv_s;
                cw[i+1] = 10.f*run - 5.f;
            }
            cw[10] = 5.f;
            #pragma unroll
            for (int i = 0; i < 10; ++i) ww[i] = cw[i+1]-cw[i];
        }
        {   // height knots
            float u[10];
            #pragma unroll
            for (int i = 0; i < 10; ++i) u[i] = pr[10+i] * invsq;
            float mx = u[0];
            #pragma unroll
            for (int i = 1; i < 10; ++i) mx = fmaxf(mx, u[i]);
            float e[10], s = 0.f;
            #pragma unroll
            for (int i = 0; i < 10; ++i) { e[i] = expf(u[i]-mx); s += e[i]; }
            float inv_s = 1.f / s;
            float run = 0.f;
            chh[0] = -5.f;
            #pragma unroll
            for (int i = 0; i < 10; ++i) {
                run += 0.001f + 0.99f * e[i] * inv_s;
                chh[i+1] = 10.f*run - 5.f;
            }
            chh[10] = 5.f;
            #pragma unroll
            for (int i = 0; i < 10; ++i) hh[i] = chh[i+1]-chh[i];
        }
        dd[0] = 1.f; dd[10] = 1.f;
        #pragma unroll
        for (int i = 1; i <= 9; ++i) dd[i] = 0.001f + softplusf(pr[19+i]);

        float x1 = x[((size_t)b*NC + NHALF + c)*NT + tg];
        float xc = fminf(fmaxf(x1, -5.f), 5.f);
        int cnt = 0;
        #pragma unroll
        for (int i = 0; i < 11; ++i) cnt += (xc >= cw[i]) ? 1 : 0;
        int kidx = cnt - 1;
        kidx = kidx < 0 ? 0 : (kidx > 9 ? 9 : kidx);

        float icw=0.f, iw=1.f, ich=0.f, ih=0.f, d0=1.f, d1=1.f;
        #pragma unroll
        for (int i = 0; i < 10; ++i) {
            if (i == kidx) {
                icw = cw[i]; iw = ww[i]; ich = chh[i]; ih = hh[i];
                d0 = dd[i]; d1 = dd[i+1];
            }
        }
        float dlt   = ih / iw;
        float theta = (xc - icw) / iw;
        float t1m   = theta * (1.f - theta);
        float den   = dlt + (d0 + d1 - 2.f*dlt) * t1m;
        float num   = ih * (dlt*theta*theta + d0*t1m);
        float outv  = ich + num / den;
        float omt   = 1.f - theta;
        float dnum  = dlt*dlt*(d1*theta*theta + 2.f*dlt*t1m + d0*omt*omt);
        float lad   = logf(dnum) - 2.f*logf(den);
        bool inside = (x1 >= -5.f) && (x1 <= 5.f);
        float xout  = inside ? outv : x1;
        float ladv  = inside ? lad : 0.f;
        outp[((size_t)b*NC + (NHALF-1 - c))*NT + tg] = xout * m;
        lsum += ladv * m;
    }

    red[tid] = lsum;
    __syncthreads();
    for (int s2 = 128; s2 > 0; s2 >>= 1) {
        if (tid < s2) red[tid] += red[tid + s2];
        __syncthreads();
    }
    if (tid == 0)
        partial[(size_t)b*512 + th*256 + blockIdx.y*16 + blockIdx.x] = red[0];
}

__global__ __launch_bounds__(256) void logdet_reduce_kernel(
    const float* __restrict__ partial, float* __restrict__ outp)
{
    __shared__ float red[256];
    const int b = blockIdx.x;
    const int tid = threadIdx.x;
    float s = 0.f;
    for (int i = tid; i < 512; i += 256) s += partial[(size_t)b*512 + i];
    red[tid] = s;
    __syncthreads();
    for (int st = 128; st > 0; st >>= 1) {
        if (tid < st) red[tid] += red[tid + st];
        __syncthreads();
    }
    if (tid == 0) outp[(size_t)OUT_ELEMS + b] = red[0];
}

extern "C" void kernel_launch(void* const* d_in, const int* in_sizes, int n_in,
                              void* d_out, int out_size, void* d_ws, size_t ws_size,
                              hipStream_t stream) {
    const float* x     = (const float*)d_in[0];
    const float* cond  = (const float*)d_in[1];
    const float* masks = (const float*)d_in[2];
    const float* pw    = (const float*)d_in[3];
    const float* pb    = (const float*)d_in[4];
    const float* w1    = (const float*)d_in[5];
    const float* b1    = (const float*)d_in[6];
    const float* g1    = (const float*)d_in[7];
    const float* bb1   = (const float*)d_in[8];
    const float* m1    = (const float*)d_in[9];
    const float* v1    = (const float*)d_in[10];
    const float* w2    = (const float*)d_in[11];
    const float* b2    = (const float*)d_in[12];
    const float* g2    = (const float*)d_in[13];
    const float* bb2   = (const float*)d_in[14];
    const float* m2    = (const float*)d_in[15];
    const float* v2    = (const float*)d_in[16];
    const float* pjw   = (const float*)d_in[17];
    const float* pjb   = (const float*)d_in[18];

    float* out = (float*)d_out;
    char* wsb = (char*)d_ws;
    // ws: [hidT fp32 12.58MB][wbf bf16 2.06MB][pjb_pad 12KB][partial 16KB][tmpT bf16 6.29MB]
    float* hidT    = (float*)wsb;
    u16*   wbf     = (u16*)(wsb + 12582912);
    float* pjb_pad = (float*)(wsb + 12582912 + 2064384);
    float* partial = (float*)(wsb + 12582912 + 2064384 + 12288);
    char*  tmpT    = wsb + 12582912 + 2064384 + 12288 + 16384;

    dim3 blk(256);

    wconv_kernel<<<dim3((WTOT + 3072 + 255)/256), blk, 0, stream>>>(w1, w2, pjw, pjb, wbf, pjb_pad);
    prenet_kernel<<<dim3(32,12,8), blk, 0, stream>>>(x, cond, pw, pb, hidT);

    for (int l = 0; l < 3; ++l) {
        const u16* w1l = wbf + (size_t)l*110592;           // [j][o][k] slabs
        const u16* w2l = wbf + W1N + (size_t)l*36864;      // [o][k]
        if (l == 0)
            mfma_gemm_kernel<1,0><<<dim3(32,1,8), blk, 0, stream>>>(
                hidT, w1l, masks, b1+l*NC, g1+l*NC, bb1+l*NC, m1+l*NC, v1+l*NC, tmpT);
        else if (l == 1)
            mfma_gemm_kernel<3,0><<<dim3(32,1,8), blk, 0, stream>>>(
                hidT, w1l, masks, b1+l*NC, g1+l*NC, bb1+l*NC, m1+l*NC, v1+l*NC, tmpT);
        else
            mfma_gemm_kernel<9,0><<<dim3(32,1,8), blk, 0, stream>>>(
                hidT, w1l, masks, b1+l*NC, g1+l*NC, bb1+l*NC, m1+l*NC, v1+l*NC, tmpT);
        mfma_gemm_kernel<0,1><<<dim3(32,1,8), blk, 0, stream>>>(
            tmpT, w2l, masks, b2+l*NC, g2+l*NC, bb2+l*NC, m2+l*NC, v2+l*NC, hidT);
    }

    copy_flip_kernel<<<dim3((NB*NHALF*NT + 255)/256), blk, 0, stream>>>(x, masks, out);

    const u16* pjwpad = wbf + W1N + W2N;
    proj_spline_mfma_kernel<<<dim3(16,16,16), blk, 0, stream>>>(
        hidT, pjwpad, pjb_pad, x, masks, out, partial);

    logdet_reduce_kernel<<<dim3(8), blk, 0, stream>>>(partial, out);
}

// Round 10
// 204.537 us; speedup vs baseline: 4.5952x; 2.0809x over previous
//
#include <hip/hip_runtime.h>
#include <math.h>

#define NB 8
#define NC 192
#define NT 2048
#define NHALF 96
#define NP 29
#define OUT_ELEMS (NB*NC*NT)
#define KP 100   // padded activation row: 100 dwords = 200 bf16 (192 used)
#define PS 68    // P LDS row stride (floats): 4*68 mod 32 = 16 -> 2-way (free)

typedef short bf16x8 __attribute__((ext_vector_type(8)));
typedef float f32x4 __attribute__((ext_vector_type(4)));
typedef unsigned short u16;
typedef unsigned int u32;

__device__ __forceinline__ u16 f2bf(float f) {
    u32 u = __builtin_bit_cast(u32, f);
    u += 0x7fffu + ((u >> 16) & 1u);
    return (u16)(u >> 16);
}
__device__ __forceinline__ float softplus_fast(float v) {
    return (v > 20.0f) ? v : __logf(1.0f + __expf(v));
}
// mish(x) = x*tanh(softplus(x)) = x*(s^2-1)/(s^2+1), s = 1+e^x
__device__ __forceinline__ float mishf(float v) {
    if (v > 20.0f) return v;
    float s = 1.0f + __expf(v);
    float s2 = s * s;
    return v * (s2 - 1.0f) / (s2 + 1.0f);
}

// ---------- weight convert + fragment swizzle ----------
// Each 192-col matrix is tiled into (mt: 16 rows) x (kk: 32 cols) MFMA tiles of
// 512 bf16, stored lane-major: swz[tile*512 + lane*8 + e] = W[m][k],
//   m = mt*16 + (lane&15), k = kk*32 + (lane>>4)*8 + e
// so a wave's A-fragment load (lane*16B) is one contiguous 1KB transaction.
// wbf: [w1: s(3) x j(3) x swz(192x192)][w2: s(3) x swz(192x192)][pj: swz(3072x192)]
#define W1N 331776   // 3*3*36864
#define W2N 110592   // 3*36864
#define PADN 589824  // 1152*512
#define WTOT (W1N+W2N+PADN)
__global__ __launch_bounds__(256) void wconv_kernel(
    const float* __restrict__ w1, const float* __restrict__ w2,
    const float* __restrict__ pjw, const float* __restrict__ pjb,
    u16* __restrict__ outw, float* __restrict__ pjb_pad)
{
    int i = blockIdx.x*256 + threadIdx.x;
    if (i < WTOT) {
        float v;
        if (i < W1N) {
            int s = i / 110592, r = i % 110592;
            int j = r / 36864, q = r % 36864;
            int tile = q >> 9, lane = (q >> 3) & 63, e = q & 7;
            int mt = tile / 6, kk = tile % 6;
            int m = mt*16 + (lane & 15);
            int k = kk*32 + (lane >> 4)*8 + e;
            v = w1[(((size_t)s*192 + m)*192 + k)*3 + j];
        } else if (i < W1N + W2N) {
            int q0 = i - W1N;
            int s = q0 / 36864, q = q0 % 36864;
            int tile = q >> 9, lane = (q >> 3) & 63, e = q & 7;
            int mt = tile / 6, kk = tile % 6;
            int m = mt*16 + (lane & 15);
            int k = kk*32 + (lane >> 4)*8 + e;
            v = w2[((size_t)s*192 + m)*192 + k];
        } else {
            int q = i - W1N - W2N;
            int tile = q >> 9, lane = (q >> 3) & 63, e = q & 7;
            int mt = tile / 6, kk = tile % 6;
            int m = mt*16 + (lane & 15);            // 0..3071
            int k = kk*32 + (lane >> 4)*8 + e;
            int c = m >> 5, p = m & 31;
            v = (p < NP) ? pjw[((size_t)(c*NP + p))*192 + k] : 0.f;
        }
        outw[i] = f2bf(v);
    } else if (i < WTOT + 3072) {
        int mp = i - WTOT;
        int c = mp >> 5, p = mp & 31;
        pjb_pad[mp] = (p < NP) ? pjb[c*NP + p] : 0.f;
    }
}

// ---------- prenet: fp32 1x1 conv 96->192, writes TRANSPOSED hidT [b][t][192] ----------
__global__ __launch_bounds__(256) void prenet_kernel(
    const float* __restrict__ x, const float* __restrict__ cond,
    const float* __restrict__ w, const float* __restrict__ bias,
    float* __restrict__ hidT)
{
    __shared__ float sh[48][64];
    const int tid = threadIdx.x;
    const int tt = tid & 63, og = tid >> 6;
    const int b = blockIdx.z;
    const int t0 = blockIdx.x * 64;
    const int o0 = blockIdx.y * 16 + og * 4;
    const int o0u = __builtin_amdgcn_readfirstlane(o0);
    const int t = t0 + tt;
    const float* inb = x + (size_t)b * NC * NT;
    float acc[4] = {0.f,0.f,0.f,0.f};
    for (int kb = 0; kb < 2; ++kb) {
        for (int idx = tid; idx < 48*64; idx += 256) {
            int r = idx >> 6, col = idx & 63;
            sh[r][col] = inb[(kb*48 + r)*NT + t0 + col];
        }
        __syncthreads();
        #pragma unroll 4
        for (int r = 0; r < 48; ++r) {
            float h = sh[r][tt];
            const float* wr = w + (size_t)o0u*96 + kb*48 + r;
            #pragma unroll
            for (int j = 0; j < 4; ++j)
                acc[j] = fmaf(wr[(size_t)j*96], h, acc[j]);
        }
        __syncthreads();
    }
    #pragma unroll
    for (int j = 0; j < 4; ++j) {
        int o = o0u + j;
        float v = acc[j] + bias[o] + cond[((size_t)b*NC + o)*NT + t];
        hidT[((size_t)b*NT + t)*NC + o] = v;
    }
}

// ---------- MFMA GEMM for residual blocks (TT=32, M split by blockIdx.y) ----------
// grid (64, 2, 8), block 256.  Per block: 96 m x 32 t x 192 k (x NPASS taps).
// EPI 0: conv3 (3 dilated passes), in=hidT fp32 *mask, out=tmpT bf16, mish+BN
// EPI 1: conv1x1, in=tmpT bf16, out=hidT fp32 += mish+BN (residual)
template<int DIL, int EPI>
__global__ __launch_bounds__(256) void mfma_gemm_kernel(
    const void* __restrict__ inp, const u16* __restrict__ wA,
    const float* __restrict__ masks, const float* __restrict__ bias,
    const float* __restrict__ g, const float* __restrict__ bb,
    const float* __restrict__ bm, const float* __restrict__ bv,
    void* __restrict__ outp)
{
    constexpr int ROWS = 32 + 2*DIL;
    __shared__ u32 sm[ROWS * KP];
    const int tid  = threadIdx.x;
    const int lane = tid & 63;
    const int wid  = tid >> 6;
    const int owave = wid & 1, twave = wid >> 1;
    const int b = blockIdx.z;
    const int tg0 = blockIdx.x * 32;

    if constexpr (EPI == 1) {
        const u32* inU = (const u32*)inp;
        for (int idx = tid; idx < 32*96; idx += 256) {
            int row = idx / 96, kp = idx - row*96;
            sm[row*KP + kp] = inU[((size_t)b*NT + tg0 + row)*96 + kp];
        }
    } else {
        const float* inF = (const float*)inp;
        for (int idx = tid; idx < ROWS*96; idx += 256) {
            int row = idx / 96, kp = idx - row*96;
            int t = tg0 + row - DIL;
            float vx = 0.f, vy = 0.f;
            if (t >= 0 && t < NT) {
                const float* p = inF + ((size_t)b*NT + t)*NC + 2*kp;
                float mv = masks[(size_t)b*NT + t];
                vx = p[0]*mv; vy = p[1]*mv;
            }
            sm[row*KP + kp] = (u32)f2bf(vx) | ((u32)f2bf(vy) << 16);
        }
    }
    __syncthreads();

    f32x4 acc[3];
    #pragma unroll
    for (int i = 0; i < 3; ++i) acc[i] = f32x4{0.f,0.f,0.f,0.f};

    constexpr int NPASS = (EPI == 0) ? 3 : 1;
    const int l15 = lane & 15;
    const int kg  = lane >> 4;
    const char* smb = (const char*)sm;

    for (int j = 0; j < NPASS; ++j) {
        const u16* wsl = wA + (size_t)j * 36864;
        const int rbase = twave*16 + l15 + j*DIL;
        for (int kk = 0; kk < 6; ++kk) {
            int k0 = kk*32 + kg*8;
            bf16x8 b0 = *(const bf16x8*)(smb + (size_t)rbase*400 + k0*2);
            bf16x8 af[3];
            #pragma unroll
            for (int ot = 0; ot < 3; ++ot) {
                int mt = blockIdx.y*6 + owave*3 + ot;
                af[ot] = *(const bf16x8*)(wsl + ((size_t)(mt*6 + kk))*512 + lane*8);
            }
            #pragma unroll
            for (int ot = 0; ot < 3; ++ot)
                acc[ot] = __builtin_amdgcn_mfma_f32_16x16x32_bf16(af[ot], b0, acc[ot], 0, 0, 0);
        }
    }

    #pragma unroll
    for (int ot = 0; ot < 3; ++ot) {
        int tl = twave*16 + l15;
        int o4 = blockIdx.y*96 + owave*48 + ot*16 + (kg << 2);
        f32x4 A = acc[ot];
        int t = tg0 + tl;
        f32x4 bi = *(const f32x4*)(bias + o4);
        f32x4 g4 = *(const f32x4*)(g + o4);
        f32x4 bb4 = *(const f32x4*)(bb + o4);
        f32x4 bm4 = *(const f32x4*)(bm + o4);
        f32x4 bv4 = *(const f32x4*)(bv + o4);
        float vr[4];
        #pragma unroll
        for (int r = 0; r < 4; ++r) {
            float v = mishf(A[r] + bi[r]);
            vr[r] = (v - bm4[r]) * (g4[r] * rsqrtf(bv4[r] + 1e-5f)) + bb4[r];
        }
        if constexpr (EPI == 0) {
            u32 lo = (u32)f2bf(vr[0]) | ((u32)f2bf(vr[1]) << 16);
            u32 hi = (u32)f2bf(vr[2]) | ((u32)f2bf(vr[3]) << 16);
            u32* dst = (u32*)((u16*)outp + ((size_t)b*NT + t)*NC + o4);
            dst[0] = lo; dst[1] = hi;
        } else {
            float* dst = (float*)outp + ((size_t)b*NT + t)*NC + o4;
            f32x4 old = *(const f32x4*)dst;
            f32x4 nv;
            #pragma unroll
            for (int r = 0; r < 4; ++r) nv[r] = old[r] + vr[r];
            *(f32x4*)dst = nv;
        }
    }
}

// ---------- copy x0 channels to flipped out channels, *mask ----------
__global__ __launch_bounds__(256) void copy_flip_kernel(
    const float* __restrict__ x, const float* __restrict__ masks,
    float* __restrict__ outp)
{
    int idx = blockIdx.x*256 + threadIdx.x;
    if (idx >= NB*NHALF*NT) return;
    int t = idx & (NT-1);
    int r = idx >> 11;
    int c = r % NHALF;
    int b = r / NHALF;
    float v = x[((size_t)b*NC + c)*NT + t] * masks[(size_t)b*NT + t];
    outp[((size_t)b*NC + (NC-1 - c))*NT + t] = v;
}

// ---------- fused proj GEMM (padded 3072x192, swizzled) + RQ spline + lad ----------
// grid (16 t-tiles, 16 m-blocks(=6c each), 16 units(b,th)), block 256
__global__ __launch_bounds__(256) void proj_spline_mfma_kernel(
    const float* __restrict__ hidT, const u16* __restrict__ wpad,
    const float* __restrict__ pjb_pad, const float* __restrict__ x,
    const float* __restrict__ masks, float* __restrict__ outp,
    float* __restrict__ partial)
{
    __shared__ float uls[192*PS];   // union: staging (first 6400 u32) then P [192][PS]
    __shared__ float red[256];
    u32* sm = (u32*)uls;
    const int tid  = threadIdx.x;
    const int lane = tid & 63;
    const int wid  = tid >> 6;
    const int owave = wid & 1, twave = wid >> 1;
    const int z  = blockIdx.z;
    const int b  = z >> 1, th = z & 1;
    const int tg0 = th*1024 + blockIdx.x*64;

    // stage B tile: 64 t-rows x 192 k, masked, bf16-pairs
    for (int idx = tid; idx < 64*96; idx += 256) {
        int row = idx / 96, kp = idx - row*96;
        int t = tg0 + row;
        const float* p = hidT + ((size_t)b*NT + t)*NC + 2*kp;
        float mv = masks[(size_t)b*NT + t];
        sm[row*KP + kp] = (u32)f2bf(p[0]*mv) | ((u32)f2bf(p[1]*mv) << 16);
    }
    __syncthreads();

    f32x4 acc[6][2];
    #pragma unroll
    for (int i = 0; i < 6; ++i) {
        acc[i][0] = f32x4{0.f,0.f,0.f,0.f};
        acc[i][1] = f32x4{0.f,0.f,0.f,0.f};
    }
    const int l15 = lane & 15;
    const int kg  = lane >> 4;
    const char* smb = (const char*)sm;

    for (int kk = 0; kk < 6; ++kk) {
        int k0 = kk*32 + kg*8;
        bf16x8 b0 = *(const bf16x8*)(smb + (size_t)(twave*32 + l15)*400 + k0*2);
        bf16x8 b1 = *(const bf16x8*)(smb + (size_t)(twave*32 + l15 + 16)*400 + k0*2);
        bf16x8 af[6];
        #pragma unroll
        for (int ot = 0; ot < 6; ++ot) {
            int mt = blockIdx.y*12 + owave*6 + ot;
            af[ot] = *(const bf16x8*)(wpad + ((size_t)(mt*6 + kk))*512 + lane*8);
        }
        #pragma unroll
        for (int ot = 0; ot < 6; ++ot) {
            acc[ot][0] = __builtin_amdgcn_mfma_f32_16x16x32_bf16(af[ot], b0, acc[ot][0], 0, 0, 0);
            acc[ot][1] = __builtin_amdgcn_mfma_f32_16x16x32_bf16(af[ot], b1, acc[ot][1], 0, 0, 0);
        }
    }
    __syncthreads();   // staging dead; reuse LDS as P

    // P[m_local][t_local] = (acc + pjb_pad) * mask, fp32, stride PS
    #pragma unroll
    for (int ot = 0; ot < 6; ++ot) {
        int o4 = owave*96 + ot*16 + (kg << 2);
        f32x4 pb = *(const f32x4*)(pjb_pad + blockIdx.y*192 + o4);
        #pragma unroll
        for (int t2 = 0; t2 < 2; ++t2) {
            int tl = twave*32 + t2*16 + l15;
            float mkv = masks[(size_t)b*NT + tg0 + tl];
            f32x4 A = acc[ot][t2];
            #pragma unroll
            for (int r = 0; r < 4; ++r)
                uls[(o4 + r)*PS + tl] = (A[r] + pb[r]) * mkv;
        }
    }
    __syncthreads();

    // spline: 6 c-channels x 64 t per block
    float lsum = 0.f;
    for (int idx = tid; idx < 384; idx += 256) {
        int cl = idx >> 6, t = idx & 63;
        int c  = blockIdx.y*6 + cl;
        int tg = tg0 + t;
        float m = masks[(size_t)b*NT + tg];

        float pr[NP];
        #pragma unroll
        for (int p = 0; p < NP; ++p)
            pr[p] = uls[(cl*32 + p)*PS + t];

        const float invsq = 0.07216878364870322f;  // 1/sqrt(192)
        float cw[11], chh[11];
        {   // width knots
            float u[10], e[10];
            #pragma unroll
            for (int i = 0; i < 10; ++i) u[i] = pr[i] * invsq;
            float mx = u[0];
            #pragma unroll
            for (int i = 1; i < 10; ++i) mx = fmaxf(mx, u[i]);
            float s = 0.f;
            #pragma unroll
            for (int i = 0; i < 10; ++i) { e[i] = __expf(u[i]-mx); s += e[i]; }
            float inv_s = 1.f / s;
            float run = 0.f;
            cw[0] = -5.f;
            #pragma unroll
            for (int i = 0; i < 10; ++i) {
                run += 0.001f + 0.99f * e[i] * inv_s;
                cw[i+1] = 10.f*run - 5.f;
            }
            cw[10] = 5.f;
        }
        {   // height knots
            float u[10], e[10];
            #pragma unroll
            for (int i = 0; i < 10; ++i) u[i] = pr[10+i] * invsq;
            float mx = u[0];
            #pragma unroll
            for (int i = 1; i < 10; ++i) mx = fmaxf(mx, u[i]);
            float s = 0.f;
            #pragma unroll
            for (int i = 0; i < 10; ++i) { e[i] = __expf(u[i]-mx); s += e[i]; }
            float inv_s = 1.f / s;
            float run = 0.f;
            chh[0] = -5.f;
            #pragma unroll
            for (int i = 0; i < 10; ++i) {
                run += 0.001f + 0.99f * e[i] * inv_s;
                chh[i+1] = 10.f*run - 5.f;
            }
            chh[10] = 5.f;
        }

        float x1 = x[((size_t)b*NC + NHALF + c)*NT + tg];
        float xc = fminf(fmaxf(x1, -5.f), 5.f);
        int cnt = 0;
        #pragma unroll
        for (int i = 0; i < 11; ++i) cnt += (xc >= cw[i]) ? 1 : 0;
        int kidx = cnt - 1;
        kidx = kidx < 0 ? 0 : (kidx > 9 ? 9 : kidx);

        // static-index selection (registers only)
        float icw=0.f, iw=1.f, ich=0.f, ih=0.f, s0=0.f, s1=0.f;
        #pragma unroll
        for (int i = 0; i < 10; ++i) {
            if (i == kidx) {
                icw = cw[i]; iw = cw[i+1]-cw[i];
                ich = chh[i]; ih = chh[i+1]-chh[i];
                s0 = (i >= 1) ? pr[19+i] : 0.f;
                s1 = (i <= 8) ? pr[20+i] : 0.f;
            }
        }
        // derivatives: endpoints exactly 1 (md + softplus(const) = 1); interior 0.001+softplus
        float d0 = (kidx == 0) ? 1.f : 0.001f + softplus_fast(s0);
        float d1 = (kidx == 9) ? 1.f : 0.001f + softplus_fast(s1);

        float dlt   = ih / iw;
        float theta = (xc - icw) / iw;
        float t1m   = theta * (1.f - theta);
        float den   = dlt + (d0 + d1 - 2.f*dlt) * t1m;
        float num   = ih * (dlt*theta*theta + d0*t1m);
        float outv  = ich + num / den;
        float omt   = 1.f - theta;
        float dnum  = dlt*dlt*(d1*theta*theta + 2.f*dlt*t1m + d0*omt*omt);
        float lad   = __logf(dnum) - 2.f*__logf(den);
        bool inside = (x1 >= -5.f) && (x1 <= 5.f);
        float xout  = inside ? outv : x1;
        float ladv  = inside ? lad : 0.f;
        outp[((size_t)b*NC + (NHALF-1 - c))*NT + tg] = xout * m;
        lsum += ladv * m;
    }

    red[tid] = lsum;
    __syncthreads();
    for (int s2 = 128; s2 > 0; s2 >>= 1) {
        if (tid < s2) red[tid] += red[tid + s2];
        __syncthreads();
    }
    if (tid == 0)
        partial[(size_t)b*512 + th*256 + blockIdx.y*16 + blockIdx.x] = red[0];
}

__global__ __launch_bounds__(256) void logdet_reduce_kernel(
    const float* __restrict__ partial, float* __restrict__ outp)
{
    __shared__ float red[256];
    const int b = blockIdx.x;
    const int tid = threadIdx.x;
    float s = 0.f;
    for (int i = tid; i < 512; i += 256) s += partial[(size_t)b*512 + i];
    red[tid] = s;
    __syncthreads();
    for (int st = 128; st > 0; st >>= 1) {
        if (tid < st) red[tid] += red[tid + st];
        __syncthreads();
    }
    if (tid == 0) outp[(size_t)OUT_ELEMS + b] = red[0];
}

extern "C" void kernel_launch(void* const* d_in, const int* in_sizes, int n_in,
                              void* d_out, int out_size, void* d_ws, size_t ws_size,
                              hipStream_t stream) {
    const float* x     = (const float*)d_in[0];
    const float* cond  = (const float*)d_in[1];
    const float* masks = (const float*)d_in[2];
    const float* pw    = (const float*)d_in[3];
    const float* pb    = (const float*)d_in[4];
    const float* w1    = (const float*)d_in[5];
    const float* b1    = (const float*)d_in[6];
    const float* g1    = (const float*)d_in[7];
    const float* bb1   = (const float*)d_in[8];
    const float* m1    = (const float*)d_in[9];
    const float* v1    = (const float*)d_in[10];
    const float* w2    = (const float*)d_in[11];
    const float* b2    = (const float*)d_in[12];
    const float* g2    = (const float*)d_in[13];
    const float* bb2   = (const float*)d_in[14];
    const float* m2    = (const float*)d_in[15];
    const float* v2    = (const float*)d_in[16];
    const float* pjw   = (const float*)d_in[17];
    const float* pjb   = (const float*)d_in[18];

    float* out = (float*)d_out;
    char* wsb = (char*)d_ws;
    // ws: [hidT fp32 12.58MB][wbf bf16 2.06MB][pjb_pad 12KB][partial 16KB][tmpT bf16 6.29MB]
    float* hidT    = (float*)wsb;
    u16*   wbf     = (u16*)(wsb + 12582912);
    float* pjb_pad = (float*)(wsb + 12582912 + 2064384);
    float* partial = (float*)(wsb + 12582912 + 2064384 + 12288);
    char*  tmpT    = wsb + 12582912 + 2064384 + 12288 + 16384;

    dim3 blk(256);

    wconv_kernel<<<dim3((WTOT + 3072 + 255)/256), blk, 0, stream>>>(w1, w2, pjw, pjb, wbf, pjb_pad);
    prenet_kernel<<<dim3(32,12,8), blk, 0, stream>>>(x, cond, pw, pb, hidT);

    dim3 grid_c(64, 2, 8);
    for (int l = 0; l < 3; ++l) {
        const u16* w1l = wbf + (size_t)l*110592;           // [j][swz 192x192] slabs
        const u16* w2l = wbf + W1N + (size_t)l*36864;      // [swz 192x192]
        if (l == 0)
            mfma_gemm_kernel<1,0><<<grid_c, blk, 0, stream>>>(
                hidT, w1l, masks, b1+l*NC, g1+l*NC, bb1+l*NC, m1+l*NC, v1+l*NC, tmpT);
        else if (l == 1)
            mfma_gemm_kernel<3,0><<<grid_c, blk, 0, stream>>>(
                hidT, w1l, masks, b1+l*NC, g1+l*NC, bb1+l*NC, m1+l*NC, v1+l*NC, tmpT);
        else
            mfma_gemm_kernel<9,0><<<grid_c, blk, 0, stream>>>(
                hidT, w1l, masks, b1+l*NC, g1+l*NC, bb1+l*NC, m1+l*NC, v1+l*NC, tmpT);
        mfma_gemm_kernel<0,1><<<grid_c, blk, 0, stream>>>(
            tmpT, w2l, masks, b2+l*NC, g2+l*NC, bb2+l*NC, m2+l*NC, v2+l*NC, hidT);
    }

    copy_flip_kernel<<<dim3((NB*NHALF*NT + 255)/256), blk, 0, stream>>>(x, masks, out);

    const u16* pjwpad = wbf + W1N + W2N;
    proj_spline_mfma_kernel<<<dim3(16,16,16), blk, 0, stream>>>(
        hidT, pjwpad, pjb_pad, x, masks, out, partial);

    logdet_reduce_kernel<<<dim3(8), blk, 0, stream>>>(partial, out);
}

// Round 11
// 162.734 us; speedup vs baseline: 5.7756x; 1.2569x over previous
//
#include <hip/hip_runtime.h>
#include <math.h>

#define NB 8
#define NC 192
#define NT 2048
#define NHALF 96
#define NP 29
#define OUT_ELEMS (NB*NC*NT)
#define KP 100   // LDS activation row stride in dwords (200 bf16, 192 used)
#define PS 68    // P LDS row stride (floats)

typedef short bf16x8 __attribute__((ext_vector_type(8)));
typedef float f32x4 __attribute__((ext_vector_type(4)));
typedef unsigned short u16;
typedef unsigned int u32;

__device__ __forceinline__ u16 f2bf(float f) {
    u32 u = __builtin_bit_cast(u32, f);
    u += 0x7fffu + ((u >> 16) & 1u);
    return (u16)(u >> 16);
}
__device__ __forceinline__ float softplus_fast(float v) {
    return (v > 20.0f) ? v : __logf(1.0f + __expf(v));
}
// mish(x) = x*tanh(softplus(x)) = x*(s^2-1)/(s^2+1), s = 1+e^x
__device__ __forceinline__ float mishf(float v) {
    if (v > 20.0f) return v;
    float s = 1.0f + __expf(v);
    float s2 = s * s;
    return v * (s2 - 1.0f) / (s2 + 1.0f);
}

// ---------- weight convert + fragment swizzle ----------
// Every matrix tiled into (mt:16 rows)x(kk:32 cols) MFMA tiles of 512 bf16,
// lane-major: swz[tile*512 + lane*8 + e] = W[m][k], m = mt*16+(lane&15),
// k = kk*32+(lane>>4)*8+e  -> wave A-load = one contiguous 1KB transaction.
// wbf: [w1: s3 x j3 x swz(192x192)][w2: s3 x swz(192x192)][pj: swz(3072x192)][pre: swz(192x96)]
#define W1N 331776   // 3*3*36864
#define W2N 110592   // 3*36864
#define PADN 589824  // 1152*512
#define PREN 18432   // 36*512
#define WT2 (W1N+W2N+PADN+PREN)
__global__ __launch_bounds__(256) void wconv_kernel(
    const float* __restrict__ w1, const float* __restrict__ w2,
    const float* __restrict__ pjw, const float* __restrict__ pjb,
    const float* __restrict__ pw,
    u16* __restrict__ outw, float* __restrict__ pjb_pad)
{
    int i = blockIdx.x*256 + threadIdx.x;
    if (i < WT2) {
        float v;
        if (i < W1N) {
            int s = i / 110592, r = i % 110592;
            int j = r / 36864, q = r % 36864;
            int tile = q >> 9, lane = (q >> 3) & 63, e = q & 7;
            int mt = tile / 6, kk = tile % 6;
            int m = mt*16 + (lane & 15);
            int k = kk*32 + (lane >> 4)*8 + e;
            v = w1[(((size_t)s*192 + m)*192 + k)*3 + j];
        } else if (i < W1N + W2N) {
            int q0 = i - W1N;
            int s = q0 / 36864, q = q0 % 36864;
            int tile = q >> 9, lane = (q >> 3) & 63, e = q & 7;
            int mt = tile / 6, kk = tile % 6;
            int m = mt*16 + (lane & 15);
            int k = kk*32 + (lane >> 4)*8 + e;
            v = w2[((size_t)s*192 + m)*192 + k];
        } else if (i < W1N + W2N + PADN) {
            int q = i - W1N - W2N;
            int tile = q >> 9, lane = (q >> 3) & 63, e = q & 7;
            int mt = tile / 6, kk = tile % 6;
            int m = mt*16 + (lane & 15);            // 0..3071
            int k = kk*32 + (lane >> 4)*8 + e;
            int c = m >> 5, p = m & 31;
            v = (p < NP) ? pjw[((size_t)(c*NP + p))*192 + k] : 0.f;
        } else {
            int q = i - W1N - W2N - PADN;
            int tile = q >> 9, lane = (q >> 3) & 63, e = q & 7;
            int mt = tile / 3, kk = tile % 3;
            int m = mt*16 + (lane & 15);            // 0..191
            int k = kk*32 + (lane >> 4)*8 + e;      // 0..95
            v = pw[(size_t)m*96 + k];
        }
        outw[i] = f2bf(v);
    } else if (i < WT2 + 3072) {
        int mp = i - WT2;
        int c = mp >> 5, p = mp & 31;
        pjb_pad[mp] = (p < NP) ? pjb[c*NP + p] : 0.f;
    }
}

// ---------- prenet MFMA: hidT[t][o] = W(192x96) x0 + bias + cond ----------
// grid (64, 1, 8), block 256.  TT=32, full M=192.
__global__ __launch_bounds__(256) void prenet_mfma_kernel(
    const float* __restrict__ x, const float* __restrict__ cond,
    const u16* __restrict__ wps, const float* __restrict__ bias,
    float* __restrict__ hidT)
{
    __shared__ u32 sm[32 * 52];
    const int tid = threadIdx.x, lane = tid & 63, wid = tid >> 6;
    const int b = blockIdx.z, tg0 = blockIdx.x * 32;
    const int l15 = lane & 15, kg = lane >> 4;

    for (int idx = tid; idx < 48*32; idx += 256) {
        int c2 = idx >> 5, tl = idx & 31;
        const float* p = x + ((size_t)b*NC + 2*c2)*NT + tg0 + tl;
        sm[tl*52 + c2] = (u32)f2bf(p[0]) | ((u32)f2bf(p[NT]) << 16);
    }
    __syncthreads();

    f32x4 acc[3][2];
    #pragma unroll
    for (int i = 0; i < 3; ++i) { acc[i][0] = f32x4{0,0,0,0}; acc[i][1] = f32x4{0,0,0,0}; }
    const char* smb = (const char*)sm;

    for (int kk = 0; kk < 3; ++kk) {
        int k0 = kk*32 + kg*8;
        bf16x8 b0 = *(const bf16x8*)(smb + (size_t)l15*208 + k0*2);
        bf16x8 b1f = *(const bf16x8*)(smb + (size_t)(l15+16)*208 + k0*2);
        bf16x8 af[3];
        #pragma unroll
        for (int ot = 0; ot < 3; ++ot) {
            int mt = wid*3 + ot;
            af[ot] = *(const bf16x8*)(wps + ((size_t)(mt*3 + kk))*512 + lane*8);
        }
        #pragma unroll
        for (int ot = 0; ot < 3; ++ot) {
            acc[ot][0] = __builtin_amdgcn_mfma_f32_16x16x32_bf16(af[ot], b0, acc[ot][0], 0, 0, 0);
            acc[ot][1] = __builtin_amdgcn_mfma_f32_16x16x32_bf16(af[ot], b1f, acc[ot][1], 0, 0, 0);
        }
    }

    #pragma unroll
    for (int ot = 0; ot < 3; ++ot) {
        int m = (wid*3 + ot)*16 + (kg << 2);
        f32x4 bi = *(const f32x4*)(bias + m);
        #pragma unroll
        for (int tt = 0; tt < 2; ++tt) {
            int t = tg0 + tt*16 + l15;
            f32x4 A = acc[ot][tt];
            f32x4 o;
            #pragma unroll
            for (int r = 0; r < 4; ++r)
                o[r] = A[r] + bi[r] + cond[((size_t)b*NC + m + r)*NT + t];
            *(f32x4*)(hidT + ((size_t)b*NT + t)*NC + m) = o;
        }
    }
}

// ---------- fused residual block: GEMM1(3-tap dilated) -> mish/BN -> LDS ->
//            GEMM2(1x1) -> mish/BN -> residual add into hidT ----------
// grid (64, 1, 8), block 256.  TT=32, full M=192 both GEMMs.
template<int DIL>
__global__ __launch_bounds__(256) void resblock_kernel(
    float* __restrict__ hidT, const u16* __restrict__ w1s, const u16* __restrict__ w2s,
    const float* __restrict__ masks,
    const float* __restrict__ b1v, const float* __restrict__ g1v, const float* __restrict__ bb1v,
    const float* __restrict__ bm1v, const float* __restrict__ bv1v,
    const float* __restrict__ b2v, const float* __restrict__ g2v, const float* __restrict__ bb2v,
    const float* __restrict__ bm2v, const float* __restrict__ bv2v)
{
    constexpr int ROWS = 32 + 2*DIL;
    __shared__ u32 sm1[ROWS * KP];
    __shared__ u32 sm2[32 * KP];
    const int tid = threadIdx.x, lane = tid & 63, wid = tid >> 6;
    const int b = blockIdx.z, tg0 = blockIdx.x * 32;
    const int l15 = lane & 15, kg = lane >> 4;

    // stage hid tile, masked, bf16 pairs [t-row][k]
    for (int idx = tid; idx < ROWS*96; idx += 256) {
        int row = idx / 96, kp = idx - row*96;
        int t = tg0 + row - DIL;
        float vx = 0.f, vy = 0.f;
        if (t >= 0 && t < NT) {
            const float* p = hidT + ((size_t)b*NT + t)*NC + 2*kp;
            float mv = masks[(size_t)b*NT + t];
            vx = p[0]*mv; vy = p[1]*mv;
        }
        sm1[row*KP + kp] = (u32)f2bf(vx) | ((u32)f2bf(vy) << 16);
    }
    __syncthreads();

    // GEMM1: 192m x 32t x 192k x 3 taps
    f32x4 acc[3][2];
    #pragma unroll
    for (int i = 0; i < 3; ++i) { acc[i][0] = f32x4{0,0,0,0}; acc[i][1] = f32x4{0,0,0,0}; }
    const char* smb1 = (const char*)sm1;

    for (int j = 0; j < 3; ++j) {
        const u16* wsl = w1s + (size_t)j * 36864;
        for (int kk = 0; kk < 6; ++kk) {
            int k0 = kk*32 + kg*8;
            bf16x8 b0  = *(const bf16x8*)(smb1 + (size_t)(l15 + j*DIL)*400 + k0*2);
            bf16x8 b1f = *(const bf16x8*)(smb1 + (size_t)(l15 + 16 + j*DIL)*400 + k0*2);
            bf16x8 af[3];
            #pragma unroll
            for (int ot = 0; ot < 3; ++ot) {
                int mt = wid*3 + ot;
                af[ot] = *(const bf16x8*)(wsl + ((size_t)(mt*6 + kk))*512 + lane*8);
            }
            #pragma unroll
            for (int ot = 0; ot < 3; ++ot) {
                acc[ot][0] = __builtin_amdgcn_mfma_f32_16x16x32_bf16(af[ot], b0,  acc[ot][0], 0, 0, 0);
                acc[ot][1] = __builtin_amdgcn_mfma_f32_16x16x32_bf16(af[ot], b1f, acc[ot][1], 0, 0, 0);
            }
        }
    }

    // epilogue1: tmp = BN1(mish(acc+b1)) -> sm2 [t][k] bf16 pairs
    #pragma unroll
    for (int ot = 0; ot < 3; ++ot) {
        int m = (wid*3 + ot)*16 + (kg << 2);
        f32x4 bi = *(const f32x4*)(b1v + m);
        f32x4 g4 = *(const f32x4*)(g1v + m);
        f32x4 bb4 = *(const f32x4*)(bb1v + m);
        f32x4 bm4 = *(const f32x4*)(bm1v + m);
        f32x4 bv4 = *(const f32x4*)(bv1v + m);
        #pragma unroll
        for (int tt = 0; tt < 2; ++tt) {
            int tl = tt*16 + l15;
            f32x4 A = acc[ot][tt];
            float vr[4];
            #pragma unroll
            for (int r = 0; r < 4; ++r) {
                float v = mishf(A[r] + bi[r]);
                vr[r] = (v - bm4[r]) * (g4[r] * rsqrtf(bv4[r] + 1e-5f)) + bb4[r];
            }
            sm2[tl*KP + (m >> 1)]     = (u32)f2bf(vr[0]) | ((u32)f2bf(vr[1]) << 16);
            sm2[tl*KP + (m >> 1) + 1] = (u32)f2bf(vr[2]) | ((u32)f2bf(vr[3]) << 16);
        }
    }
    __syncthreads();

    // GEMM2: 192m x 32t x 192k from sm2
    f32x4 acc2[3][2];
    #pragma unroll
    for (int i = 0; i < 3; ++i) { acc2[i][0] = f32x4{0,0,0,0}; acc2[i][1] = f32x4{0,0,0,0}; }
    const char* smb2 = (const char*)sm2;

    for (int kk = 0; kk < 6; ++kk) {
        int k0 = kk*32 + kg*8;
        bf16x8 b0  = *(const bf16x8*)(smb2 + (size_t)l15*400 + k0*2);
        bf16x8 b1f = *(const bf16x8*)(smb2 + (size_t)(l15+16)*400 + k0*2);
        bf16x8 af[3];
        #pragma unroll
        for (int ot = 0; ot < 3; ++ot) {
            int mt = wid*3 + ot;
            af[ot] = *(const bf16x8*)(w2s + ((size_t)(mt*6 + kk))*512 + lane*8);
        }
        #pragma unroll
        for (int ot = 0; ot < 3; ++ot) {
            acc2[ot][0] = __builtin_amdgcn_mfma_f32_16x16x32_bf16(af[ot], b0,  acc2[ot][0], 0, 0, 0);
            acc2[ot][1] = __builtin_amdgcn_mfma_f32_16x16x32_bf16(af[ot], b1f, acc2[ot][1], 0, 0, 0);
        }
    }

    // epilogue2: hidT += BN2(mish(acc2+b2))
    #pragma unroll
    for (int ot = 0; ot < 3; ++ot) {
        int m = (wid*3 + ot)*16 + (kg << 2);
        f32x4 bi = *(const f32x4*)(b2v + m);
        f32x4 g4 = *(const f32x4*)(g2v + m);
        f32x4 bb4 = *(const f32x4*)(bb2v + m);
        f32x4 bm4 = *(const f32x4*)(bm2v + m);
        f32x4 bv4 = *(const f32x4*)(bv2v + m);
        #pragma unroll
        for (int tt = 0; tt < 2; ++tt) {
            int t = tg0 + tt*16 + l15;
            f32x4 A = acc2[ot][tt];
            float* dst = hidT + ((size_t)b*NT + t)*NC + m;
            f32x4 old = *(const f32x4*)dst;
            f32x4 nv;
            #pragma unroll
            for (int r = 0; r < 4; ++r) {
                float v = mishf(A[r] + bi[r]);
                nv[r] = old[r] + (v - bm4[r]) * (g4[r] * rsqrtf(bv4[r] + 1e-5f)) + bb4[r] * 0.f;
                nv[r] = old[r] + ((v - bm4[r]) * (g4[r] * rsqrtf(bv4[r] + 1e-5f)) + bb4[r]);
            }
            *(f32x4*)dst = nv;
        }
    }
}

// ---------- copy x0 channels to flipped out channels, *mask ----------
__global__ __launch_bounds__(256) void copy_flip_kernel(
    const float* __restrict__ x, const float* __restrict__ masks,
    float* __restrict__ outp)
{
    int idx = blockIdx.x*256 + threadIdx.x;
    if (idx >= NB*NHALF*NT) return;
    int t = idx & (NT-1);
    int r = idx >> 11;
    int c = r % NHALF;
    int b = r / NHALF;
    float v = x[((size_t)b*NC + c)*NT + t] * masks[(size_t)b*NT + t];
    outp[((size_t)b*NC + (NC-1 - c))*NT + t] = v;
}

// ---------- fused proj GEMM (padded 3072x192, swizzled) + RQ spline + lad ----------
// grid (16 t-tiles, 16 m-blocks(=6c each), 16 units(b,th)), block 256
__global__ __launch_bounds__(256) void proj_spline_mfma_kernel(
    const float* __restrict__ hidT, const u16* __restrict__ wpad,
    const float* __restrict__ pjb_pad, const float* __restrict__ x,
    const float* __restrict__ masks, float* __restrict__ outp,
    float* __restrict__ partial)
{
    __shared__ float uls[192*PS];   // union: staging (first 6400 u32) then P [192][PS]
    __shared__ float red[256];
    u32* sm = (u32*)uls;
    const int tid  = threadIdx.x;
    const int lane = tid & 63;
    const int wid  = tid >> 6;
    const int owave = wid & 1, twave = wid >> 1;
    const int z  = blockIdx.z;
    const int b  = z >> 1, th = z & 1;
    const int tg0 = th*1024 + blockIdx.x*64;

    // stage B tile: 64 t-rows x 192 k, masked, bf16-pairs
    for (int idx = tid; idx < 64*96; idx += 256) {
        int row = idx / 96, kp = idx - row*96;
        int t = tg0 + row;
        const float* p = hidT + ((size_t)b*NT + t)*NC + 2*kp;
        float mv = masks[(size_t)b*NT + t];
        sm[row*KP + kp] = (u32)f2bf(p[0]*mv) | ((u32)f2bf(p[1]*mv) << 16);
    }
    __syncthreads();

    f32x4 acc[6][2];
    #pragma unroll
    for (int i = 0; i < 6; ++i) {
        acc[i][0] = f32x4{0.f,0.f,0.f,0.f};
        acc[i][1] = f32x4{0.f,0.f,0.f,0.f};
    }
    const int l15 = lane & 15;
    const int kg  = lane >> 4;
    const char* smb = (const char*)sm;

    for (int kk = 0; kk < 6; ++kk) {
        int k0 = kk*32 + kg*8;
        bf16x8 b0 = *(const bf16x8*)(smb + (size_t)(twave*32 + l15)*400 + k0*2);
        bf16x8 b1 = *(const bf16x8*)(smb + (size_t)(twave*32 + l15 + 16)*400 + k0*2);
        bf16x8 af[6];
        #pragma unroll
        for (int ot = 0; ot < 6; ++ot) {
            int mt = blockIdx.y*12 + owave*6 + ot;
            af[ot] = *(const bf16x8*)(wpad + ((size_t)(mt*6 + kk))*512 + lane*8);
        }
        #pragma unroll
        for (int ot = 0; ot < 6; ++ot) {
            acc[ot][0] = __builtin_amdgcn_mfma_f32_16x16x32_bf16(af[ot], b0, acc[ot][0], 0, 0, 0);
            acc[ot][1] = __builtin_amdgcn_mfma_f32_16x16x32_bf16(af[ot], b1, acc[ot][1], 0, 0, 0);
        }
    }
    __syncthreads();   // staging dead; reuse LDS as P

    // P[m_local][t_local] = (acc + pjb_pad) * mask, fp32, stride PS
    #pragma unroll
    for (int ot = 0; ot < 6; ++ot) {
        int o4 = owave*96 + ot*16 + (kg << 2);
        f32x4 pb = *(const f32x4*)(pjb_pad + blockIdx.y*192 + o4);
        #pragma unroll
        for (int t2 = 0; t2 < 2; ++t2) {
            int tl = twave*32 + t2*16 + l15;
            float mkv = masks[(size_t)b*NT + tg0 + tl];
            f32x4 A = acc[ot][t2];
            #pragma unroll
            for (int r = 0; r < 4; ++r)
                uls[(o4 + r)*PS + tl] = (A[r] + pb[r]) * mkv;
        }
    }
    __syncthreads();

    // spline: 6 c-channels x 64 t per block
    float lsum = 0.f;
    for (int idx = tid; idx < 384; idx += 256) {
        int cl = idx >> 6, t = idx & 63;
        int c  = blockIdx.y*6 + cl;
        int tg = tg0 + t;
        float m = masks[(size_t)b*NT + tg];

        float pr[NP];
        #pragma unroll
        for (int p = 0; p < NP; ++p)
            pr[p] = uls[(cl*32 + p)*PS + t];

        const float invsq = 0.07216878364870322f;  // 1/sqrt(192)
        float cw[11], chh[11];
        {   // width knots
            float u[10], e[10];
            #pragma unroll
            for (int i = 0; i < 10; ++i) u[i] = pr[i] * invsq;
            float mx = u[0];
            #pragma unroll
            for (int i = 1; i < 10; ++i) mx = fmaxf(mx, u[i]);
            float s = 0.f;
            #pragma unroll
            for (int i = 0; i < 10; ++i) { e[i] = __expf(u[i]-mx); s += e[i]; }
            float inv_s = 1.f / s;
            float run = 0.f;
            cw[0] = -5.f;
            #pragma unroll
            for (int i = 0; i < 10; ++i) {
                run += 0.001f + 0.99f * e[i] * inv_s;
                cw[i+1] = 10.f*run - 5.f;
            }
            cw[10] = 5.f;
        }
        {   // height knots
            float u[10], e[10];
            #pragma unroll
            for (int i = 0; i < 10; ++i) u[i] = pr[10+i] * invsq;
            float mx = u[0];
            #pragma unroll
            for (int i = 1; i < 10; ++i) mx = fmaxf(mx, u[i]);
            float s = 0.f;
            #pragma unroll
            for (int i = 0; i < 10; ++i) { e[i] = __expf(u[i]-mx); s += e[i]; }
            float inv_s = 1.f / s;
            float run = 0.f;
            chh[0] = -5.f;
            #pragma unroll
            for (int i = 0; i < 10; ++i) {
                run += 0.001f + 0.99f * e[i] * inv_s;
                chh[i+1] = 10.f*run - 5.f;
            }
            chh[10] = 5.f;
        }

        float x1 = x[((size_t)b*NC + NHALF + c)*NT + tg];
        float xc = fminf(fmaxf(x1, -5.f), 5.f);
        int cnt = 0;
        #pragma unroll
        for (int i = 0; i < 11; ++i) cnt += (xc >= cw[i]) ? 1 : 0;
        int kidx = cnt - 1;
        kidx = kidx < 0 ? 0 : (kidx > 9 ? 9 : kidx);

        // static-index selection (registers only)
        float icw=0.f, iw=1.f, ich=0.f, ih=0.f, s0=0.f, s1=0.f;
        #pragma unroll
        for (int i = 0; i < 10; ++i) {
            if (i == kidx) {
                icw = cw[i]; iw = cw[i+1]-cw[i];
                ich = chh[i]; ih = chh[i+1]-chh[i];
                s0 = (i >= 1) ? pr[19+i] : 0.f;
                s1 = (i <= 8) ? pr[20+i] : 0.f;
            }
        }
        // derivatives: endpoints exactly 1 (md + softplus(const) = 1); interior 0.001+softplus
        float d0 = (kidx == 0) ? 1.f : 0.001f + softplus_fast(s0);
        float d1 = (kidx == 9) ? 1.f : 0.001f + softplus_fast(s1);

        float rw    = 1.0f / iw;
        float dlt   = ih * rw;
        float theta = (xc - icw) * rw;
        float t1m   = theta * (1.f - theta);
        float den   = dlt + (d0 + d1 - 2.f*dlt) * t1m;
        float rden  = 1.0f / den;
        float num   = ih * (dlt*theta*theta + d0*t1m);
        float outv  = ich + num * rden;
        float omt   = 1.f - theta;
        float dnum  = dlt*dlt*(d1*theta*theta + 2.f*dlt*t1m + d0*omt*omt);
        float lad   = __logf(dnum * rden * rden);
        bool inside = (x1 >= -5.f) && (x1 <= 5.f);
        float xout  = inside ? outv : x1;
        float ladv  = inside ? lad : 0.f;
        outp[((size_t)b*NC + (NHALF-1 - c))*NT + tg] = xout * m;
        lsum += ladv * m;
    }

    red[tid] = lsum;
    __syncthreads();
    for (int s2 = 128; s2 > 0; s2 >>= 1) {
        if (tid < s2) red[tid] += red[tid + s2];
        __syncthreads();
    }
    if (tid == 0)
        partial[(size_t)b*512 + th*256 + blockIdx.y*16 + blockIdx.x] = red[0];
}

__global__ __launch_bounds__(256) void logdet_reduce_kernel(
    const float* __restrict__ partial, float* __restrict__ outp)
{
    __shared__ float red[256];
    const int b = blockIdx.x;
    const int tid = threadIdx.x;
    float s = 0.f;
    for (int i = tid; i < 512; i += 256) s += partial[(size_t)b*512 + i];
    red[tid] = s;
    __syncthreads();
    for (int st = 128; st > 0; st >>= 1) {
        if (tid < st) red[tid] += red[tid + st];
        __syncthreads();
    }
    if (tid == 0) outp[(size_t)OUT_ELEMS + b] = red[0];
}

extern "C" void kernel_launch(void* const* d_in, const int* in_sizes, int n_in,
                              void* d_out, int out_size, void* d_ws, size_t ws_size,
                              hipStream_t stream) {
    const float* x     = (const float*)d_in[0];
    const float* cond  = (const float*)d_in[1];
    const float* masks = (const float*)d_in[2];
    const float* pw    = (const float*)d_in[3];
    const float* pb    = (const float*)d_in[4];
    const float* w1    = (const float*)d_in[5];
    const float* b1    = (const float*)d_in[6];
    const float* g1    = (const float*)d_in[7];
    const float* bb1   = (const float*)d_in[8];
    const float* m1    = (const float*)d_in[9];
    const float* v1    = (const float*)d_in[10];
    const float* w2    = (const float*)d_in[11];
    const float* b2    = (const float*)d_in[12];
    const float* g2    = (const float*)d_in[13];
    const float* bb2   = (const float*)d_in[14];
    const float* m2    = (const float*)d_in[15];
    const float* v2    = (const float*)d_in[16];
    const float* pjw   = (const float*)d_in[17];
    const float* pjb   = (const float*)d_in[18];

    float* out = (float*)d_out;
    char* wsb = (char*)d_ws;
    // ws: [hidT fp32 12.58MB][wbf bf16 2.10MB][pjb_pad 12KB][partial 16KB]
    float* hidT    = (float*)wsb;
    u16*   wbf     = (u16*)(wsb + 12582912);
    float* pjb_pad = (float*)(wsb + 12582912 + 2101248);
    float* partial = (float*)(wsb + 12582912 + 2101248 + 12288);

    dim3 blk(256);

    wconv_kernel<<<dim3((WT2 + 3072 + 255)/256), blk, 0, stream>>>(
        w1, w2, pjw, pjb, pw, wbf, pjb_pad);

    const u16* preswz = wbf + W1N + W2N + PADN;
    prenet_mfma_kernel<<<dim3(64,1,8), blk, 0, stream>>>(x, cond, preswz, pb, hidT);

    dim3 grid_r(64, 1, 8);
    for (int l = 0; l < 3; ++l) {
        const u16* w1l = wbf + (size_t)l*110592;
        const u16* w2l = wbf + W1N + (size_t)l*36864;
        if (l == 0)
            resblock_kernel<1><<<grid_r, blk, 0, stream>>>(hidT, w1l, w2l, masks,
                b1+l*NC, g1+l*NC, bb1+l*NC, m1+l*NC, v1+l*NC,
                b2+l*NC, g2+l*NC, bb2+l*NC, m2+l*NC, v2+l*NC);
        else if (l == 1)
            resblock_kernel<3><<<grid_r, blk, 0, stream>>>(hidT, w1l, w2l, masks,
                b1+l*NC, g1+l*NC, bb1+l*NC, m1+l*NC, v1+l*NC,
                b2+l*NC, g2+l*NC, bb2+l*NC, m2+l*NC, v2+l*NC);
        else
            resblock_kernel<9><<<grid_r, blk, 0, stream>>>(hidT, w1l, w2l, masks,
                b1+l*NC, g1+l*NC, bb1+l*NC, m1+l*NC, v1+l*NC,
                b2+l*NC, g2+l*NC, bb2+l*NC, m2+l*NC, v2+l*NC);
    }

    copy_flip_kernel<<<dim3((NB*NHALF*NT + 255)/256), blk, 0, stream>>>(x, masks, out);

    const u16* pjwpad = wbf + W1N + W2N;
    proj_spline_mfma_kernel<<<dim3(16,16,16), blk, 0, stream>>>(
        hidT, pjwpad, pjb_pad, x, masks, out, partial);

    logdet_reduce_kernel<<<dim3(8), blk, 0, stream>>>(partial, out);
}

// Round 12
// 141.579 us; speedup vs baseline: 6.6386x; 1.1494x over previous
//
#include <hip/hip_runtime.h>
#include <math.h>

#define NB 8
#define NC 192
#define NT 2048
#define NHALF 96
#define NP 29
#define OUT_ELEMS (NB*NC*NT)
#define KP 100    // staging LDS row stride in dwords (200 bf16, 192 used)
#define PR 129    // P LDS row stride in dwords ([t][m] bf16, 256 m + pad)

typedef short bf16x8 __attribute__((ext_vector_type(8)));
typedef float f32x4 __attribute__((ext_vector_type(4)));
typedef unsigned int u32x2 __attribute__((ext_vector_type(2)));
typedef unsigned short u16;
typedef unsigned int u32;

__device__ __forceinline__ u16 f2bf(float f) {
    u32 u = __builtin_bit_cast(u32, f);
    u += 0x7fffu + ((u >> 16) & 1u);
    return (u16)(u >> 16);
}
__device__ __forceinline__ float softplus_fast(float v) {
    return (v > 20.0f) ? v : __logf(1.0f + __expf(v));
}
// mish(x) = x*tanh(softplus(x)) = x*(s^2-1)/(s^2+1), s = 1+e^x
__device__ __forceinline__ float mishf(float v) {
    if (v > 20.0f) return v;
    float s = 1.0f + __expf(v);
    float s2 = s * s;
    return v * (s2 - 1.0f) / (s2 + 1.0f);
}

// ---------- weight convert + fragment swizzle ----------
// swz[tile*512 + lane*8 + e] = W[m][k], m = mt*16+(lane&15), k = kk*32+(lane>>4)*8+e
#define W1N 331776   // 3*3*36864
#define W2N 110592   // 3*36864
#define PADN 589824  // 1152*512
#define PREN 18432   // 36*512
#define WT2 (W1N+W2N+PADN+PREN)
__global__ __launch_bounds__(256) void wconv_kernel(
    const float* __restrict__ w1, const float* __restrict__ w2,
    const float* __restrict__ pjw, const float* __restrict__ pjb,
    const float* __restrict__ pw,
    u16* __restrict__ outw, float* __restrict__ pjb_pad)
{
    int i = blockIdx.x*256 + threadIdx.x;
    if (i < WT2) {
        float v;
        if (i < W1N) {
            int s = i / 110592, r = i % 110592;
            int j = r / 36864, q = r % 36864;
            int tile = q >> 9, lane = (q >> 3) & 63, e = q & 7;
            int mt = tile / 6, kk = tile % 6;
            int m = mt*16 + (lane & 15);
            int k = kk*32 + (lane >> 4)*8 + e;
            v = w1[(((size_t)s*192 + m)*192 + k)*3 + j];
        } else if (i < W1N + W2N) {
            int q0 = i - W1N;
            int s = q0 / 36864, q = q0 % 36864;
            int tile = q >> 9, lane = (q >> 3) & 63, e = q & 7;
            int mt = tile / 6, kk = tile % 6;
            int m = mt*16 + (lane & 15);
            int k = kk*32 + (lane >> 4)*8 + e;
            v = w2[((size_t)s*192 + m)*192 + k];
        } else if (i < W1N + W2N + PADN) {
            int q = i - W1N - W2N;
            int tile = q >> 9, lane = (q >> 3) & 63, e = q & 7;
            int mt = tile / 6, kk = tile % 6;
            int m = mt*16 + (lane & 15);            // 0..3071
            int k = kk*32 + (lane >> 4)*8 + e;
            int c = m >> 5, p = m & 31;
            v = (p < NP) ? pjw[((size_t)(c*NP + p))*192 + k] : 0.f;
        } else {
            int q = i - W1N - W2N - PADN;
            int tile = q >> 9, lane = (q >> 3) & 63, e = q & 7;
            int mt = tile / 3, kk = tile % 3;
            int m = mt*16 + (lane & 15);            // 0..191
            int k = kk*32 + (lane >> 4)*8 + e;      // 0..95
            v = pw[(size_t)m*96 + k];
        }
        outw[i] = f2bf(v);
    } else if (i < WT2 + 3072) {
        int mp = i - WT2;
        int c = mp >> 5, p = mp & 31;
        pjb_pad[mp] = (p < NP) ? pjb[c*NP + p] : 0.f;
    }
}

// ---------- prenet MFMA: hidT[t][o] = W(192x96) x0 + bias + cond ----------
__global__ __launch_bounds__(256) void prenet_mfma_kernel(
    const float* __restrict__ x, const float* __restrict__ cond,
    const u16* __restrict__ wps, const float* __restrict__ bias,
    float* __restrict__ hidT)
{
    __shared__ u32 sm[32 * 52];
    const int tid = threadIdx.x, lane = tid & 63, wid = tid >> 6;
    const int b = blockIdx.z, tg0 = blockIdx.x * 32;
    const int l15 = lane & 15, kg = lane >> 4;

    for (int idx = tid; idx < 48*32; idx += 256) {
        int c2 = idx >> 5, tl = idx & 31;
        const float* p = x + ((size_t)b*NC + 2*c2)*NT + tg0 + tl;
        sm[tl*52 + c2] = (u32)f2bf(p[0]) | ((u32)f2bf(p[NT]) << 16);
    }
    __syncthreads();

    f32x4 acc[3][2];
    #pragma unroll
    for (int i = 0; i < 3; ++i) { acc[i][0] = f32x4{0,0,0,0}; acc[i][1] = f32x4{0,0,0,0}; }
    const char* smb = (const char*)sm;

    for (int kk = 0; kk < 3; ++kk) {
        int k0 = kk*32 + kg*8;
        bf16x8 b0 = *(const bf16x8*)(smb + (size_t)l15*208 + k0*2);
        bf16x8 b1f = *(const bf16x8*)(smb + (size_t)(l15+16)*208 + k0*2);
        bf16x8 af[3];
        #pragma unroll
        for (int ot = 0; ot < 3; ++ot) {
            int mt = wid*3 + ot;
            af[ot] = *(const bf16x8*)(wps + ((size_t)(mt*3 + kk))*512 + lane*8);
        }
        #pragma unroll
        for (int ot = 0; ot < 3; ++ot) {
            acc[ot][0] = __builtin_amdgcn_mfma_f32_16x16x32_bf16(af[ot], b0, acc[ot][0], 0, 0, 0);
            acc[ot][1] = __builtin_amdgcn_mfma_f32_16x16x32_bf16(af[ot], b1f, acc[ot][1], 0, 0, 0);
        }
    }

    #pragma unroll
    for (int ot = 0; ot < 3; ++ot) {
        int m = (wid*3 + ot)*16 + (kg << 2);
        f32x4 bi = *(const f32x4*)(bias + m);
        #pragma unroll
        for (int tt = 0; tt < 2; ++tt) {
            int t = tg0 + tt*16 + l15;
            f32x4 A = acc[ot][tt];
            f32x4 o;
            #pragma unroll
            for (int r = 0; r < 4; ++r)
                o[r] = A[r] + bi[r] + cond[((size_t)b*NC + m + r)*NT + t];
            *(f32x4*)(hidT + ((size_t)b*NT + t)*NC + m) = o;
        }
    }
}

// ---------- fused residual block ----------
template<int DIL>
__global__ __launch_bounds__(256) void resblock_kernel(
    float* __restrict__ hidT, const u16* __restrict__ w1s, const u16* __restrict__ w2s,
    const float* __restrict__ masks,
    const float* __restrict__ b1v, const float* __restrict__ g1v, const float* __restrict__ bb1v,
    const float* __restrict__ bm1v, const float* __restrict__ bv1v,
    const float* __restrict__ b2v, const float* __restrict__ g2v, const float* __restrict__ bb2v,
    const float* __restrict__ bm2v, const float* __restrict__ bv2v)
{
    constexpr int ROWS = 32 + 2*DIL;
    __shared__ u32 sm1[ROWS * KP];
    __shared__ u32 sm2[32 * KP];
    const int tid = threadIdx.x, lane = tid & 63, wid = tid >> 6;
    const int b = blockIdx.z, tg0 = blockIdx.x * 32;
    const int l15 = lane & 15, kg = lane >> 4;

    // stage hid tile, masked, bf16 pairs [t-row][k] -- vectorized f32x4
    for (int it = tid; it < ROWS*48; it += 256) {
        int row = it / 48, kq = it - row*48;
        int t = tg0 + row - DIL;
        u32 lo = 0, hi = 0;
        if (t >= 0 && t < NT) {
            f32x4 v = *(const f32x4*)(hidT + ((size_t)b*NT + t)*NC + kq*4);
            float mv = masks[(size_t)b*NT + t];
            lo = (u32)f2bf(v[0]*mv) | ((u32)f2bf(v[1]*mv) << 16);
            hi = (u32)f2bf(v[2]*mv) | ((u32)f2bf(v[3]*mv) << 16);
        }
        *(u32x2*)(&sm1[row*KP + kq*2]) = u32x2{lo, hi};
    }
    __syncthreads();

    // GEMM1: 192m x 32t x 192k x 3 taps
    f32x4 acc[3][2];
    #pragma unroll
    for (int i = 0; i < 3; ++i) { acc[i][0] = f32x4{0,0,0,0}; acc[i][1] = f32x4{0,0,0,0}; }
    const char* smb1 = (const char*)sm1;

    for (int j = 0; j < 3; ++j) {
        const u16* wsl = w1s + (size_t)j * 36864;
        for (int kk = 0; kk < 6; ++kk) {
            int k0 = kk*32 + kg*8;
            bf16x8 b0  = *(const bf16x8*)(smb1 + (size_t)(l15 + j*DIL)*400 + k0*2);
            bf16x8 b1f = *(const bf16x8*)(smb1 + (size_t)(l15 + 16 + j*DIL)*400 + k0*2);
            bf16x8 af[3];
            #pragma unroll
            for (int ot = 0; ot < 3; ++ot) {
                int mt = wid*3 + ot;
                af[ot] = *(const bf16x8*)(wsl + ((size_t)(mt*6 + kk))*512 + lane*8);
            }
            #pragma unroll
            for (int ot = 0; ot < 3; ++ot) {
                acc[ot][0] = __builtin_amdgcn_mfma_f32_16x16x32_bf16(af[ot], b0,  acc[ot][0], 0, 0, 0);
                acc[ot][1] = __builtin_amdgcn_mfma_f32_16x16x32_bf16(af[ot], b1f, acc[ot][1], 0, 0, 0);
            }
        }
    }

    // epilogue1: tmp = BN1(mish(acc+b1)) -> sm2 [t][k] bf16 pairs
    #pragma unroll
    for (int ot = 0; ot < 3; ++ot) {
        int m = (wid*3 + ot)*16 + (kg << 2);
        f32x4 bi = *(const f32x4*)(b1v + m);
        f32x4 g4 = *(const f32x4*)(g1v + m);
        f32x4 bb4 = *(const f32x4*)(bb1v + m);
        f32x4 bm4 = *(const f32x4*)(bm1v + m);
        f32x4 bv4 = *(const f32x4*)(bv1v + m);
        #pragma unroll
        for (int tt = 0; tt < 2; ++tt) {
            int tl = tt*16 + l15;
            f32x4 A = acc[ot][tt];
            float vr[4];
            #pragma unroll
            for (int r = 0; r < 4; ++r) {
                float v = mishf(A[r] + bi[r]);
                vr[r] = (v - bm4[r]) * (g4[r] * rsqrtf(bv4[r] + 1e-5f)) + bb4[r];
            }
            u32 lo = (u32)f2bf(vr[0]) | ((u32)f2bf(vr[1]) << 16);
            u32 hi = (u32)f2bf(vr[2]) | ((u32)f2bf(vr[3]) << 16);
            *(u32x2*)(&sm2[tl*KP + (m >> 1)]) = u32x2{lo, hi};
        }
    }
    __syncthreads();

    // GEMM2: 192m x 32t x 192k from sm2
    f32x4 acc2[3][2];
    #pragma unroll
    for (int i = 0; i < 3; ++i) { acc2[i][0] = f32x4{0,0,0,0}; acc2[i][1] = f32x4{0,0,0,0}; }
    const char* smb2 = (const char*)sm2;

    for (int kk = 0; kk < 6; ++kk) {
        int k0 = kk*32 + kg*8;
        bf16x8 b0  = *(const bf16x8*)(smb2 + (size_t)l15*400 + k0*2);
        bf16x8 b1f = *(const bf16x8*)(smb2 + (size_t)(l15+16)*400 + k0*2);
        bf16x8 af[3];
        #pragma unroll
        for (int ot = 0; ot < 3; ++ot) {
            int mt = wid*3 + ot;
            af[ot] = *(const bf16x8*)(w2s + ((size_t)(mt*6 + kk))*512 + lane*8);
        }
        #pragma unroll
        for (int ot = 0; ot < 3; ++ot) {
            acc2[ot][0] = __builtin_amdgcn_mfma_f32_16x16x32_bf16(af[ot], b0,  acc2[ot][0], 0, 0, 0);
            acc2[ot][1] = __builtin_amdgcn_mfma_f32_16x16x32_bf16(af[ot], b1f, acc2[ot][1], 0, 0, 0);
        }
    }

    // epilogue2: hidT += BN2(mish(acc2+b2))
    #pragma unroll
    for (int ot = 0; ot < 3; ++ot) {
        int m = (wid*3 + ot)*16 + (kg << 2);
        f32x4 bi = *(const f32x4*)(b2v + m);
        f32x4 g4 = *(const f32x4*)(g2v + m);
        f32x4 bb4 = *(const f32x4*)(bb2v + m);
        f32x4 bm4 = *(const f32x4*)(bm2v + m);
        f32x4 bv4 = *(const f32x4*)(bv2v + m);
        #pragma unroll
        for (int tt = 0; tt < 2; ++tt) {
            int t = tg0 + tt*16 + l15;
            f32x4 A = acc2[ot][tt];
            float* dst = hidT + ((size_t)b*NT + t)*NC + m;
            f32x4 old = *(const f32x4*)dst;
            f32x4 nv;
            #pragma unroll
            for (int r = 0; r < 4; ++r) {
                float v = mishf(A[r] + bi[r]);
                nv[r] = old[r] + ((v - bm4[r]) * (g4[r] * rsqrtf(bv4[r] + 1e-5f)) + bb4[r]);
            }
            *(f32x4*)dst = nv;
        }
    }
}

// ---------- fused proj GEMM (M=256/block) + RQ spline + x0-flip + lad ----------
// grid (16 t-tiles, 12 m-blocks(=8c each), 16 units(b,th)), block 256
__global__ __launch_bounds__(256) void proj_spline_mfma_kernel(
    const float* __restrict__ hidT, const u16* __restrict__ wpad,
    const float* __restrict__ pjb_pad, const float* __restrict__ x,
    const float* __restrict__ masks, float* __restrict__ outp,
    float* __restrict__ partial)
{
    __shared__ u32 uls[64*PR];   // union: staging [64][KP] then P [64 t][258 u16]
    __shared__ float red[256];
    const int tid  = threadIdx.x;
    const int lane = tid & 63;
    const int wid  = tid >> 6;
    const int z  = blockIdx.z;
    const int b  = z >> 1, th = z & 1;
    const int tg0 = th*1024 + blockIdx.x*64;
    const int l15 = lane & 15;
    const int kg  = lane >> 4;

    // ---- stage B tile: 64 t-rows x 192 k, masked, vectorized ----
    for (int it = tid; it < 64*48; it += 256) {
        int row = it / 48, kq = it - row*48;
        int t = tg0 + row;
        f32x4 v = *(const f32x4*)(hidT + ((size_t)b*NT + t)*NC + kq*4);
        float mv = masks[(size_t)b*NT + t];
        u32 lo = (u32)f2bf(v[0]*mv) | ((u32)f2bf(v[1]*mv) << 16);
        u32 hi = (u32)f2bf(v[2]*mv) | ((u32)f2bf(v[3]*mv) << 16);
        *(u32x2*)(&uls[row*KP + kq*2]) = u32x2{lo, hi};
    }
    __syncthreads();

    // ---- GEMM: 256 m x 64 t x 192 k.  4 waves along m (4 mt each), t=64 per wave ----
    f32x4 acc[4][4];   // [ot][tt]
    #pragma unroll
    for (int i = 0; i < 4; ++i)
        #pragma unroll
        for (int j2 = 0; j2 < 4; ++j2) acc[i][j2] = f32x4{0,0,0,0};
    const char* smb = (const char*)uls;
    const int mtb = blockIdx.y*16 + wid*4;

    for (int kk = 0; kk < 6; ++kk) {
        int k0 = kk*32 + kg*8;
        bf16x8 bt[4];
        #pragma unroll
        for (int tt = 0; tt < 4; ++tt)
            bt[tt] = *(const bf16x8*)(smb + (size_t)(tt*16 + l15)*400 + k0*2);
        bf16x8 af[4];
        #pragma unroll
        for (int ot = 0; ot < 4; ++ot)
            af[ot] = *(const bf16x8*)(wpad + ((size_t)((mtb + ot)*6 + kk))*512 + lane*8);
        #pragma unroll
        for (int ot = 0; ot < 4; ++ot)
            #pragma unroll
            for (int tt = 0; tt < 4; ++tt)
                acc[ot][tt] = __builtin_amdgcn_mfma_f32_16x16x32_bf16(af[ot], bt[tt], acc[ot][tt], 0, 0, 0);
    }
    __syncthreads();   // staging dead; reuse LDS as P [t][m] bf16

    // ---- P[t][mloc] = bf16((acc + pjb)*mask), vector u32x2 stores ----
    #pragma unroll
    for (int tt = 0; tt < 4; ++tt) {
        int t = tt*16 + l15;
        float mkv = masks[(size_t)b*NT + tg0 + t];
        #pragma unroll
        for (int ot = 0; ot < 4; ++ot) {
            int mloc = (wid*4 + ot)*16 + (kg << 2);
            f32x4 pb = *(const f32x4*)(pjb_pad + blockIdx.y*256 + mloc);
            f32x4 A = acc[ot][tt];
            u32 lo = (u32)f2bf((A[0]+pb[0])*mkv) | ((u32)f2bf((A[1]+pb[1])*mkv) << 16);
            u32 hi = (u32)f2bf((A[2]+pb[2])*mkv) | ((u32)f2bf((A[3]+pb[3])*mkv) << 16);
            *(u32x2*)(&uls[t*PR + (mloc >> 1)]) = u32x2{lo, hi};
        }
    }
    __syncthreads();

    // ---- spline: 8 c-channels x 64 t = 512 items, exactly 2 per thread ----
    float lsum = 0.f;
    #pragma unroll
    for (int rep = 0; rep < 2; ++rep) {
        int item = tid + rep*256;
        int cl = item >> 6, t = item & 63;
        int c  = blockIdx.y*8 + cl;
        int tg = tg0 + t;
        float m = masks[(size_t)b*NT + tg];

        // x0 flip copy (each (c,tg) covered exactly once across the grid)
        float x0v = x[((size_t)b*NC + c)*NT + tg];
        outp[((size_t)b*NC + (NC-1 - c))*NT + tg] = x0v * m;

        float pr[30];
        #pragma unroll
        for (int j = 0; j < 15; ++j) {
            u32 w = uls[t*PR + cl*16 + j];
            pr[2*j]   = __builtin_bit_cast(float, w << 16);
            pr[2*j+1] = __builtin_bit_cast(float, w & 0xffff0000u);
        }

        const float invsq = 0.07216878364870322f;  // 1/sqrt(192)
        float cw[11], chh[11];
        {   // width knots
            float u[10], e[10];
            #pragma unroll
            for (int i = 0; i < 10; ++i) u[i] = pr[i] * invsq;
            float mx = u[0];
            #pragma unroll
            for (int i = 1; i < 10; ++i) mx = fmaxf(mx, u[i]);
            float s = 0.f;
            #pragma unroll
            for (int i = 0; i < 10; ++i) { e[i] = __expf(u[i]-mx); s += e[i]; }
            float inv_s = 1.f / s;
            float run = 0.f;
            cw[0] = -5.f;
            #pragma unroll
            for (int i = 0; i < 10; ++i) {
                run += 0.001f + 0.99f * e[i] * inv_s;
                cw[i+1] = 10.f*run - 5.f;
            }
            cw[10] = 5.f;
        }
        {   // height knots
            float u[10], e[10];
            #pragma unroll
            for (int i = 0; i < 10; ++i) u[i] = pr[10+i] * invsq;
            float mx = u[0];
            #pragma unroll
            for (int i = 1; i < 10; ++i) mx = fmaxf(mx, u[i]);
            float s = 0.f;
            #pragma unroll
            for (int i = 0; i < 10; ++i) { e[i] = __expf(u[i]-mx); s += e[i]; }
            float inv_s = 1.f / s;
            float run = 0.f;
            chh[0] = -5.f;
            #pragma unroll
            for (int i = 0; i < 10; ++i) {
                run += 0.001f + 0.99f * e[i] * inv_s;
                chh[i+1] = 10.f*run - 5.f;
            }
            chh[10] = 5.f;
        }

        float x1 = x[((size_t)b*NC + NHALF + c)*NT + tg];
        float xc = fminf(fmaxf(x1, -5.f), 5.f);
        int cnt = 0;
        #pragma unroll
        for (int i = 0; i < 11; ++i) cnt += (xc >= cw[i]) ? 1 : 0;
        int kidx = cnt - 1;
        kidx = kidx < 0 ? 0 : (kidx > 9 ? 9 : kidx);

        float icw=0.f, iw=1.f, ich=0.f, ih=0.f, s0=0.f, s1=0.f;
        #pragma unroll
        for (int i = 0; i < 10; ++i) {
            if (i == kidx) {
                icw = cw[i]; iw = cw[i+1]-cw[i];
                ich = chh[i]; ih = chh[i+1]-chh[i];
                s0 = (i >= 1) ? pr[19+i] : 0.f;
                s1 = (i <= 8) ? pr[20+i] : 0.f;
            }
        }
        float d0 = (kidx == 0) ? 1.f : 0.001f + softplus_fast(s0);
        float d1 = (kidx == 9) ? 1.f : 0.001f + softplus_fast(s1);

        float rw    = 1.0f / iw;
        float dlt   = ih * rw;
        float theta = (xc - icw) * rw;
        float t1m   = theta * (1.f - theta);
        float den   = dlt + (d0 + d1 - 2.f*dlt) * t1m;
        float rden  = 1.0f / den;
        float num   = ih * (dlt*theta*theta + d0*t1m);
        float outv  = ich + num * rden;
        float omt   = 1.f - theta;
        float dnum  = dlt*dlt*(d1*theta*theta + 2.f*dlt*t1m + d0*omt*omt);
        float lad   = __logf(dnum * rden * rden);
        bool inside = (x1 >= -5.f) && (x1 <= 5.f);
        float xout  = inside ? outv : x1;
        float ladv  = inside ? lad : 0.f;
        outp[((size_t)b*NC + (NHALF-1 - c))*NT + tg] = xout * m;
        lsum += ladv * m;
    }

    red[tid] = lsum;
    __syncthreads();
    for (int s2 = 128; s2 > 0; s2 >>= 1) {
        if (tid < s2) red[tid] += red[tid + s2];
        __syncthreads();
    }
    if (tid == 0)
        partial[(size_t)b*384 + th*192 + blockIdx.y*16 + blockIdx.x] = red[0];
}

__global__ __launch_bounds__(256) void logdet_reduce_kernel(
    const float* __restrict__ partial, float* __restrict__ outp)
{
    __shared__ float red[256];
    const int b = blockIdx.x;
    const int tid = threadIdx.x;
    float s = 0.f;
    for (int i = tid; i < 384; i += 256) s += partial[(size_t)b*384 + i];
    red[tid] = s;
    __syncthreads();
    for (int st = 128; st > 0; st >>= 1) {
        if (tid < st) red[tid] += red[tid + st];
        __syncthreads();
    }
    if (tid == 0) outp[(size_t)OUT_ELEMS + b] = red[0];
}

extern "C" void kernel_launch(void* const* d_in, const int* in_sizes, int n_in,
                              void* d_out, int out_size, void* d_ws, size_t ws_size,
                              hipStream_t stream) {
    const float* x     = (const float*)d_in[0];
    const float* cond  = (const float*)d_in[1];
    const float* masks = (const float*)d_in[2];
    const float* pw    = (const float*)d_in[3];
    const float* pb    = (const float*)d_in[4];
    const float* w1    = (const float*)d_in[5];
    const float* b1    = (const float*)d_in[6];
    const float* g1    = (const float*)d_in[7];
    const float* bb1   = (const float*)d_in[8];
    const float* m1    = (const float*)d_in[9];
    const float* v1    = (const float*)d_in[10];
    const float* w2    = (const float*)d_in[11];
    const float* b2    = (const float*)d_in[12];
    const float* g2    = (const float*)d_in[13];
    const float* bb2   = (const float*)d_in[14];
    const float* m2    = (const float*)d_in[15];
    const float* v2    = (const float*)d_in[16];
    const float* pjw   = (const float*)d_in[17];
    const float* pjb   = (const float*)d_in[18];

    float* out = (float*)d_out;
    char* wsb = (char*)d_ws;
    float* hidT    = (float*)wsb;
    u16*   wbf     = (u16*)(wsb + 12582912);
    float* pjb_pad = (float*)(wsb + 12582912 + 2101248);
    float* partial = (float*)(wsb + 12582912 + 2101248 + 12288);

    dim3 blk(256);

    wconv_kernel<<<dim3((WT2 + 3072 + 255)/256), blk, 0, stream>>>(
        w1, w2, pjw, pjb, pw, wbf, pjb_pad);

    const u16* preswz = wbf + W1N + W2N + PADN;
    prenet_mfma_kernel<<<dim3(64,1,8), blk, 0, stream>>>(x, cond, preswz, pb, hidT);

    dim3 grid_r(64, 1, 8);
    for (int l = 0; l < 3; ++l) {
        const u16* w1l = wbf + (size_t)l*110592;
        const u16* w2l = wbf + W1N + (size_t)l*36864;
        if (l == 0)
            resblock_kernel<1><<<grid_r, blk, 0, stream>>>(hidT, w1l, w2l, masks,
                b1+l*NC, g1+l*NC, bb1+l*NC, m1+l*NC, v1+l*NC,
                b2+l*NC, g2+l*NC, bb2+l*NC, m2+l*NC, v2+l*NC);
        else if (l == 1)
            resblock_kernel<3><<<grid_r, blk, 0, stream>>>(hidT, w1l, w2l, masks,
                b1+l*NC, g1+l*NC, bb1+l*NC, m1+l*NC, v1+l*NC,
                b2+l*NC, g2+l*NC, bb2+l*NC, m2+l*NC, v2+l*NC);
        else
            resblock_kernel<9><<<grid_r, blk, 0, stream>>>(hidT, w1l, w2l, masks,
                b1+l*NC, g1+l*NC, bb1+l*NC, m1+l*NC, v1+l*NC,
                b2+l*NC, g2+l*NC, bb2+l*NC, m2+l*NC, v2+l*NC);
    }

    const u16* pjwpad = wbf + W1N + W2N;
    proj_spline_mfma_kernel<<<dim3(16,12,16), blk, 0, stream>>>(
        hidT, pjwpad, pjb_pad, x, masks, out, partial);

    logdet_reduce_kernel<<<dim3(8), blk, 0, stream>>>(partial, out);
}

// Round 13
// 132.507 us; speedup vs baseline: 7.0931x; 1.0685x over previous
//
#include <hip/hip_runtime.h>
#include <math.h>

#define NB 8
#define NC 192
#define NT 2048
#define NHALF 96
#define NP 29
#define OUT_ELEMS (NB*NC*NT)
#define KP 100    // staging LDS row stride in dwords (200 bf16, 192 used)
#define PR 129    // P LDS row stride in dwords ([t][m] bf16, 256 m + pad)

typedef short bf16x8 __attribute__((ext_vector_type(8)));
typedef float f32x4 __attribute__((ext_vector_type(4)));
typedef unsigned int u32x2 __attribute__((ext_vector_type(2)));
typedef unsigned short u16;
typedef unsigned int u32;

__device__ __forceinline__ u16 f2bf(float f) {
    u32 u = __builtin_bit_cast(u32, f);
    u += 0x7fffu + ((u >> 16) & 1u);
    return (u16)(u >> 16);
}
// packed f32 pair -> 2x bf16 in one instruction (RNE, same as f2bf)
__device__ __forceinline__ u32 pk_bf16(float lo, float hi) {
    u32 r;
    asm("v_cvt_pk_bf16_f32 %0, %1, %2" : "=v"(r) : "v"(lo), "v"(hi));
    return r;
}
__device__ __forceinline__ float softplus_fast(float v) {
    return (v > 20.0f) ? v : __logf(1.0f + __expf(v));
}
// mish(x) = x*tanh(softplus(x)) = x*(s^2-1)/(s^2+1), s = 1+e^x
__device__ __forceinline__ float mishf(float v) {
    if (v > 20.0f) return v;
    float s = 1.0f + __expf(v);
    float s2 = s * s;
    return v * (s2 - 1.0f) / (s2 + 1.0f);
}

// ---------- weight convert + fragment swizzle ----------
// swz[tile*512 + lane*8 + e] = W[m][k], m = mt*16+(lane&15), k = kk*32+(lane>>4)*8+e
#define W1N 331776   // 3*3*36864
#define W2N 110592   // 3*36864
#define PADN 589824  // 1152*512
#define PREN 18432   // 36*512
#define WT2 (W1N+W2N+PADN+PREN)
__global__ __launch_bounds__(256) void wconv_kernel(
    const float* __restrict__ w1, const float* __restrict__ w2,
    const float* __restrict__ pjw, const float* __restrict__ pjb,
    const float* __restrict__ pw,
    u16* __restrict__ outw, float* __restrict__ pjb_pad)
{
    int i = blockIdx.x*256 + threadIdx.x;
    if (i < WT2) {
        float v;
        if (i < W1N) {
            int s = i / 110592, r = i % 110592;
            int j = r / 36864, q = r % 36864;
            int tile = q >> 9, lane = (q >> 3) & 63, e = q & 7;
            int mt = tile / 6, kk = tile % 6;
            int m = mt*16 + (lane & 15);
            int k = kk*32 + (lane >> 4)*8 + e;
            v = w1[(((size_t)s*192 + m)*192 + k)*3 + j];
        } else if (i < W1N + W2N) {
            int q0 = i - W1N;
            int s = q0 / 36864, q = q0 % 36864;
            int tile = q >> 9, lane = (q >> 3) & 63, e = q & 7;
            int mt = tile / 6, kk = tile % 6;
            int m = mt*16 + (lane & 15);
            int k = kk*32 + (lane >> 4)*8 + e;
            v = w2[((size_t)s*192 + m)*192 + k];
        } else if (i < W1N + W2N + PADN) {
            int q = i - W1N - W2N;
            int tile = q >> 9, lane = (q >> 3) & 63, e = q & 7;
            int mt = tile / 6, kk = tile % 6;
            int m = mt*16 + (lane & 15);            // 0..3071
            int k = kk*32 + (lane >> 4)*8 + e;
            int c = m >> 5, p = m & 31;
            v = (p < NP) ? pjw[((size_t)(c*NP + p))*192 + k] : 0.f;
        } else {
            int q = i - W1N - W2N - PADN;
            int tile = q >> 9, lane = (q >> 3) & 63, e = q & 7;
            int mt = tile / 3, kk = tile % 3;
            int m = mt*16 + (lane & 15);            // 0..191
            int k = kk*32 + (lane >> 4)*8 + e;      // 0..95
            v = pw[(size_t)m*96 + k];
        }
        outw[i] = f2bf(v);
    } else if (i < WT2 + 3072) {
        int mp = i - WT2;
        int c = mp >> 5, p = mp & 31;
        pjb_pad[mp] = (p < NP) ? pjb[c*NP + p] : 0.f;
    }
}

// ---------- prenet MFMA: hidT[t][o] = W(192x96) x0 + bias + cond ----------
__global__ __launch_bounds__(256) void prenet_mfma_kernel(
    const float* __restrict__ x, const float* __restrict__ cond,
    const u16* __restrict__ wps, const float* __restrict__ bias,
    float* __restrict__ hidT)
{
    __shared__ u32 sm[32 * 52];
    const int tid = threadIdx.x, lane = tid & 63, wid = tid >> 6;
    const int b = blockIdx.z, tg0 = blockIdx.x * 32;
    const int l15 = lane & 15, kg = lane >> 4;

    for (int idx = tid; idx < 48*32; idx += 256) {
        int c2 = idx >> 5, tl = idx & 31;
        const float* p = x + ((size_t)b*NC + 2*c2)*NT + tg0 + tl;
        sm[tl*52 + c2] = pk_bf16(p[0], p[NT]);
    }
    __syncthreads();

    f32x4 acc[3][2];
    #pragma unroll
    for (int i = 0; i < 3; ++i) { acc[i][0] = f32x4{0,0,0,0}; acc[i][1] = f32x4{0,0,0,0}; }
    const char* smb = (const char*)sm;

    for (int kk = 0; kk < 3; ++kk) {
        int k0 = kk*32 + kg*8;
        bf16x8 b0 = *(const bf16x8*)(smb + (size_t)l15*208 + k0*2);
        bf16x8 b1f = *(const bf16x8*)(smb + (size_t)(l15+16)*208 + k0*2);
        bf16x8 af[3];
        #pragma unroll
        for (int ot = 0; ot < 3; ++ot) {
            int mt = wid*3 + ot;
            af[ot] = *(const bf16x8*)(wps + ((size_t)(mt*3 + kk))*512 + lane*8);
        }
        #pragma unroll
        for (int ot = 0; ot < 3; ++ot) {
            acc[ot][0] = __builtin_amdgcn_mfma_f32_16x16x32_bf16(af[ot], b0, acc[ot][0], 0, 0, 0);
            acc[ot][1] = __builtin_amdgcn_mfma_f32_16x16x32_bf16(af[ot], b1f, acc[ot][1], 0, 0, 0);
        }
    }

    #pragma unroll
    for (int ot = 0; ot < 3; ++ot) {
        int m = (wid*3 + ot)*16 + (kg << 2);
        f32x4 bi = *(const f32x4*)(bias + m);
        #pragma unroll
        for (int tt = 0; tt < 2; ++tt) {
            int t = tg0 + tt*16 + l15;
            f32x4 A = acc[ot][tt];
            f32x4 o;
            #pragma unroll
            for (int r = 0; r < 4; ++r)
                o[r] = A[r] + bi[r] + cond[((size_t)b*NC + m + r)*NT + t];
            *(f32x4*)(hidT + ((size_t)b*NT + t)*NC + m) = o;
        }
    }
}

// ---------- fused residual block ----------
template<int DIL>
__global__ __launch_bounds__(256) void resblock_kernel(
    float* __restrict__ hidT, const u16* __restrict__ w1s, const u16* __restrict__ w2s,
    const float* __restrict__ masks,
    const float* __restrict__ b1v, const float* __restrict__ g1v, const float* __restrict__ bb1v,
    const float* __restrict__ bm1v, const float* __restrict__ bv1v,
    const float* __restrict__ b2v, const float* __restrict__ g2v, const float* __restrict__ bb2v,
    const float* __restrict__ bm2v, const float* __restrict__ bv2v)
{
    constexpr int ROWS = 32 + 2*DIL;
    __shared__ u32 sm1[ROWS * KP];
    __shared__ u32 sm2[32 * KP];
    const int tid = threadIdx.x, lane = tid & 63, wid = tid >> 6;
    const int b = blockIdx.z, tg0 = blockIdx.x * 32;
    const int l15 = lane & 15, kg = lane >> 4;

    // stage hid tile, masked, bf16 pairs [t-row][k] -- vectorized f32x4 + cvt_pk
    for (int it = tid; it < ROWS*48; it += 256) {
        int row = it / 48, kq = it - row*48;
        int t = tg0 + row - DIL;
        u32 lo = 0, hi = 0;
        if (t >= 0 && t < NT) {
            f32x4 v = *(const f32x4*)(hidT + ((size_t)b*NT + t)*NC + kq*4);
            float mv = masks[(size_t)b*NT + t];
            lo = pk_bf16(v[0]*mv, v[1]*mv);
            hi = pk_bf16(v[2]*mv, v[3]*mv);
        }
        *(u32x2*)(&sm1[row*KP + kq*2]) = u32x2{lo, hi};
    }
    __syncthreads();

    // GEMM1: 192m x 32t x 192k x 3 taps
    f32x4 acc[3][2];
    #pragma unroll
    for (int i = 0; i < 3; ++i) { acc[i][0] = f32x4{0,0,0,0}; acc[i][1] = f32x4{0,0,0,0}; }
    const char* smb1 = (const char*)sm1;

    for (int j = 0; j < 3; ++j) {
        const u16* wsl = w1s + (size_t)j * 36864;
        for (int kk = 0; kk < 6; ++kk) {
            int k0 = kk*32 + kg*8;
            bf16x8 b0  = *(const bf16x8*)(smb1 + (size_t)(l15 + j*DIL)*400 + k0*2);
            bf16x8 b1f = *(const bf16x8*)(smb1 + (size_t)(l15 + 16 + j*DIL)*400 + k0*2);
            bf16x8 af[3];
            #pragma unroll
            for (int ot = 0; ot < 3; ++ot) {
                int mt = wid*3 + ot;
                af[ot] = *(const bf16x8*)(wsl + ((size_t)(mt*6 + kk))*512 + lane*8);
            }
            #pragma unroll
            for (int ot = 0; ot < 3; ++ot) {
                acc[ot][0] = __builtin_amdgcn_mfma_f32_16x16x32_bf16(af[ot], b0,  acc[ot][0], 0, 0, 0);
                acc[ot][1] = __builtin_amdgcn_mfma_f32_16x16x32_bf16(af[ot], b1f, acc[ot][1], 0, 0, 0);
            }
        }
    }

    // epilogue1: tmp = BN1(mish(acc+b1)) -> sm2 [t][k] bf16 pairs
    #pragma unroll
    for (int ot = 0; ot < 3; ++ot) {
        int m = (wid*3 + ot)*16 + (kg << 2);
        f32x4 bi = *(const f32x4*)(b1v + m);
        f32x4 g4 = *(const f32x4*)(g1v + m);
        f32x4 bb4 = *(const f32x4*)(bb1v + m);
        f32x4 bm4 = *(const f32x4*)(bm1v + m);
        f32x4 bv4 = *(const f32x4*)(bv1v + m);
        #pragma unroll
        for (int tt = 0; tt < 2; ++tt) {
            int tl = tt*16 + l15;
            f32x4 A = acc[ot][tt];
            float vr[4];
            #pragma unroll
            for (int r = 0; r < 4; ++r) {
                float v = mishf(A[r] + bi[r]);
                vr[r] = (v - bm4[r]) * (g4[r] * rsqrtf(bv4[r] + 1e-5f)) + bb4[r];
            }
            *(u32x2*)(&sm2[tl*KP + (m >> 1)]) = u32x2{pk_bf16(vr[0], vr[1]), pk_bf16(vr[2], vr[3])};
        }
    }
    __syncthreads();

    // GEMM2: 192m x 32t x 192k from sm2
    f32x4 acc2[3][2];
    #pragma unroll
    for (int i = 0; i < 3; ++i) { acc2[i][0] = f32x4{0,0,0,0}; acc2[i][1] = f32x4{0,0,0,0}; }
    const char* smb2 = (const char*)sm2;

    for (int kk = 0; kk < 6; ++kk) {
        int k0 = kk*32 + kg*8;
        bf16x8 b0  = *(const bf16x8*)(smb2 + (size_t)l15*400 + k0*2);
        bf16x8 b1f = *(const bf16x8*)(smb2 + (size_t)(l15+16)*400 + k0*2);
        bf16x8 af[3];
        #pragma unroll
        for (int ot = 0; ot < 3; ++ot) {
            int mt = wid*3 + ot;
            af[ot] = *(const bf16x8*)(w2s + ((size_t)(mt*6 + kk))*512 + lane*8);
        }
        #pragma unroll
        for (int ot = 0; ot < 3; ++ot) {
            acc2[ot][0] = __builtin_amdgcn_mfma_f32_16x16x32_bf16(af[ot], b0,  acc2[ot][0], 0, 0, 0);
            acc2[ot][1] = __builtin_amdgcn_mfma_f32_16x16x32_bf16(af[ot], b1f, acc2[ot][1], 0, 0, 0);
        }
    }

    // epilogue2: hidT += BN2(mish(acc2+b2))
    #pragma unroll
    for (int ot = 0; ot < 3; ++ot) {
        int m = (wid*3 + ot)*16 + (kg << 2);
        f32x4 bi = *(const f32x4*)(b2v + m);
        f32x4 g4 = *(const f32x4*)(g2v + m);
        f32x4 bb4 = *(const f32x4*)(bb2v + m);
        f32x4 bm4 = *(const f32x4*)(bm2v + m);
        f32x4 bv4 = *(const f32x4*)(bv2v + m);
        #pragma unroll
        for (int tt = 0; tt < 2; ++tt) {
            int t = tg0 + tt*16 + l15;
            f32x4 A = acc2[ot][tt];
            float* dst = hidT + ((size_t)b*NT + t)*NC + m;
            f32x4 old = *(const f32x4*)dst;
            f32x4 nv;
            #pragma unroll
            for (int r = 0; r < 4; ++r) {
                float v = mishf(A[r] + bi[r]);
                nv[r] = old[r] + ((v - bm4[r]) * (g4[r] * rsqrtf(bv4[r] + 1e-5f)) + bb4[r]);
            }
            *(f32x4*)dst = nv;
        }
    }
}

// ---------- fused proj GEMM (M=256/block) + RQ spline + x0-flip + lad ----------
// grid (16 t-tiles, 12 m-blocks(=8c each), 16 units(b,th)), block 256
__global__ __launch_bounds__(256) void proj_spline_mfma_kernel(
    const float* __restrict__ hidT, const u16* __restrict__ wpad,
    const float* __restrict__ pjb_pad, const float* __restrict__ x,
    const float* __restrict__ masks, float* __restrict__ outp,
    float* __restrict__ partial)
{
    __shared__ u32 uls[64*PR];   // union: staging [64][KP] then P [64 t][258 u16]
    __shared__ float red4[4];
    const int tid  = threadIdx.x;
    const int lane = tid & 63;
    const int wid  = tid >> 6;
    const int z  = blockIdx.z;
    const int b  = z >> 1, th = z & 1;
    const int tg0 = th*1024 + blockIdx.x*64;
    const int l15 = lane & 15;
    const int kg  = lane >> 4;

    // ---- stage B tile: 64 t-rows x 192 k, masked, vectorized + cvt_pk ----
    for (int it = tid; it < 64*48; it += 256) {
        int row = it / 48, kq = it - row*48;
        int t = tg0 + row;
        f32x4 v = *(const f32x4*)(hidT + ((size_t)b*NT + t)*NC + kq*4);
        float mv = masks[(size_t)b*NT + t];
        *(u32x2*)(&uls[row*KP + kq*2]) = u32x2{pk_bf16(v[0]*mv, v[1]*mv), pk_bf16(v[2]*mv, v[3]*mv)};
    }
    __syncthreads();

    // ---- GEMM: 256 m x 64 t x 192 k.  4 waves along m (4 mt each), t=64 per wave ----
    f32x4 acc[4][4];   // [ot][tt]
    #pragma unroll
    for (int i = 0; i < 4; ++i)
        #pragma unroll
        for (int j2 = 0; j2 < 4; ++j2) acc[i][j2] = f32x4{0,0,0,0};
    const char* smb = (const char*)uls;
    const int mtb = blockIdx.y*16 + wid*4;

    for (int kk = 0; kk < 6; ++kk) {
        int k0 = kk*32 + kg*8;
        bf16x8 bt[4];
        #pragma unroll
        for (int tt = 0; tt < 4; ++tt)
            bt[tt] = *(const bf16x8*)(smb + (size_t)(tt*16 + l15)*400 + k0*2);
        bf16x8 af[4];
        #pragma unroll
        for (int ot = 0; ot < 4; ++ot)
            af[ot] = *(const bf16x8*)(wpad + ((size_t)((mtb + ot)*6 + kk))*512 + lane*8);
        #pragma unroll
        for (int ot = 0; ot < 4; ++ot)
            #pragma unroll
            for (int tt = 0; tt < 4; ++tt)
                acc[ot][tt] = __builtin_amdgcn_mfma_f32_16x16x32_bf16(af[ot], bt[tt], acc[ot][tt], 0, 0, 0);
    }
    __syncthreads();   // staging dead; reuse LDS as P [t][m] bf16

    // ---- P[t][mloc] = bf16((acc + pjb)*mask), cvt_pk + u32x2 stores ----
    #pragma unroll
    for (int tt = 0; tt < 4; ++tt) {
        int t = tt*16 + l15;
        float mkv = masks[(size_t)b*NT + tg0 + t];
        #pragma unroll
        for (int ot = 0; ot < 4; ++ot) {
            int mloc = (wid*4 + ot)*16 + (kg << 2);
            f32x4 pb = *(const f32x4*)(pjb_pad + blockIdx.y*256 + mloc);
            f32x4 A = acc[ot][tt];
            *(u32x2*)(&uls[t*PR + (mloc >> 1)]) =
                u32x2{pk_bf16((A[0]+pb[0])*mkv, (A[1]+pb[1])*mkv),
                      pk_bf16((A[2]+pb[2])*mkv, (A[3]+pb[3])*mkv)};
        }
    }
    __syncthreads();

    // ---- spline: 8 c-channels x 64 t = 512 items, exactly 2 per thread ----
    float lsum = 0.f;
    #pragma unroll
    for (int rep = 0; rep < 2; ++rep) {
        int item = tid + rep*256;
        int cl = item >> 6, t = item & 63;
        int c  = blockIdx.y*8 + cl;
        int tg = tg0 + t;
        float m = masks[(size_t)b*NT + tg];

        // x0 flip copy (each (c,tg) covered exactly once across the grid)
        float x0v = x[((size_t)b*NC + c)*NT + tg];
        outp[((size_t)b*NC + (NC-1 - c))*NT + tg] = x0v * m;

        float pr[30];
        #pragma unroll
        for (int j = 0; j < 15; ++j) {
            u32 w = uls[t*PR + cl*16 + j];
            pr[2*j]   = __builtin_bit_cast(float, w << 16);
            pr[2*j+1] = __builtin_bit_cast(float, w & 0xffff0000u);
        }

        const float invsq = 0.07216878364870322f;  // 1/sqrt(192)
        float cw[11], chh[11];
        {   // width knots
            float u[10], e[10];
            #pragma unroll
            for (int i = 0; i < 10; ++i) u[i] = pr[i] * invsq;
            float mx = u[0];
            #pragma unroll
            for (int i = 1; i < 10; ++i) mx = fmaxf(mx, u[i]);
            float s = 0.f;
            #pragma unroll
            for (int i = 0; i < 10; ++i) { e[i] = __expf(u[i]-mx); s += e[i]; }
            float inv_s = __builtin_amdgcn_rcpf(s);
            float run = 0.f;
            cw[0] = -5.f;
            #pragma unroll
            for (int i = 0; i < 10; ++i) {
                run += 0.001f + 0.99f * e[i] * inv_s;
                cw[i+1] = 10.f*run - 5.f;
            }
            cw[10] = 5.f;
        }
        {   // height knots
            float u[10], e[10];
            #pragma unroll
            for (int i = 0; i < 10; ++i) u[i] = pr[10+i] * invsq;
            float mx = u[0];
            #pragma unroll
            for (int i = 1; i < 10; ++i) mx = fmaxf(mx, u[i]);
            float s = 0.f;
            #pragma unroll
            for (int i = 0; i < 10; ++i) { e[i] = __expf(u[i]-mx); s += e[i]; }
            float inv_s = __builtin_amdgcn_rcpf(s);
            float run = 0.f;
            chh[0] = -5.f;
            #pragma unroll
            for (int i = 0; i < 10; ++i) {
                run += 0.001f + 0.99f * e[i] * inv_s;
                chh[i+1] = 10.f*run - 5.f;
            }
            chh[10] = 5.f;
        }

        float x1 = x[((size_t)b*NC + NHALF + c)*NT + tg];
        float xc = fminf(fmaxf(x1, -5.f), 5.f);
        int cnt = 0;
        #pragma unroll
        for (int i = 0; i < 11; ++i) cnt += (xc >= cw[i]) ? 1 : 0;
        int kidx = cnt - 1;
        kidx = kidx < 0 ? 0 : (kidx > 9 ? 9 : kidx);

        float icw=0.f, iw=1.f, ich=0.f, ih=0.f, s0=0.f, s1=0.f;
        #pragma unroll
        for (int i = 0; i < 10; ++i) {
            if (i == kidx) {
                icw = cw[i]; iw = cw[i+1]-cw[i];
                ich = chh[i]; ih = chh[i+1]-chh[i];
                s0 = (i >= 1) ? pr[19+i] : 0.f;
                s1 = (i <= 8) ? pr[20+i] : 0.f;
            }
        }
        float d0 = (kidx == 0) ? 1.f : 0.001f + softplus_fast(s0);
        float d1 = (kidx == 9) ? 1.f : 0.001f + softplus_fast(s1);

        float rw    = __builtin_amdgcn_rcpf(iw);
        float dlt   = ih * rw;
        float theta = (xc - icw) * rw;
        float t1m   = theta * (1.f - theta);
        float den   = dlt + (d0 + d1 - 2.f*dlt) * t1m;
        float rden  = __builtin_amdgcn_rcpf(den);
        float num   = ih * (dlt*theta*theta + d0*t1m);
        float outv  = ich + num * rden;
        float omt   = 1.f - theta;
        float dnum  = dlt*dlt*(d1*theta*theta + 2.f*dlt*t1m + d0*omt*omt);
        float lad   = __logf(dnum * rden * rden);
        bool inside = (x1 >= -5.f) && (x1 <= 5.f);
        float xout  = inside ? outv : x1;
        float ladv  = inside ? lad : 0.f;
        outp[((size_t)b*NC + (NHALF-1 - c))*NT + tg] = xout * m;
        lsum += ladv * m;
    }

    // ---- wave-shuffle reduction, then 4-way cross-wave sum ----
    #pragma unroll
    for (int off = 32; off > 0; off >>= 1)
        lsum += __shfl_down(lsum, off, 64);
    if (lane == 0) red4[wid] = lsum;
    __syncthreads();
    if (tid == 0)
        partial[(size_t)b*384 + th*192 + blockIdx.y*16 + blockIdx.x] =
            red4[0] + red4[1] + red4[2] + red4[3];
}

__global__ __launch_bounds__(256) void logdet_reduce_kernel(
    const float* __restrict__ partial, float* __restrict__ outp)
{
    __shared__ float red[256];
    const int b = blockIdx.x;
    const int tid = threadIdx.x;
    float s = 0.f;
    for (int i = tid; i < 384; i += 256) s += partial[(size_t)b*384 + i];
    red[tid] = s;
    __syncthreads();
    for (int st = 128; st > 0; st >>= 1) {
        if (tid < st) red[tid] += red[tid + st];
        __syncthreads();
    }
    if (tid == 0) outp[(size_t)OUT_ELEMS + b] = red[0];
}

extern "C" void kernel_launch(void* const* d_in, const int* in_sizes, int n_in,
                              void* d_out, int out_size, void* d_ws, size_t ws_size,
                              hipStream_t stream) {
    const float* x     = (const float*)d_in[0];
    const float* cond  = (const float*)d_in[1];
    const float* masks = (const float*)d_in[2];
    const float* pw    = (const float*)d_in[3];
    const float* pb    = (const float*)d_in[4];
    const float* w1    = (const float*)d_in[5];
    const float* b1    = (const float*)d_in[6];
    const float* g1    = (const float*)d_in[7];
    const float* bb1   = (const float*)d_in[8];
    const float* m1    = (const float*)d_in[9];
    const float* v1    = (const float*)d_in[10];
    const float* w2    = (const float*)d_in[11];
    const float* b2    = (const float*)d_in[12];
    const float* g2    = (const float*)d_in[13];
    const float* bb2   = (const float*)d_in[14];
    const float* m2    = (const float*)d_in[15];
    const float* v2    = (const float*)d_in[16];
    const float* pjw   = (const float*)d_in[17];
    const float* pjb   = (const float*)d_in[18];

    float* out = (float*)d_out;
    char* wsb = (char*)d_ws;
    float* hidT    = (float*)wsb;
    u16*   wbf     = (u16*)(wsb + 12582912);
    float* pjb_pad = (float*)(wsb + 12582912 + 2101248);
    float* partial = (float*)(wsb + 12582912 + 2101248 + 12288);

    dim3 blk(256);

    wconv_kernel<<<dim3((WT2 + 3072 + 255)/256), blk, 0, stream>>>(
        w1, w2, pjw, pjb, pw, wbf, pjb_pad);

    const u16* preswz = wbf + W1N + W2N + PADN;
    prenet_mfma_kernel<<<dim3(64,1,8), blk, 0, stream>>>(x, cond, preswz, pb, hidT);

    dim3 grid_r(64, 1, 8);
    for (int l = 0; l < 3; ++l) {
        const u16* w1l = wbf + (size_t)l*110592;
        const u16* w2l = wbf + W1N + (size_t)l*36864;
        if (l == 0)
            resblock_kernel<1><<<grid_r, blk, 0, stream>>>(hidT, w1l, w2l, masks,
                b1+l*NC, g1+l*NC, bb1+l*NC, m1+l*NC, v1+l*NC,
                b2+l*NC, g2+l*NC, bb2+l*NC, m2+l*NC, v2+l*NC);
        else if (l == 1)
            resblock_kernel<3><<<grid_r, blk, 0, stream>>>(hidT, w1l, w2l, masks,
                b1+l*NC, g1+l*NC, bb1+l*NC, m1+l*NC, v1+l*NC,
                b2+l*NC, g2+l*NC, bb2+l*NC, m2+l*NC, v2+l*NC);
        else
            resblock_kernel<9><<<grid_r, blk, 0, stream>>>(hidT, w1l, w2l, masks,
                b1+l*NC, g1+l*NC, bb1+l*NC, m1+l*NC, v1+l*NC,
                b2+l*NC, g2+l*NC, bb2+l*NC, m2+l*NC, v2+l*NC);
    }

    const u16* pjwpad = wbf + W1N + W2N;
    proj_spline_mfma_kernel<<<dim3(16,12,16), blk, 0, stream>>>(
        hidT, pjwpad, pjb_pad, x, masks, out, partial);

    logdet_reduce_kernel<<<dim3(8), blk, 0, stream>>>(partial, out);
}

// Round 14
// 131.228 us; speedup vs baseline: 7.1622x; 1.0098x over previous
//
#include <hip/hip_runtime.h>
#include <math.h>

#define NB 8
#define NC 192
#define NT 2048
#define NHALF 96
#define NP 29
#define OUT_ELEMS (NB*NC*NT)
#define KP 100    // staging LDS row stride in dwords (200 bf16, 192 used)
#define PR 129    // P LDS row stride in dwords ([t][m] bf16, 256 m + pad)

typedef short bf16x8 __attribute__((ext_vector_type(8)));
typedef float f32x4 __attribute__((ext_vector_type(4)));
typedef unsigned int u32x2 __attribute__((ext_vector_type(2)));
typedef unsigned int u32x4 __attribute__((ext_vector_type(4)));
typedef unsigned short u16;
typedef unsigned int u32;

__device__ __forceinline__ u16 f2bf(float f) {
    u32 u = __builtin_bit_cast(u32, f);
    u += 0x7fffu + ((u >> 16) & 1u);
    return (u16)(u >> 16);
}
// packed f32 pair -> 2x bf16 in one instruction (RNE, same as f2bf)
__device__ __forceinline__ u32 pk_bf16(float lo, float hi) {
    u32 r;
    asm("v_cvt_pk_bf16_f32 %0, %1, %2" : "=v"(r) : "v"(lo), "v"(hi));
    return r;
}
__device__ __forceinline__ float softplus_fast(float v) {
    return (v > 20.0f) ? v : __logf(1.0f + __expf(v));
}
// mish(x) = x*tanh(softplus(x)) = x*(s^2-1)/(s^2+1), s = 1+e^x
__device__ __forceinline__ float mishf(float v) {
    if (v > 20.0f) return v;
    float s = 1.0f + __expf(v);
    float s2 = s * s;
    return v * (s2 - 1.0f) / (s2 + 1.0f);
}

// ---------- weight convert + fragment swizzle ----------
// swz[tile*512 + lane*8 + e] = W[m][k], m = mt*16+(lane&15), k = kk*32+(lane>>4)*8+e
#define W1N 331776   // 3*3*36864
#define W2N 110592   // 3*36864
#define PADN 589824  // 1152*512
#define PREN 18432   // 36*512
#define WT2 (W1N+W2N+PADN+PREN)
__global__ __launch_bounds__(256) void wconv_kernel(
    const float* __restrict__ w1, const float* __restrict__ w2,
    const float* __restrict__ pjw, const float* __restrict__ pjb,
    const float* __restrict__ pw,
    u16* __restrict__ outw, float* __restrict__ pjb_pad)
{
    int i = blockIdx.x*256 + threadIdx.x;
    if (i < WT2) {
        float v;
        if (i < W1N) {
            int s = i / 110592, r = i % 110592;
            int j = r / 36864, q = r % 36864;
            int tile = q >> 9, lane = (q >> 3) & 63, e = q & 7;
            int mt = tile / 6, kk = tile % 6;
            int m = mt*16 + (lane & 15);
            int k = kk*32 + (lane >> 4)*8 + e;
            v = w1[(((size_t)s*192 + m)*192 + k)*3 + j];
        } else if (i < W1N + W2N) {
            int q0 = i - W1N;
            int s = q0 / 36864, q = q0 % 36864;
            int tile = q >> 9, lane = (q >> 3) & 63, e = q & 7;
            int mt = tile / 6, kk = tile % 6;
            int m = mt*16 + (lane & 15);
            int k = kk*32 + (lane >> 4)*8 + e;
            v = w2[((size_t)s*192 + m)*192 + k];
        } else if (i < W1N + W2N + PADN) {
            int q = i - W1N - W2N;
            int tile = q >> 9, lane = (q >> 3) & 63, e = q & 7;
            int mt = tile / 6, kk = tile % 6;
            int m = mt*16 + (lane & 15);            // 0..3071
            int k = kk*32 + (lane >> 4)*8 + e;
            int c = m >> 5, p = m & 31;
            v = (p < NP) ? pjw[((size_t)(c*NP + p))*192 + k] : 0.f;
        } else {
            int q = i - W1N - W2N - PADN;
            int tile = q >> 9, lane = (q >> 3) & 63, e = q & 7;
            int mt = tile / 3, kk = tile % 3;
            int m = mt*16 + (lane & 15);            // 0..191
            int k = kk*32 + (lane >> 4)*8 + e;      // 0..95
            v = pw[(size_t)m*96 + k];
        }
        outw[i] = f2bf(v);
    } else if (i < WT2 + 3072) {
        int mp = i - WT2;
        int c = mp >> 5, p = mp & 31;
        pjb_pad[mp] = (p < NP) ? pjb[c*NP + p] : 0.f;
    }
}

// ---------- prenet MFMA: hidT[t][o] = W(192x96) x0 + bias + cond ----------
__global__ __launch_bounds__(256) void prenet_mfma_kernel(
    const float* __restrict__ x, const float* __restrict__ cond,
    const u16* __restrict__ wps, const float* __restrict__ bias,
    float* __restrict__ hidT)
{
    __shared__ u32 sm[32 * 52];
    const int tid = threadIdx.x, lane = tid & 63, wid = tid >> 6;
    const int b = blockIdx.z, tg0 = blockIdx.x * 32;
    const int l15 = lane & 15, kg = lane >> 4;

    for (int idx = tid; idx < 48*32; idx += 256) {
        int c2 = idx >> 5, tl = idx & 31;
        const float* p = x + ((size_t)b*NC + 2*c2)*NT + tg0 + tl;
        sm[tl*52 + c2] = pk_bf16(p[0], p[NT]);
    }
    __syncthreads();

    f32x4 acc[3][2];
    #pragma unroll
    for (int i = 0; i < 3; ++i) { acc[i][0] = f32x4{0,0,0,0}; acc[i][1] = f32x4{0,0,0,0}; }
    const char* smb = (const char*)sm;

    for (int kk = 0; kk < 3; ++kk) {
        int k0 = kk*32 + kg*8;
        bf16x8 b0 = *(const bf16x8*)(smb + (size_t)l15*208 + k0*2);
        bf16x8 b1f = *(const bf16x8*)(smb + (size_t)(l15+16)*208 + k0*2);
        bf16x8 af[3];
        #pragma unroll
        for (int ot = 0; ot < 3; ++ot) {
            int mt = wid*3 + ot;
            af[ot] = *(const bf16x8*)(wps + ((size_t)(mt*3 + kk))*512 + lane*8);
        }
        #pragma unroll
        for (int ot = 0; ot < 3; ++ot) {
            acc[ot][0] = __builtin_amdgcn_mfma_f32_16x16x32_bf16(af[ot], b0, acc[ot][0], 0, 0, 0);
            acc[ot][1] = __builtin_amdgcn_mfma_f32_16x16x32_bf16(af[ot], b1f, acc[ot][1], 0, 0, 0);
        }
    }

    #pragma unroll
    for (int ot = 0; ot < 3; ++ot) {
        int m = (wid*3 + ot)*16 + (kg << 2);
        f32x4 bi = *(const f32x4*)(bias + m);
        #pragma unroll
        for (int tt = 0; tt < 2; ++tt) {
            int t = tg0 + tt*16 + l15;
            f32x4 A = acc[ot][tt];
            f32x4 o;
            #pragma unroll
            for (int r = 0; r < 4; ++r)
                o[r] = A[r] + bi[r] + cond[((size_t)b*NC + m + r)*NT + t];
            *(f32x4*)(hidT + ((size_t)b*NT + t)*NC + m) = o;
        }
    }
}

// ---------- fused residual block (TT=16, 4 blocks/CU) ----------
// LAST: also emit hidB = bf16(hid*mask) [b][t][96 dwords] for the proj stage.
template<int DIL, int LAST>
__global__ __launch_bounds__(256) void resblock_kernel(
    float* __restrict__ hidT, const u16* __restrict__ w1s, const u16* __restrict__ w2s,
    const float* __restrict__ masks,
    const float* __restrict__ b1v, const float* __restrict__ g1v, const float* __restrict__ bb1v,
    const float* __restrict__ bm1v, const float* __restrict__ bv1v,
    const float* __restrict__ b2v, const float* __restrict__ g2v, const float* __restrict__ bb2v,
    const float* __restrict__ bm2v, const float* __restrict__ bv2v,
    u32* __restrict__ hidB)
{
    constexpr int ROWS = 16 + 2*DIL;
    __shared__ u32 sm1[ROWS * KP];
    __shared__ u32 sm2[16 * KP];
    const int tid = threadIdx.x, lane = tid & 63, wid = tid >> 6;
    const int b = blockIdx.z, tg0 = blockIdx.x * 16;
    const int l15 = lane & 15, kg = lane >> 4;

    // stage hid tile, masked, bf16 pairs [t-row][k]
    for (int it = tid; it < ROWS*48; it += 256) {
        int row = it / 48, kq = it - row*48;
        int t = tg0 + row - DIL;
        u32 lo = 0, hi = 0;
        if (t >= 0 && t < NT) {
            f32x4 v = *(const f32x4*)(hidT + ((size_t)b*NT + t)*NC + kq*4);
            float mv = masks[(size_t)b*NT + t];
            lo = pk_bf16(v[0]*mv, v[1]*mv);
            hi = pk_bf16(v[2]*mv, v[3]*mv);
        }
        *(u32x2*)(&sm1[row*KP + kq*2]) = u32x2{lo, hi};
    }
    __syncthreads();

    // GEMM1: 192m x 16t x 192k x 3 taps; wave handles 3 mt
    f32x4 acc[3];
    #pragma unroll
    for (int i = 0; i < 3; ++i) acc[i] = f32x4{0,0,0,0};
    const char* smb1 = (const char*)sm1;

    for (int j = 0; j < 3; ++j) {
        const u16* wsl = w1s + (size_t)j * 36864;
        for (int kk = 0; kk < 6; ++kk) {
            int k0 = kk*32 + kg*8;
            bf16x8 b0 = *(const bf16x8*)(smb1 + (size_t)(l15 + j*DIL)*400 + k0*2);
            bf16x8 af[3];
            #pragma unroll
            for (int ot = 0; ot < 3; ++ot) {
                int mt = wid*3 + ot;
                af[ot] = *(const bf16x8*)(wsl + ((size_t)(mt*6 + kk))*512 + lane*8);
            }
            #pragma unroll
            for (int ot = 0; ot < 3; ++ot)
                acc[ot] = __builtin_amdgcn_mfma_f32_16x16x32_bf16(af[ot], b0, acc[ot], 0, 0, 0);
        }
    }

    // epilogue1: tmp = BN1(mish(acc+b1)) -> sm2 [t][k] bf16 pairs
    #pragma unroll
    for (int ot = 0; ot < 3; ++ot) {
        int m = (wid*3 + ot)*16 + (kg << 2);
        f32x4 bi = *(const f32x4*)(b1v + m);
        f32x4 g4 = *(const f32x4*)(g1v + m);
        f32x4 bb4 = *(const f32x4*)(bb1v + m);
        f32x4 bm4 = *(const f32x4*)(bm1v + m);
        f32x4 bv4 = *(const f32x4*)(bv1v + m);
        f32x4 A = acc[ot];
        float vr[4];
        #pragma unroll
        for (int r = 0; r < 4; ++r) {
            float v = mishf(A[r] + bi[r]);
            vr[r] = (v - bm4[r]) * (g4[r] * rsqrtf(bv4[r] + 1e-5f)) + bb4[r];
        }
        *(u32x2*)(&sm2[l15*KP + (m >> 1)]) = u32x2{pk_bf16(vr[0], vr[1]), pk_bf16(vr[2], vr[3])};
    }
    __syncthreads();

    // GEMM2: 192m x 16t x 192k from sm2
    f32x4 acc2[3];
    #pragma unroll
    for (int i = 0; i < 3; ++i) acc2[i] = f32x4{0,0,0,0};
    const char* smb2 = (const char*)sm2;

    for (int kk = 0; kk < 6; ++kk) {
        int k0 = kk*32 + kg*8;
        bf16x8 b0 = *(const bf16x8*)(smb2 + (size_t)l15*400 + k0*2);
        bf16x8 af[3];
        #pragma unroll
        for (int ot = 0; ot < 3; ++ot) {
            int mt = wid*3 + ot;
            af[ot] = *(const bf16x8*)(w2s + ((size_t)(mt*6 + kk))*512 + lane*8);
        }
        #pragma unroll
        for (int ot = 0; ot < 3; ++ot)
            acc2[ot] = __builtin_amdgcn_mfma_f32_16x16x32_bf16(af[ot], b0, acc2[ot], 0, 0, 0);
    }

    // epilogue2: hidT += BN2(mish(acc2+b2)); LAST also writes hidB
    const int t = tg0 + l15;
    float mv = LAST ? masks[(size_t)b*NT + t] : 0.f;
    #pragma unroll
    for (int ot = 0; ot < 3; ++ot) {
        int m = (wid*3 + ot)*16 + (kg << 2);
        f32x4 bi = *(const f32x4*)(b2v + m);
        f32x4 g4 = *(const f32x4*)(g2v + m);
        f32x4 bb4 = *(const f32x4*)(bb2v + m);
        f32x4 bm4 = *(const f32x4*)(bm2v + m);
        f32x4 bv4 = *(const f32x4*)(bv2v + m);
        f32x4 A = acc2[ot];
        float* dst = hidT + ((size_t)b*NT + t)*NC + m;
        f32x4 old = *(const f32x4*)dst;
        f32x4 nv;
        #pragma unroll
        for (int r = 0; r < 4; ++r) {
            float v = mishf(A[r] + bi[r]);
            nv[r] = old[r] + ((v - bm4[r]) * (g4[r] * rsqrtf(bv4[r] + 1e-5f)) + bb4[r]);
        }
        *(f32x4*)dst = nv;
        if constexpr (LAST) {
            *(u32x2*)(hidB + ((size_t)b*NT + t)*96 + (m >> 1)) =
                u32x2{pk_bf16(nv[0]*mv, nv[1]*mv), pk_bf16(nv[2]*mv, nv[3]*mv)};
        }
    }
}

// ---------- fused proj GEMM (M=256/block) + RQ spline + x0-flip + lad ----------
// grid (16 t-tiles, 12 m-blocks(=8c each), 16 units(b,th)), block 256
__global__ __launch_bounds__(256) void proj_spline_mfma_kernel(
    const u32* __restrict__ hidB, const u16* __restrict__ wpad,
    const float* __restrict__ pjb_pad, const float* __restrict__ x,
    const float* __restrict__ masks, float* __restrict__ outp,
    float* __restrict__ partial)
{
    __shared__ u32 uls[64*PR];   // union: staging [64][KP] then P [64 t][258 u16]
    __shared__ float red4[4];
    const int tid  = threadIdx.x;
    const int lane = tid & 63;
    const int wid  = tid >> 6;
    const int z  = blockIdx.z;
    const int b  = z >> 1, th = z & 1;
    const int tg0 = th*1024 + blockIdx.x*64;
    const int l15 = lane & 15;
    const int kg  = lane >> 4;

    // ---- stage B tile: pre-masked bf16 from hidB, pure 16B copies ----
    for (int it = tid; it < 64*24; it += 256) {
        int row = it / 24, q = it - row*24;
        u32x4 v = *(const u32x4*)(hidB + ((size_t)b*NT + tg0 + row)*96 + q*4);
        *(u32x4*)(&uls[row*KP + q*4]) = v;
    }
    __syncthreads();

    // ---- GEMM: 256 m x 64 t x 192 k.  4 waves along m (4 mt each), t=64 per wave ----
    f32x4 acc[4][4];   // [ot][tt]
    #pragma unroll
    for (int i = 0; i < 4; ++i)
        #pragma unroll
        for (int j2 = 0; j2 < 4; ++j2) acc[i][j2] = f32x4{0,0,0,0};
    const char* smb = (const char*)uls;
    const int mtb = blockIdx.y*16 + wid*4;

    for (int kk = 0; kk < 6; ++kk) {
        int k0 = kk*32 + kg*8;
        bf16x8 bt[4];
        #pragma unroll
        for (int tt = 0; tt < 4; ++tt)
            bt[tt] = *(const bf16x8*)(smb + (size_t)(tt*16 + l15)*400 + k0*2);
        bf16x8 af[4];
        #pragma unroll
        for (int ot = 0; ot < 4; ++ot)
            af[ot] = *(const bf16x8*)(wpad + ((size_t)((mtb + ot)*6 + kk))*512 + lane*8);
        #pragma unroll
        for (int ot = 0; ot < 4; ++ot)
            #pragma unroll
            for (int tt = 0; tt < 4; ++tt)
                acc[ot][tt] = __builtin_amdgcn_mfma_f32_16x16x32_bf16(af[ot], bt[tt], acc[ot][tt], 0, 0, 0);
    }
    __syncthreads();   // staging dead; reuse LDS as P [t][m] bf16

    // ---- P[t][mloc] = bf16((acc + pjb)*mask), cvt_pk + u32x2 stores ----
    #pragma unroll
    for (int tt = 0; tt < 4; ++tt) {
        int t = tt*16 + l15;
        float mkv = masks[(size_t)b*NT + tg0 + t];
        #pragma unroll
        for (int ot = 0; ot < 4; ++ot) {
            int mloc = (wid*4 + ot)*16 + (kg << 2);
            f32x4 pb = *(const f32x4*)(pjb_pad + blockIdx.y*256 + mloc);
            f32x4 A = acc[ot][tt];
            *(u32x2*)(&uls[t*PR + (mloc >> 1)]) =
                u32x2{pk_bf16((A[0]+pb[0])*mkv, (A[1]+pb[1])*mkv),
                      pk_bf16((A[2]+pb[2])*mkv, (A[3]+pb[3])*mkv)};
        }
    }
    __syncthreads();

    // ---- spline: 8 c-channels x 64 t = 512 items, exactly 2 per thread ----
    float lsum = 0.f;
    #pragma unroll
    for (int rep = 0; rep < 2; ++rep) {
        int item = tid + rep*256;
        int cl = item >> 6, t = item & 63;
        int c  = blockIdx.y*8 + cl;
        int tg = tg0 + t;
        float m = masks[(size_t)b*NT + tg];

        // x0 flip copy (each (c,tg) covered exactly once across the grid)
        float x0v = x[((size_t)b*NC + c)*NT + tg];
        outp[((size_t)b*NC + (NC-1 - c))*NT + tg] = x0v * m;

        float pr[30];
        #pragma unroll
        for (int j = 0; j < 15; ++j) {
            u32 w = uls[t*PR + cl*16 + j];
            pr[2*j]   = __builtin_bit_cast(float, w << 16);
            pr[2*j+1] = __builtin_bit_cast(float, w & 0xffff0000u);
        }

        const float invsq = 0.07216878364870322f;  // 1/sqrt(192)
        float cw[11], chh[11];
        {   // width knots (no max-subtraction: |u| << 1 analytically)
            float e[10], s = 0.f;
            #pragma unroll
            for (int i = 0; i < 10; ++i) { e[i] = __expf(pr[i] * invsq); s += e[i]; }
            float inv_s = __builtin_amdgcn_rcpf(s);
            float run = 0.f;
            cw[0] = -5.f;
            #pragma unroll
            for (int i = 0; i < 10; ++i) {
                run += 0.001f + 0.99f * e[i] * inv_s;
                cw[i+1] = 10.f*run - 5.f;
            }
            cw[10] = 5.f;
        }
        {   // height knots
            float e[10], s = 0.f;
            #pragma unroll
            for (int i = 0; i < 10; ++i) { e[i] = __expf(pr[10+i] * invsq); s += e[i]; }
            float inv_s = __builtin_amdgcn_rcpf(s);
            float run = 0.f;
            chh[0] = -5.f;
            #pragma unroll
            for (int i = 0; i < 10; ++i) {
                run += 0.001f + 0.99f * e[i] * inv_s;
                chh[i+1] = 10.f*run - 5.f;
            }
            chh[10] = 5.f;
        }

        float x1 = x[((size_t)b*NC + NHALF + c)*NT + tg];
        float xc = fminf(fmaxf(x1, -5.f), 5.f);
        int cnt = 0;
        #pragma unroll
        for (int i = 0; i < 11; ++i) cnt += (xc >= cw[i]) ? 1 : 0;
        int kidx = cnt - 1;
        kidx = kidx < 0 ? 0 : (kidx > 9 ? 9 : kidx);

        float icw=0.f, iw=1.f, ich=0.f, ih=0.f, s0=0.f, s1=0.f;
        #pragma unroll
        for (int i = 0; i < 10; ++i) {
            if (i == kidx) {
                icw = cw[i]; iw = cw[i+1]-cw[i];
                ich = chh[i]; ih = chh[i+1]-chh[i];
                s0 = (i >= 1) ? pr[19+i] : 0.f;
                s1 = (i <= 8) ? pr[20+i] : 0.f;
            }
        }
        float d0 = (kidx == 0) ? 1.f : 0.001f + softplus_fast(s0);
        float d1 = (kidx == 9) ? 1.f : 0.001f + softplus_fast(s1);

        float rw    = __builtin_amdgcn_rcpf(iw);
        float dlt   = ih * rw;
        float theta = (xc - icw) * rw;
        float t1m   = theta * (1.f - theta);
        float den   = dlt + (d0 + d1 - 2.f*dlt) * t1m;
        float rden  = __builtin_amdgcn_rcpf(den);
        float num   = ih * (dlt*theta*theta + d0*t1m);
        float outv  = ich + num * rden;
        float omt   = 1.f - theta;
        float dnum  = dlt*dlt*(d1*theta*theta + 2.f*dlt*t1m + d0*omt*omt);
        float lad   = __logf(dnum * rden * rden);
        bool inside = (x1 >= -5.f) && (x1 <= 5.f);
        float xout  = inside ? outv : x1;
        float ladv  = inside ? lad : 0.f;
        outp[((size_t)b*NC + (NHALF-1 - c))*NT + tg] = xout * m;
        lsum += ladv * m;
    }

    // ---- wave-shuffle reduction, then 4-way cross-wave sum ----
    #pragma unroll
    for (int off = 32; off > 0; off >>= 1)
        lsum += __shfl_down(lsum, off, 64);
    if (lane == 0) red4[wid] = lsum;
    __syncthreads();
    if (tid == 0)
        partial[(size_t)b*384 + th*192 + blockIdx.y*16 + blockIdx.x] =
            red4[0] + red4[1] + red4[2] + red4[3];
}

__global__ __launch_bounds__(256) void logdet_reduce_kernel(
    const float* __restrict__ partial, float* __restrict__ outp)
{
    __shared__ float red[256];
    const int b = blockIdx.x;
    const int tid = threadIdx.x;
    float s = 0.f;
    for (int i = tid; i < 384; i += 256) s += partial[(size_t)b*384 + i];
    red[tid] = s;
    __syncthreads();
    for (int st = 128; st > 0; st >>= 1) {
        if (tid < st) red[tid] += red[tid + st];
        __syncthreads();
    }
    if (tid == 0) outp[(size_t)OUT_ELEMS + b] = red[0];
}

extern "C" void kernel_launch(void* const* d_in, const int* in_sizes, int n_in,
                              void* d_out, int out_size, void* d_ws, size_t ws_size,
                              hipStream_t stream) {
    const float* x     = (const float*)d_in[0];
    const float* cond  = (const float*)d_in[1];
    const float* masks = (const float*)d_in[2];
    const float* pw    = (const float*)d_in[3];
    const float* pb    = (const float*)d_in[4];
    const float* w1    = (const float*)d_in[5];
    const float* b1    = (const float*)d_in[6];
    const float* g1    = (const float*)d_in[7];
    const float* bb1   = (const float*)d_in[8];
    const float* m1    = (const float*)d_in[9];
    const float* v1    = (const float*)d_in[10];
    const float* w2    = (const float*)d_in[11];
    const float* b2    = (const float*)d_in[12];
    const float* g2    = (const float*)d_in[13];
    const float* bb2   = (const float*)d_in[14];
    const float* m2    = (const float*)d_in[15];
    const float* v2    = (const float*)d_in[16];
    const float* pjw   = (const float*)d_in[17];
    const float* pjb   = (const float*)d_in[18];

    float* out = (float*)d_out;
    char* wsb = (char*)d_ws;
    float* hidT    = (float*)wsb;                                  // 12,582,912 B
    u16*   wbf     = (u16*)(wsb + 12582912);                       //  2,101,248 B
    float* pjb_pad = (float*)(wsb + 12582912 + 2101248);           //     12,288 B
    float* partial = (float*)(wsb + 12582912 + 2101248 + 12288);   //     16,384 B
    u32*   hidB    = (u32*)(wsb + 14712832);                       //  6,291,456 B

    dim3 blk(256);

    wconv_kernel<<<dim3((WT2 + 3072 + 255)/256), blk, 0, stream>>>(
        w1, w2, pjw, pjb, pw, wbf, pjb_pad);

    const u16* preswz = wbf + W1N + W2N + PADN;
    prenet_mfma_kernel<<<dim3(64,1,8), blk, 0, stream>>>(x, cond, preswz, pb, hidT);

    dim3 grid_r(128, 1, 8);
    for (int l = 0; l < 3; ++l) {
        const u16* w1l = wbf + (size_t)l*110592;
        const u16* w2l = wbf + W1N + (size_t)l*36864;
        if (l == 0)
            resblock_kernel<1,0><<<grid_r, blk, 0, stream>>>(hidT, w1l, w2l, masks,
                b1+l*NC, g1+l*NC, bb1+l*NC, m1+l*NC, v1+l*NC,
                b2+l*NC, g2+l*NC, bb2+l*NC, m2+l*NC, v2+l*NC, hidB);
        else if (l == 1)
            resblock_kernel<3,0><<<grid_r, blk, 0, stream>>>(hidT, w1l, w2l, masks,
                b1+l*NC, g1+l*NC, bb1+l*NC, m1+l*NC, v1+l*NC,
                b2+l*NC, g2+l*NC, bb2+l*NC, m2+l*NC, v2+l*NC, hidB);
        else
            resblock_kernel<9,1><<<grid_r, blk, 0, stream>>>(hidT, w1l, w2l, masks,
                b1+l*NC, g1+l*NC, bb1+l*NC, m1+l*NC, v1+l*NC,
                b2+l*NC, g2+l*NC, bb2+l*NC, m2+l*NC, v2+l*NC, hidB);
    }

    const u16* pjwpad = wbf + W1N + W2N;
    proj_spline_mfma_kernel<<<dim3(16,12,16), blk, 0, stream>>>(
        hidB, pjwpad, pjb_pad, x, masks, out, partial);

    logdet_reduce_kernel<<<dim3(8), blk, 0, stream>>>(partial, out);
}

// Round 15
// 126.394 us; speedup vs baseline: 7.4361x; 1.0382x over previous
//
#include <hip/hip_runtime.h>
#include <math.h>

#define NB 8
#define NC 192
#define NT 2048
#define NHALF 96
#define NP 29
#define OUT_ELEMS (NB*NC*NT)
#define KP 100    // staging LDS row stride in dwords (200 bf16, 192 used)
#define PR 129    // P LDS row stride in dwords ([t][m] bf16, 256 m + pad)

typedef short bf16x8 __attribute__((ext_vector_type(8)));
typedef float f32x4 __attribute__((ext_vector_type(4)));
typedef unsigned int u32x2 __attribute__((ext_vector_type(2)));
typedef unsigned int u32x4 __attribute__((ext_vector_type(4)));
typedef unsigned short u16;
typedef unsigned int u32;

__device__ __forceinline__ u16 f2bf(float f) {
    u32 u = __builtin_bit_cast(u32, f);
    u += 0x7fffu + ((u >> 16) & 1u);
    return (u16)(u >> 16);
}
// packed f32 pair -> 2x bf16 in one instruction (RNE, same as f2bf)
__device__ __forceinline__ u32 pk_bf16(float lo, float hi) {
    u32 r;
    asm("v_cvt_pk_bf16_f32 %0, %1, %2" : "=v"(r) : "v"(lo), "v"(hi));
    return r;
}
__device__ __forceinline__ float softplus_fast(float v) {
    return (v > 20.0f) ? v : __logf(1.0f + __expf(v));
}
// mish(x) = x*tanh(softplus(x)) = x*(s^2-1)/(s^2+1), s = 1+e^x
__device__ __forceinline__ float mishf(float v) {
    if (v > 20.0f) return v;
    float s = 1.0f + __expf(v);
    float s2 = s * s;
    return v * (s2 - 1.0f) / (s2 + 1.0f);
}

// ---------- weight convert + fragment swizzle ----------
// swz[tile*512 + lane*8 + e] = W[m][k], m = mt*16+(lane&15), k = kk*32+(lane>>4)*8+e
#define W1N 331776   // 3*3*36864
#define W2N 110592   // 3*36864
#define PADN 589824  // 1152*512
#define PREN 18432   // 36*512
#define WT2 (W1N+W2N+PADN+PREN)
__global__ __launch_bounds__(256) void wconv_kernel(
    const float* __restrict__ w1, const float* __restrict__ w2,
    const float* __restrict__ pjw, const float* __restrict__ pjb,
    const float* __restrict__ pw,
    u16* __restrict__ outw, float* __restrict__ pjb_pad)
{
    int i = blockIdx.x*256 + threadIdx.x;
    if (i < WT2) {
        float v;
        if (i < W1N) {
            int s = i / 110592, r = i % 110592;
            int j = r / 36864, q = r % 36864;
            int tile = q >> 9, lane = (q >> 3) & 63, e = q & 7;
            int mt = tile / 6, kk = tile % 6;
            int m = mt*16 + (lane & 15);
            int k = kk*32 + (lane >> 4)*8 + e;
            v = w1[(((size_t)s*192 + m)*192 + k)*3 + j];
        } else if (i < W1N + W2N) {
            int q0 = i - W1N;
            int s = q0 / 36864, q = q0 % 36864;
            int tile = q >> 9, lane = (q >> 3) & 63, e = q & 7;
            int mt = tile / 6, kk = tile % 6;
            int m = mt*16 + (lane & 15);
            int k = kk*32 + (lane >> 4)*8 + e;
            v = w2[((size_t)s*192 + m)*192 + k];
        } else if (i < W1N + W2N + PADN) {
            int q = i - W1N - W2N;
            int tile = q >> 9, lane = (q >> 3) & 63, e = q & 7;
            int mt = tile / 6, kk = tile % 6;
            int m = mt*16 + (lane & 15);            // 0..3071
            int k = kk*32 + (lane >> 4)*8 + e;
            int c = m >> 5, p = m & 31;
            v = (p < NP) ? pjw[((size_t)(c*NP + p))*192 + k] : 0.f;
        } else {
            int q = i - W1N - W2N - PADN;
            int tile = q >> 9, lane = (q >> 3) & 63, e = q & 7;
            int mt = tile / 3, kk = tile % 3;
            int m = mt*16 + (lane & 15);            // 0..191
            int k = kk*32 + (lane >> 4)*8 + e;      // 0..95
            v = pw[(size_t)m*96 + k];
        }
        outw[i] = f2bf(v);
    } else if (i < WT2 + 3072) {
        int mp = i - WT2;
        int c = mp >> 5, p = mp & 31;
        pjb_pad[mp] = (p < NP) ? pjb[c*NP + p] : 0.f;
    }
}

// ---------- prenet MFMA: hidT/hidB = W(192x96) x0 + bias + cond ----------
__global__ __launch_bounds__(256) void prenet_mfma_kernel(
    const float* __restrict__ x, const float* __restrict__ cond,
    const u16* __restrict__ wps, const float* __restrict__ bias,
    const float* __restrict__ masks,
    float* __restrict__ hidT, u32* __restrict__ hidB)
{
    __shared__ u32 sm[32 * 52];
    const int tid = threadIdx.x, lane = tid & 63, wid = tid >> 6;
    const int b = blockIdx.z, tg0 = blockIdx.x * 32;
    const int l15 = lane & 15, kg = lane >> 4;

    for (int idx = tid; idx < 48*32; idx += 256) {
        int c2 = idx >> 5, tl = idx & 31;
        const float* p = x + ((size_t)b*NC + 2*c2)*NT + tg0 + tl;
        sm[tl*52 + c2] = pk_bf16(p[0], p[NT]);
    }
    __syncthreads();

    f32x4 acc[3][2];
    #pragma unroll
    for (int i = 0; i < 3; ++i) { acc[i][0] = f32x4{0,0,0,0}; acc[i][1] = f32x4{0,0,0,0}; }
    const char* smb = (const char*)sm;

    for (int kk = 0; kk < 3; ++kk) {
        int k0 = kk*32 + kg*8;
        bf16x8 b0 = *(const bf16x8*)(smb + (size_t)l15*208 + k0*2);
        bf16x8 b1f = *(const bf16x8*)(smb + (size_t)(l15+16)*208 + k0*2);
        bf16x8 af[3];
        #pragma unroll
        for (int ot = 0; ot < 3; ++ot) {
            int mt = wid*3 + ot;
            af[ot] = *(const bf16x8*)(wps + ((size_t)(mt*3 + kk))*512 + lane*8);
        }
        #pragma unroll
        for (int ot = 0; ot < 3; ++ot) {
            acc[ot][0] = __builtin_amdgcn_mfma_f32_16x16x32_bf16(af[ot], b0, acc[ot][0], 0, 0, 0);
            acc[ot][1] = __builtin_amdgcn_mfma_f32_16x16x32_bf16(af[ot], b1f, acc[ot][1], 0, 0, 0);
        }
    }

    #pragma unroll
    for (int ot = 0; ot < 3; ++ot) {
        int m = (wid*3 + ot)*16 + (kg << 2);
        f32x4 bi = *(const f32x4*)(bias + m);
        #pragma unroll
        for (int tt = 0; tt < 2; ++tt) {
            int t = tg0 + tt*16 + l15;
            float mv = masks[(size_t)b*NT + t];
            f32x4 A = acc[ot][tt];
            f32x4 o;
            #pragma unroll
            for (int r = 0; r < 4; ++r)
                o[r] = A[r] + bi[r] + cond[((size_t)b*NC + m + r)*NT + t];
            *(f32x4*)(hidT + ((size_t)b*NT + t)*NC + m) = o;
            *(u32x2*)(hidB + ((size_t)b*NT + t)*96 + (m >> 1)) =
                u32x2{pk_bf16(o[0]*mv, o[1]*mv), pk_bf16(o[2]*mv, o[3]*mv)};
        }
    }
}

// ---------- fused residual block (TT=32), hidB chain + A-prefetch ----------
// in: hidB_in (pre-masked bf16), hidT (fp32 trunk, RMW)
// out: hidT += BN2(mish(conv2(...))), hidB_out = bf16(new hid * mask)
template<int DIL>
__global__ __launch_bounds__(256) void resblock_kernel(
    float* __restrict__ hidT, const u32* __restrict__ hidBin, u32* __restrict__ hidBout,
    const u16* __restrict__ w1s, const u16* __restrict__ w2s,
    const float* __restrict__ masks,
    const float* __restrict__ b1v, const float* __restrict__ g1v, const float* __restrict__ bb1v,
    const float* __restrict__ bm1v, const float* __restrict__ bv1v,
    const float* __restrict__ b2v, const float* __restrict__ g2v, const float* __restrict__ bb2v,
    const float* __restrict__ bm2v, const float* __restrict__ bv2v)
{
    constexpr int ROWS = 32 + 2*DIL;
    __shared__ u32 sm1[ROWS * KP];
    __shared__ u32 sm2[32 * KP];
    const int tid = threadIdx.x, lane = tid & 63, wid = tid >> 6;
    const int b = blockIdx.z, tg0 = blockIdx.x * 32;
    const int l15 = lane & 15, kg = lane >> 4;

    // stage pre-masked bf16 rows from hidBin: pure 16B copies, zero halo
    for (int it = tid; it < ROWS*24; it += 256) {
        int row = it / 24, q = it - row*24;
        int t = tg0 + row - DIL;
        u32x4 v = u32x4{0,0,0,0};
        if (t >= 0 && t < NT)
            v = *(const u32x4*)(hidBin + ((size_t)b*NT + t)*96 + q*4);
        *(u32x4*)(&sm1[row*KP + q*4]) = v;
    }
    __syncthreads();

    // GEMM1: 192m x 32t x 192k x 3 taps, A-prefetch across 18 iters
    f32x4 acc[3][2];
    #pragma unroll
    for (int i = 0; i < 3; ++i) { acc[i][0] = f32x4{0,0,0,0}; acc[i][1] = f32x4{0,0,0,0}; }
    const char* smb1 = (const char*)sm1;

    bf16x8 afc[3], afn[3];
    #pragma unroll
    for (int ot = 0; ot < 3; ++ot)
        afc[ot] = *(const bf16x8*)(w1s + ((size_t)((wid*3 + ot)*6))*512 + lane*8);

    #pragma unroll
    for (int it = 0; it < 18; ++it) {
        const int j = it / 6, kk = it % 6;
        if (it + 1 < 18) {
            const int jn = (it + 1) / 6, kkn = (it + 1) % 6;
            const u16* wn = w1s + (size_t)jn * 36864;
            #pragma unroll
            for (int ot = 0; ot < 3; ++ot)
                afn[ot] = *(const bf16x8*)(wn + ((size_t)((wid*3 + ot)*6 + kkn))*512 + lane*8);
        }
        int k0 = kk*32 + kg*8;
        bf16x8 b0  = *(const bf16x8*)(smb1 + (size_t)(l15 + j*DIL)*400 + k0*2);
        bf16x8 b1f = *(const bf16x8*)(smb1 + (size_t)(l15 + 16 + j*DIL)*400 + k0*2);
        #pragma unroll
        for (int ot = 0; ot < 3; ++ot) {
            acc[ot][0] = __builtin_amdgcn_mfma_f32_16x16x32_bf16(afc[ot], b0,  acc[ot][0], 0, 0, 0);
            acc[ot][1] = __builtin_amdgcn_mfma_f32_16x16x32_bf16(afc[ot], b1f, acc[ot][1], 0, 0, 0);
        }
        #pragma unroll
        for (int ot = 0; ot < 3; ++ot) afc[ot] = afn[ot];
    }

    // epilogue1: tmp = BN1(mish(acc+b1)) -> sm2 [t][k] bf16 pairs
    #pragma unroll
    for (int ot = 0; ot < 3; ++ot) {
        int m = (wid*3 + ot)*16 + (kg << 2);
        f32x4 bi = *(const f32x4*)(b1v + m);
        f32x4 g4 = *(const f32x4*)(g1v + m);
        f32x4 bb4 = *(const f32x4*)(bb1v + m);
        f32x4 bm4 = *(const f32x4*)(bm1v + m);
        f32x4 bv4 = *(const f32x4*)(bv1v + m);
        #pragma unroll
        for (int tt = 0; tt < 2; ++tt) {
            int tl = tt*16 + l15;
            f32x4 A = acc[ot][tt];
            float vr[4];
            #pragma unroll
            for (int r = 0; r < 4; ++r) {
                float v = mishf(A[r] + bi[r]);
                vr[r] = (v - bm4[r]) * (g4[r] * rsqrtf(bv4[r] + 1e-5f)) + bb4[r];
            }
            *(u32x2*)(&sm2[tl*KP + (m >> 1)]) = u32x2{pk_bf16(vr[0], vr[1]), pk_bf16(vr[2], vr[3])};
        }
    }
    __syncthreads();

    // GEMM2: 192m x 32t x 192k from sm2, A-prefetch across 6 iters
    f32x4 acc2[3][2];
    #pragma unroll
    for (int i = 0; i < 3; ++i) { acc2[i][0] = f32x4{0,0,0,0}; acc2[i][1] = f32x4{0,0,0,0}; }
    const char* smb2 = (const char*)sm2;

    #pragma unroll
    for (int ot = 0; ot < 3; ++ot)
        afc[ot] = *(const bf16x8*)(w2s + ((size_t)((wid*3 + ot)*6))*512 + lane*8);

    #pragma unroll
    for (int kk = 0; kk < 6; ++kk) {
        if (kk + 1 < 6) {
            #pragma unroll
            for (int ot = 0; ot < 3; ++ot)
                afn[ot] = *(const bf16x8*)(w2s + ((size_t)((wid*3 + ot)*6 + kk + 1))*512 + lane*8);
        }
        int k0 = kk*32 + kg*8;
        bf16x8 b0  = *(const bf16x8*)(smb2 + (size_t)l15*400 + k0*2);
        bf16x8 b1f = *(const bf16x8*)(smb2 + (size_t)(l15+16)*400 + k0*2);
        #pragma unroll
        for (int ot = 0; ot < 3; ++ot) {
            acc2[ot][0] = __builtin_amdgcn_mfma_f32_16x16x32_bf16(afc[ot], b0,  acc2[ot][0], 0, 0, 0);
            acc2[ot][1] = __builtin_amdgcn_mfma_f32_16x16x32_bf16(afc[ot], b1f, acc2[ot][1], 0, 0, 0);
        }
        #pragma unroll
        for (int ot = 0; ot < 3; ++ot) afc[ot] = afn[ot];
    }

    // epilogue2: hidT += BN2(mish(acc2+b2)); emit hidBout = bf16(new*mask)
    #pragma unroll
    for (int ot = 0; ot < 3; ++ot) {
        int m = (wid*3 + ot)*16 + (kg << 2);
        f32x4 bi = *(const f32x4*)(b2v + m);
        f32x4 g4 = *(const f32x4*)(g2v + m);
        f32x4 bb4 = *(const f32x4*)(bb2v + m);
        f32x4 bm4 = *(const f32x4*)(bm2v + m);
        f32x4 bv4 = *(const f32x4*)(bv2v + m);
        #pragma unroll
        for (int tt = 0; tt < 2; ++tt) {
            int t = tg0 + tt*16 + l15;
            float mv = masks[(size_t)b*NT + t];
            f32x4 A = acc2[ot][tt];
            float* dst = hidT + ((size_t)b*NT + t)*NC + m;
            f32x4 old = *(const f32x4*)dst;
            f32x4 nv;
            #pragma unroll
            for (int r = 0; r < 4; ++r) {
                float v = mishf(A[r] + bi[r]);
                nv[r] = old[r] + ((v - bm4[r]) * (g4[r] * rsqrtf(bv4[r] + 1e-5f)) + bb4[r]);
            }
            *(f32x4*)dst = nv;
            *(u32x2*)(hidBout + ((size_t)b*NT + t)*96 + (m >> 1)) =
                u32x2{pk_bf16(nv[0]*mv, nv[1]*mv), pk_bf16(nv[2]*mv, nv[3]*mv)};
        }
    }
}

// ---------- fused proj GEMM (M=256/block) + RQ spline + x0-flip + lad ----------
// grid (16 t-tiles, 12 m-blocks(=8c each), 16 units(b,th)), block 256
__global__ __launch_bounds__(256) void proj_spline_mfma_kernel(
    const u32* __restrict__ hidB, const u16* __restrict__ wpad,
    const float* __restrict__ pjb_pad, const float* __restrict__ x,
    const float* __restrict__ masks, float* __restrict__ outp,
    float* __restrict__ partial)
{
    __shared__ u32 uls[64*PR];   // union: staging [64][KP] then P [64 t][258 u16]
    __shared__ float red4[4];
    const int tid  = threadIdx.x;
    const int lane = tid & 63;
    const int wid  = tid >> 6;
    const int z  = blockIdx.z;
    const int b  = z >> 1, th = z & 1;
    const int tg0 = th*1024 + blockIdx.x*64;
    const int l15 = lane & 15;
    const int kg  = lane >> 4;

    // ---- stage B tile: pre-masked bf16 from hidB, pure 16B copies ----
    for (int it = tid; it < 64*24; it += 256) {
        int row = it / 24, q = it - row*24;
        u32x4 v = *(const u32x4*)(hidB + ((size_t)b*NT + tg0 + row)*96 + q*4);
        *(u32x4*)(&uls[row*KP + q*4]) = v;
    }
    __syncthreads();

    // ---- GEMM: 256 m x 64 t x 192 k.  4 waves along m (4 mt each), t=64 per wave ----
    f32x4 acc[4][4];   // [ot][tt]
    #pragma unroll
    for (int i = 0; i < 4; ++i)
        #pragma unroll
        for (int j2 = 0; j2 < 4; ++j2) acc[i][j2] = f32x4{0,0,0,0};
    const char* smb = (const char*)uls;
    const int mtb = blockIdx.y*16 + wid*4;

    for (int kk = 0; kk < 6; ++kk) {
        int k0 = kk*32 + kg*8;
        bf16x8 bt[4];
        #pragma unroll
        for (int tt = 0; tt < 4; ++tt)
            bt[tt] = *(const bf16x8*)(smb + (size_t)(tt*16 + l15)*400 + k0*2);
        bf16x8 af[4];
        #pragma unroll
        for (int ot = 0; ot < 4; ++ot)
            af[ot] = *(const bf16x8*)(wpad + ((size_t)((mtb + ot)*6 + kk))*512 + lane*8);
        #pragma unroll
        for (int ot = 0; ot < 4; ++ot)
            #pragma unroll
            for (int tt = 0; tt < 4; ++tt)
                acc[ot][tt] = __builtin_amdgcn_mfma_f32_16x16x32_bf16(af[ot], bt[tt], acc[ot][tt], 0, 0, 0);
    }
    __syncthreads();   // staging dead; reuse LDS as P [t][m] bf16

    // ---- P[t][mloc] = bf16((acc + pjb)*mask), cvt_pk + u32x2 stores ----
    #pragma unroll
    for (int tt = 0; tt < 4; ++tt) {
        int t = tt*16 + l15;
        float mkv = masks[(size_t)b*NT + tg0 + t];
        #pragma unroll
        for (int ot = 0; ot < 4; ++ot) {
            int mloc = (wid*4 + ot)*16 + (kg << 2);
            f32x4 pb = *(const f32x4*)(pjb_pad + blockIdx.y*256 + mloc);
            f32x4 A = acc[ot][tt];
            *(u32x2*)(&uls[t*PR + (mloc >> 1)]) =
                u32x2{pk_bf16((A[0]+pb[0])*mkv, (A[1]+pb[1])*mkv),
                      pk_bf16((A[2]+pb[2])*mkv, (A[3]+pb[3])*mkv)};
        }
    }
    __syncthreads();

    // ---- spline: 8 c-channels x 64 t = 512 items, exactly 2 per thread ----
    float lsum = 0.f;
    #pragma unroll
    for (int rep = 0; rep < 2; ++rep) {
        int item = tid + rep*256;
        int cl = item >> 6, t = item & 63;
        int c  = blockIdx.y*8 + cl;
        int tg = tg0 + t;
        float m = masks[(size_t)b*NT + tg];

        // x0 flip copy (each (c,tg) covered exactly once across the grid)
        float x0v = x[((size_t)b*NC + c)*NT + tg];
        outp[((size_t)b*NC + (NC-1 - c))*NT + tg] = x0v * m;

        float pr[30];
        #pragma unroll
        for (int j = 0; j < 15; ++j) {
            u32 w = uls[t*PR + cl*16 + j];
            pr[2*j]   = __builtin_bit_cast(float, w << 16);
            pr[2*j+1] = __builtin_bit_cast(float, w & 0xffff0000u);
        }

        const float invsq = 0.07216878364870322f;  // 1/sqrt(192)
        float cw[11], chh[11];
        {   // width knots (no max-subtraction: |u| << 1 analytically)
            float e[10], s = 0.f;
            #pragma unroll
            for (int i = 0; i < 10; ++i) { e[i] = __expf(pr[i] * invsq); s += e[i]; }
            float inv_s = __builtin_amdgcn_rcpf(s);
            float run = 0.f;
            cw[0] = -5.f;
            #pragma unroll
            for (int i = 0; i < 10; ++i) {
                run += 0.001f + 0.99f * e[i] * inv_s;
                cw[i+1] = 10.f*run - 5.f;
            }
            cw[10] = 5.f;
        }
        {   // height knots
            float e[10], s = 0.f;
            #pragma unroll
            for (int i = 0; i < 10; ++i) { e[i] = __expf(pr[10+i] * invsq); s += e[i]; }
            float inv_s = __builtin_amdgcn_rcpf(s);
            float run = 0.f;
            chh[0] = -5.f;
            #pragma unroll
            for (int i = 0; i < 10; ++i) {
                run += 0.001f + 0.99f * e[i] * inv_s;
                chh[i+1] = 10.f*run - 5.f;
            }
            chh[10] = 5.f;
        }

        float x1 = x[((size_t)b*NC + NHALF + c)*NT + tg];
        float xc = fminf(fmaxf(x1, -5.f), 5.f);
        int cnt = 0;
        #pragma unroll
        for (int i = 0; i < 11; ++i) cnt += (xc >= cw[i]) ? 1 : 0;
        int kidx = cnt - 1;
        kidx = kidx < 0 ? 0 : (kidx > 9 ? 9 : kidx);

        float icw=0.f, iw=1.f, ich=0.f, ih=0.f, s0=0.f, s1=0.f;
        #pragma unroll
        for (int i = 0; i < 10; ++i) {
            if (i == kidx) {
                icw = cw[i]; iw = cw[i+1]-cw[i];
                ich = chh[i]; ih = chh[i+1]-chh[i];
                s0 = (i >= 1) ? pr[19+i] : 0.f;
                s1 = (i <= 8) ? pr[20+i] : 0.f;
            }
        }
        float d0 = (kidx == 0) ? 1.f : 0.001f + softplus_fast(s0);
        float d1 = (kidx == 9) ? 1.f : 0.001f + softplus_fast(s1);

        float rw    = __builtin_amdgcn_rcpf(iw);
        float dlt   = ih * rw;
        float theta = (xc - icw) * rw;
        float t1m   = theta * (1.f - theta);
        float den   = dlt + (d0 + d1 - 2.f*dlt) * t1m;
        float rden  = __builtin_amdgcn_rcpf(den);
        float num   = ih * (dlt*theta*theta + d0*t1m);
        float outv  = ich + num * rden;
        float omt   = 1.f - theta;
        float dnum  = dlt*dlt*(d1*theta*theta + 2.f*dlt*t1m + d0*omt*omt);
        float lad   = __logf(dnum * rden * rden);
        bool inside = (x1 >= -5.f) && (x1 <= 5.f);
        float xout  = inside ? outv : x1;
        float ladv  = inside ? lad : 0.f;
        outp[((size_t)b*NC + (NHALF-1 - c))*NT + tg] = xout * m;
        lsum += ladv * m;
    }

    // ---- wave-shuffle reduction, then 4-way cross-wave sum ----
    #pragma unroll
    for (int off = 32; off > 0; off >>= 1)
        lsum += __shfl_down(lsum, off, 64);
    if (lane == 0) red4[wid] = lsum;
    __syncthreads();
    if (tid == 0)
        partial[(size_t)b*384 + th*192 + blockIdx.y*16 + blockIdx.x] =
            red4[0] + red4[1] + red4[2] + red4[3];
}

__global__ __launch_bounds__(256) void logdet_reduce_kernel(
    const float* __restrict__ partial, float* __restrict__ outp)
{
    __shared__ float red[256];
    const int b = blockIdx.x;
    const int tid = threadIdx.x;
    float s = 0.f;
    for (int i = tid; i < 384; i += 256) s += partial[(size_t)b*384 + i];
    red[tid] = s;
    __syncthreads();
    for (int st = 128; st > 0; st >>= 1) {
        if (tid < st) red[tid] += red[tid + st];
        __syncthreads();
    }
    if (tid == 0) outp[(size_t)OUT_ELEMS + b] = red[0];
}

extern "C" void kernel_launch(void* const* d_in, const int* in_sizes, int n_in,
                              void* d_out, int out_size, void* d_ws, size_t ws_size,
                              hipStream_t stream) {
    const float* x     = (const float*)d_in[0];
    const float* cond  = (const float*)d_in[1];
    const float* masks = (const float*)d_in[2];
    const float* pw    = (const float*)d_in[3];
    const float* pb    = (const float*)d_in[4];
    const float* w1    = (const float*)d_in[5];
    const float* b1    = (const float*)d_in[6];
    const float* g1    = (const float*)d_in[7];
    const float* bb1   = (const float*)d_in[8];
    const float* m1    = (const float*)d_in[9];
    const float* v1    = (const float*)d_in[10];
    const float* w2    = (const float*)d_in[11];
    const float* b2    = (const float*)d_in[12];
    const float* g2    = (const float*)d_in[13];
    const float* bb2   = (const float*)d_in[14];
    const float* m2    = (const float*)d_in[15];
    const float* v2    = (const float*)d_in[16];
    const float* pjw   = (const float*)d_in[17];
    const float* pjb   = (const float*)d_in[18];

    float* out = (float*)d_out;
    char* wsb = (char*)d_ws;
    float* hidT    = (float*)wsb;                                  // 12,582,912 B
    u16*   wbf     = (u16*)(wsb + 12582912);                       //  2,101,248 B
    float* pjb_pad = (float*)(wsb + 12582912 + 2101248);           //     12,288 B
    float* partial = (float*)(wsb + 12582912 + 2101248 + 12288);   //     16,384 B
    u32*   hidB0   = (u32*)(wsb + 14712832);                       //  6,291,456 B
    u32*   hidB1   = (u32*)(wsb + 14712832 + 6291456);             //  6,291,456 B

    dim3 blk(256);

    wconv_kernel<<<dim3((WT2 + 3072 + 255)/256), blk, 0, stream>>>(
        w1, w2, pjw, pjb, pw, wbf, pjb_pad);

    const u16* preswz = wbf + W1N + W2N + PADN;
    prenet_mfma_kernel<<<dim3(64,1,8), blk, 0, stream>>>(
        x, cond, preswz, pb, masks, hidT, hidB0);

    dim3 grid_r(64, 1, 8);
    {
        const u16* w1l = wbf;
        const u16* w2l = wbf + W1N;
        resblock_kernel<1><<<grid_r, blk, 0, stream>>>(hidT, hidB0, hidB1, w1l, w2l, masks,
            b1, g1, bb1, m1, v1, b2, g2, bb2, m2, v2);
    }
    {
        const u16* w1l = wbf + (size_t)1*110592;
        const u16* w2l = wbf + W1N + (size_t)1*36864;
        resblock_kernel<3><<<grid_r, blk, 0, stream>>>(hidT, hidB1, hidB0, w1l, w2l, masks,
            b1+NC, g1+NC, bb1+NC, m1+NC, v1+NC, b2+NC, g2+NC, bb2+NC, m2+NC, v2+NC);
    }
    {
        const u16* w1l = wbf + (size_t)2*110592;
        const u16* w2l = wbf + W1N + (size_t)2*36864;
        resblock_kernel<9><<<grid_r, blk, 0, stream>>>(hidT, hidB0, hidB1, w1l, w2l, masks,
            b1+2*NC, g1+2*NC, bb1+2*NC, m1+2*NC, v1+2*NC,
            b2+2*NC, g2+2*NC, bb2+2*NC, m2+2*NC, v2+2*NC);
    }

    const u16* pjwpad = wbf + W1N + W2N;
    proj_spline_mfma_kernel<<<dim3(16,12,16), blk, 0, stream>>>(
        hidB1, pjwpad, pjb_pad, x, masks, out, partial);

    logdet_reduce_kernel<<<dim3(8), blk, 0, stream>>>(partial, out);
}

// Round 18
// 117.839 us; speedup vs baseline: 7.9760x; 1.0726x over previous
//
#include <hip/hip_runtime.h>
#include <math.h>

#define NB 8
#define NC 192
#define NT 2048
#define NHALF 96
#define NP 29
#define OUT_ELEMS (NB*NC*NT)
#define KP 100    // staging LDS row stride in dwords (200 bf16, 192 used)
#define PR 129    // P LDS row stride in dwords ([t][m] bf16, 256 m + pad)

typedef short bf16x8 __attribute__((ext_vector_type(8)));
typedef float f32x4 __attribute__((ext_vector_type(4)));
typedef unsigned int u32x2 __attribute__((ext_vector_type(2)));
typedef unsigned int u32x4 __attribute__((ext_vector_type(4)));
typedef unsigned short u16;
typedef unsigned int u32;

__device__ __forceinline__ u16 f2bf(float f) {
    u32 u = __builtin_bit_cast(u32, f);
    u += 0x7fffu + ((u >> 16) & 1u);
    return (u16)(u >> 16);
}
// packed f32 pair -> 2x bf16 in one instruction (RNE, same as f2bf)
__device__ __forceinline__ u32 pk_bf16(float lo, float hi) {
    u32 r;
    asm("v_cvt_pk_bf16_f32 %0, %1, %2" : "=v"(r) : "v"(lo), "v"(hi));
    return r;
}
__device__ __forceinline__ float softplus_fast(float v) {
    return (v > 20.0f) ? v : __logf(1.0f + __expf(v));
}
// mish(x) = x*tanh(softplus(x)) = x*(s^2-1)/(s^2+1), s = 1+e^x
__device__ __forceinline__ float mishf(float v) {
    if (v > 20.0f) return v;
    float s = 1.0f + __expf(v);
    float s2 = s * s;
    return v * (s2 - 1.0f) / (s2 + 1.0f);
}

// ---------- weight convert + fragment swizzle ----------
// swz[tile*512 + lane*8 + e] = W[m][k], m = mt*16+(lane&15), k = kk*32+(lane>>4)*8+e
#define W1N 331776   // 3*3*36864
#define W2N 110592   // 3*36864
#define PADN 589824  // 1152*512
#define PREN 18432   // 36*512
#define WT2 (W1N+W2N+PADN+PREN)
__global__ __launch_bounds__(256) void wconv_kernel(
    const float* __restrict__ w1, const float* __restrict__ w2,
    const float* __restrict__ pjw, const float* __restrict__ pjb,
    const float* __restrict__ pw,
    u16* __restrict__ outw, float* __restrict__ pjb_pad)
{
    int i = blockIdx.x*256 + threadIdx.x;
    if (i < WT2) {
        float v;
        if (i < W1N) {
            int s = i / 110592, r = i % 110592;
            int j = r / 36864, q = r % 36864;
            int tile = q >> 9, lane = (q >> 3) & 63, e = q & 7;
            int mt = tile / 6, kk = tile % 6;
            int m = mt*16 + (lane & 15);
            int k = kk*32 + (lane >> 4)*8 + e;
            v = w1[(((size_t)s*192 + m)*192 + k)*3 + j];
        } else if (i < W1N + W2N) {
            int q0 = i - W1N;
            int s = q0 / 36864, q = q0 % 36864;
            int tile = q >> 9, lane = (q >> 3) & 63, e = q & 7;
            int mt = tile / 6, kk = tile % 6;
            int m = mt*16 + (lane & 15);
            int k = kk*32 + (lane >> 4)*8 + e;
            v = w2[((size_t)s*192 + m)*192 + k];
        } else if (i < W1N + W2N + PADN) {
            int q = i - W1N - W2N;
            int tile = q >> 9, lane = (q >> 3) & 63, e = q & 7;
            int mt = tile / 6, kk = tile % 6;
            int m = mt*16 + (lane & 15);            // 0..3071
            int k = kk*32 + (lane >> 4)*8 + e;
            int c = m >> 5, p = m & 31;
            v = (p < NP) ? pjw[((size_t)(c*NP + p))*192 + k] : 0.f;
        } else {
            int q = i - W1N - W2N - PADN;
            int tile = q >> 9, lane = (q >> 3) & 63, e = q & 7;
            int mt = tile / 3, kk = tile % 3;
            int m = mt*16 + (lane & 15);            // 0..191
            int k = kk*32 + (lane >> 4)*8 + e;      // 0..95
            v = pw[(size_t)m*96 + k];
        }
        outw[i] = f2bf(v);
    } else if (i < WT2 + 3072) {
        int mp = i - WT2;
        int c = mp >> 5, p = mp & 31;
        pjb_pad[mp] = (p < NP) ? pjb[c*NP + p] : 0.f;
    }
}

// ---------- prenet MFMA: hidT/hidB = W(192x96) x0 + bias + cond ----------
__global__ __launch_bounds__(256) void prenet_mfma_kernel(
    const float* __restrict__ x, const float* __restrict__ cond,
    const u16* __restrict__ wps, const float* __restrict__ bias,
    const float* __restrict__ masks,
    float* __restrict__ hidT, u32* __restrict__ hidB)
{
    __shared__ u32 sm[32 * 52];
    const int tid = threadIdx.x, lane = tid & 63, wid = tid >> 6;
    const int b = blockIdx.z, tg0 = blockIdx.x * 32;
    const int l15 = lane & 15, kg = lane >> 4;

    for (int idx = tid; idx < 48*32; idx += 256) {
        int c2 = idx >> 5, tl = idx & 31;
        const float* p = x + ((size_t)b*NC + 2*c2)*NT + tg0 + tl;
        sm[tl*52 + c2] = pk_bf16(p[0], p[NT]);
    }
    __syncthreads();

    // bias-init accumulators (MFMA C-in carries bias)
    f32x4 acc[3][2];
    #pragma unroll
    for (int ot = 0; ot < 3; ++ot) {
        f32x4 bi = *(const f32x4*)(bias + (wid*3 + ot)*16 + (kg << 2));
        acc[ot][0] = bi; acc[ot][1] = bi;
    }
    const char* smb = (const char*)sm;

    for (int kk = 0; kk < 3; ++kk) {
        int k0 = kk*32 + kg*8;
        bf16x8 b0 = *(const bf16x8*)(smb + (size_t)l15*208 + k0*2);
        bf16x8 b1f = *(const bf16x8*)(smb + (size_t)(l15+16)*208 + k0*2);
        bf16x8 af[3];
        #pragma unroll
        for (int ot = 0; ot < 3; ++ot) {
            int mt = wid*3 + ot;
            af[ot] = *(const bf16x8*)(wps + ((size_t)(mt*3 + kk))*512 + lane*8);
        }
        #pragma unroll
        for (int ot = 0; ot < 3; ++ot) {
            acc[ot][0] = __builtin_amdgcn_mfma_f32_16x16x32_bf16(af[ot], b0, acc[ot][0], 0, 0, 0);
            acc[ot][1] = __builtin_amdgcn_mfma_f32_16x16x32_bf16(af[ot], b1f, acc[ot][1], 0, 0, 0);
        }
    }

    #pragma unroll
    for (int ot = 0; ot < 3; ++ot) {
        int m = (wid*3 + ot)*16 + (kg << 2);
        #pragma unroll
        for (int tt = 0; tt < 2; ++tt) {
            int t = tg0 + tt*16 + l15;
            float mv = masks[(size_t)b*NT + t];
            f32x4 A = acc[ot][tt];
            f32x4 o;
            #pragma unroll
            for (int r = 0; r < 4; ++r)
                o[r] = A[r] + cond[((size_t)b*NC + m + r)*NT + t];
            *(f32x4*)(hidT + ((size_t)b*NT + t)*NC + m) = o;
            *(u32x2*)(hidB + ((size_t)b*NT + t)*96 + (m >> 1)) =
                u32x2{pk_bf16(o[0]*mv, o[1]*mv), pk_bf16(o[2]*mv, o[3]*mv)};
        }
    }
}

// ---------- fused residual block (TT=32), hidB chain + A-prefetch ----------
template<int DIL>
__global__ __launch_bounds__(256) void resblock_kernel(
    float* __restrict__ hidT, const u32* __restrict__ hidBin, u32* __restrict__ hidBout,
    const u16* __restrict__ w1s, const u16* __restrict__ w2s,
    const float* __restrict__ masks,
    const float* __restrict__ b1v, const float* __restrict__ g1v, const float* __restrict__ bb1v,
    const float* __restrict__ bm1v, const float* __restrict__ bv1v,
    const float* __restrict__ b2v, const float* __restrict__ g2v, const float* __restrict__ bb2v,
    const float* __restrict__ bm2v, const float* __restrict__ bv2v)
{
    constexpr int ROWS = 32 + 2*DIL;
    __shared__ u32 sm1[ROWS * KP];
    __shared__ u32 sm2[32 * KP];
    const int tid = threadIdx.x, lane = tid & 63, wid = tid >> 6;
    const int b = blockIdx.z, tg0 = blockIdx.x * 32;
    const int l15 = lane & 15, kg = lane >> 4;

    // stage pre-masked bf16 rows from hidBin: pure 16B copies
    for (int it = tid; it < ROWS*24; it += 256) {
        int row = it / 24, q = it - row*24;
        int t = tg0 + row - DIL;
        u32x4 v = u32x4{0,0,0,0};
        if (t >= 0 && t < NT)
            v = *(const u32x4*)(hidBin + ((size_t)b*NT + t)*96 + q*4);
        *(u32x4*)(&sm1[row*KP + q*4]) = v;
    }
    __syncthreads();

    // GEMM1 (bias-init acc), A-prefetch across 18 iters
    f32x4 acc[3][2];
    #pragma unroll
    for (int ot = 0; ot < 3; ++ot) {
        f32x4 bi = *(const f32x4*)(b1v + (wid*3 + ot)*16 + (kg << 2));
        acc[ot][0] = bi; acc[ot][1] = bi;
    }
    const char* smb1 = (const char*)sm1;

    bf16x8 afc[3], afn[3];
    #pragma unroll
    for (int ot = 0; ot < 3; ++ot)
        afc[ot] = *(const bf16x8*)(w1s + ((size_t)((wid*3 + ot)*6))*512 + lane*8);

    #pragma unroll
    for (int it = 0; it < 18; ++it) {
        const int j = it / 6, kk = it % 6;
        if (it + 1 < 18) {
            const int jn = (it + 1) / 6, kkn = (it + 1) % 6;
            const u16* wn = w1s + (size_t)jn * 36864;
            #pragma unroll
            for (int ot = 0; ot < 3; ++ot)
                afn[ot] = *(const bf16x8*)(wn + ((size_t)((wid*3 + ot)*6 + kkn))*512 + lane*8);
        }
        int k0 = kk*32 + kg*8;
        bf16x8 b0  = *(const bf16x8*)(smb1 + (size_t)(l15 + j*DIL)*400 + k0*2);
        bf16x8 b1f = *(const bf16x8*)(smb1 + (size_t)(l15 + 16 + j*DIL)*400 + k0*2);
        #pragma unroll
        for (int ot = 0; ot < 3; ++ot) {
            acc[ot][0] = __builtin_amdgcn_mfma_f32_16x16x32_bf16(afc[ot], b0,  acc[ot][0], 0, 0, 0);
            acc[ot][1] = __builtin_amdgcn_mfma_f32_16x16x32_bf16(afc[ot], b1f, acc[ot][1], 0, 0, 0);
        }
        #pragma unroll
        for (int ot = 0; ot < 3; ++ot) afc[ot] = afn[ot];
    }

    // epilogue1: tmp = BN1(mish(acc)) -> sm2 [t][k] bf16 pairs
    #pragma unroll
    for (int ot = 0; ot < 3; ++ot) {
        int m = (wid*3 + ot)*16 + (kg << 2);
        f32x4 g4 = *(const f32x4*)(g1v + m);
        f32x4 bb4 = *(const f32x4*)(bb1v + m);
        f32x4 bm4 = *(const f32x4*)(bm1v + m);
        f32x4 bv4 = *(const f32x4*)(bv1v + m);
        #pragma unroll
        for (int tt = 0; tt < 2; ++tt) {
            int tl = tt*16 + l15;
            f32x4 A = acc[ot][tt];
            float vr[4];
            #pragma unroll
            for (int r = 0; r < 4; ++r) {
                float v = mishf(A[r]);
                vr[r] = (v - bm4[r]) * (g4[r] * rsqrtf(bv4[r] + 1e-5f)) + bb4[r];
            }
            *(u32x2*)(&sm2[tl*KP + (m >> 1)]) = u32x2{pk_bf16(vr[0], vr[1]), pk_bf16(vr[2], vr[3])};
        }
    }
    __syncthreads();

    // GEMM2 (bias-init acc), A-prefetch across 6 iters
    f32x4 acc2[3][2];
    #pragma unroll
    for (int ot = 0; ot < 3; ++ot) {
        f32x4 bi = *(const f32x4*)(b2v + (wid*3 + ot)*16 + (kg << 2));
        acc2[ot][0] = bi; acc2[ot][1] = bi;
    }
    const char* smb2 = (const char*)sm2;

    #pragma unroll
    for (int ot = 0; ot < 3; ++ot)
        afc[ot] = *(const bf16x8*)(w2s + ((size_t)((wid*3 + ot)*6))*512 + lane*8);

    #pragma unroll
    for (int kk = 0; kk < 6; ++kk) {
        if (kk + 1 < 6) {
            #pragma unroll
            for (int ot = 0; ot < 3; ++ot)
                afn[ot] = *(const bf16x8*)(w2s + ((size_t)((wid*3 + ot)*6 + kk + 1))*512 + lane*8);
        }
        int k0 = kk*32 + kg*8;
        bf16x8 b0  = *(const bf16x8*)(smb2 + (size_t)l15*400 + k0*2);
        bf16x8 b1f = *(const bf16x8*)(smb2 + (size_t)(l15+16)*400 + k0*2);
        #pragma unroll
        for (int ot = 0; ot < 3; ++ot) {
            acc2[ot][0] = __builtin_amdgcn_mfma_f32_16x16x32_bf16(afc[ot], b0,  acc2[ot][0], 0, 0, 0);
            acc2[ot][1] = __builtin_amdgcn_mfma_f32_16x16x32_bf16(afc[ot], b1f, acc2[ot][1], 0, 0, 0);
        }
        #pragma unroll
        for (int ot = 0; ot < 3; ++ot) afc[ot] = afn[ot];
    }

    // epilogue2: hidT += BN2(mish(acc2)); emit hidBout = bf16(new*mask)
    #pragma unroll
    for (int ot = 0; ot < 3; ++ot) {
        int m = (wid*3 + ot)*16 + (kg << 2);
        f32x4 g4 = *(const f32x4*)(g2v + m);
        f32x4 bb4 = *(const f32x4*)(bb2v + m);
        f32x4 bm4 = *(const f32x4*)(bm2v + m);
        f32x4 bv4 = *(const f32x4*)(bv2v + m);
        #pragma unroll
        for (int tt = 0; tt < 2; ++tt) {
            int t = tg0 + tt*16 + l15;
            float mv = masks[(size_t)b*NT + t];
            f32x4 A = acc2[ot][tt];
            float* dst = hidT + ((size_t)b*NT + t)*NC + m;
            f32x4 old = *(const f32x4*)dst;
            f32x4 nv;
            #pragma unroll
            for (int r = 0; r < 4; ++r) {
                float v = mishf(A[r]);
                nv[r] = old[r] + ((v - bm4[r]) * (g4[r] * rsqrtf(bv4[r] + 1e-5f)) + bb4[r]);
            }
            *(f32x4*)dst = nv;
            *(u32x2*)(hidBout + ((size_t)b*NT + t)*96 + (m >> 1)) =
                u32x2{pk_bf16(nv[0]*mv, nv[1]*mv), pk_bf16(nv[2]*mv, nv[3]*mv)};
        }
    }
}

// ---------- fused proj GEMM (M=256/block) + RQ spline + x0-flip + lad ----------
// grid (16 t-tiles, 12 m-blocks(=8c each), 16 units(b,th)), block 256
__global__ __launch_bounds__(256) void proj_spline_mfma_kernel(
    const u32* __restrict__ hidB, const u16* __restrict__ wpad,
    const float* __restrict__ pjb_pad, const float* __restrict__ x,
    const float* __restrict__ masks, float* __restrict__ outp,
    float* __restrict__ partial)
{
    __shared__ u32 uls[64*PR];   // union: staging [64][KP] then P [64 t][258 u16]
    __shared__ float red4[4];
    const int tid  = threadIdx.x;
    const int lane = tid & 63;
    const int wid  = tid >> 6;
    const int z  = blockIdx.z;
    const int b  = z >> 1, th = z & 1;
    const int tg0 = th*1024 + blockIdx.x*64;
    const int l15 = lane & 15;
    const int kg  = lane >> 4;

    // ---- stage B tile: pre-masked bf16 from hidB, pure 16B copies ----
    for (int it = tid; it < 64*24; it += 256) {
        int row = it / 24, q = it - row*24;
        u32x4 v = *(const u32x4*)(hidB + ((size_t)b*NT + tg0 + row)*96 + q*4);
        *(u32x4*)(&uls[row*KP + q*4]) = v;
    }
    __syncthreads();

    // ---- GEMM: 256 m x 64 t x 192 k, bias-init acc ----
    f32x4 acc[4][4];   // [ot][tt]
    const int mtb = blockIdx.y*16 + wid*4;
    #pragma unroll
    for (int ot = 0; ot < 4; ++ot) {
        f32x4 pb = *(const f32x4*)(pjb_pad + blockIdx.y*256 + (wid*4 + ot)*16 + (kg << 2));
        #pragma unroll
        for (int tt = 0; tt < 4; ++tt) acc[ot][tt] = pb;
    }
    const char* smb = (const char*)uls;

    for (int kk = 0; kk < 6; ++kk) {
        int k0 = kk*32 + kg*8;
        bf16x8 bt[4];
        #pragma unroll
        for (int tt = 0; tt < 4; ++tt)
            bt[tt] = *(const bf16x8*)(smb + (size_t)(tt*16 + l15)*400 + k0*2);
        bf16x8 af[4];
        #pragma unroll
        for (int ot = 0; ot < 4; ++ot)
            af[ot] = *(const bf16x8*)(wpad + ((size_t)((mtb + ot)*6 + kk))*512 + lane*8);
        #pragma unroll
        for (int ot = 0; ot < 4; ++ot)
            #pragma unroll
            for (int tt = 0; tt < 4; ++tt)
                acc[ot][tt] = __builtin_amdgcn_mfma_f32_16x16x32_bf16(af[ot], bt[tt], acc[ot][tt], 0, 0, 0);
    }
    __syncthreads();   // staging dead; reuse LDS as P [t][m] bf16

    // ---- P[t][mloc] = bf16(acc*mask), cvt_pk + u32x2 stores ----
    #pragma unroll
    for (int tt = 0; tt < 4; ++tt) {
        int t = tt*16 + l15;
        float mkv = masks[(size_t)b*NT + tg0 + t];
        #pragma unroll
        for (int ot = 0; ot < 4; ++ot) {
            int mloc = (wid*4 + ot)*16 + (kg << 2);
            f32x4 A = acc[ot][tt];
            *(u32x2*)(&uls[t*PR + (mloc >> 1)]) =
                u32x2{pk_bf16(A[0]*mkv, A[1]*mkv), pk_bf16(A[2]*mkv, A[3]*mkv)};
        }
    }
    __syncthreads();

    // ---- spline: 8 c-channels x 64 t = 512 items, exactly 2 per thread ----
    float lsum = 0.f;
    #pragma unroll
    for (int rep = 0; rep < 2; ++rep) {
        int item = tid + rep*256;
        int cl = item >> 6, t = item & 63;
        int c  = blockIdx.y*8 + cl;
        int tg = tg0 + t;
        float m = masks[(size_t)b*NT + tg];

        // x0 flip copy
        float x0v = x[((size_t)b*NC + c)*NT + tg];
        outp[((size_t)b*NC + (NC-1 - c))*NT + tg] = x0v * m;

        float pr[30];
        #pragma unroll
        for (int j = 0; j < 15; ++j) {
            u32 w = uls[t*PR + cl*16 + j];
            pr[2*j]   = __builtin_bit_cast(float, w << 16);
            pr[2*j+1] = __builtin_bit_cast(float, w & 0xffff0000u);
        }

        float x1 = x[((size_t)b*NC + NHALF + c)*NT + tg];
        float xc = fminf(fmaxf(x1, -5.f), 5.f);

        // exp2 constant-fold: exp(pr*invsq) = exp2(pr * invsq*log2e)
        const float C = 0.10412020934368074f;  // (1/sqrt(192)) * log2(e)
        float ew[10], eh[10], sw = 0.f, sh = 0.f;
        #pragma unroll
        for (int i = 0; i < 10; ++i) { ew[i] = __builtin_amdgcn_exp2f(pr[i]    * C); sw += ew[i]; }
        #pragma unroll
        for (int i = 0; i < 10; ++i) { eh[i] = __builtin_amdgcn_exp2f(pr[10+i] * C); sh += eh[i]; }
        float isw = __builtin_amdgcn_rcpf(sw) * 9.9f;   // step = 0.01 + 9.9*e*inv_s
        float ish = __builtin_amdgcn_rcpf(sh) * 9.9f;

        // fused cumsum + knot selection (forced endpoints preserved)
        float cwp = -5.f, chp = -5.f;
        float icw = -5.f, ich = -5.f, iw = 0.f, ih = 0.f;
        float s0 = 0.f, s1 = pr[20], f0 = 1.f, f9 = 0.f;
        #pragma unroll
        for (int i = 0; i < 10; ++i) {
            float stepw = 0.01f + ew[i]*isw;
            float steph = 0.01f + eh[i]*ish;
            if (i == 9) { stepw = 5.f - cwp; steph = 5.f - chp; }  // forced cw[10]=5
            if (i == 0) {
                iw = stepw; ih = steph;
            } else {
                bool ge = (xc >= cwp);
                icw = ge ? cwp   : icw;
                iw  = ge ? stepw : iw;
                ich = ge ? chp   : ich;
                ih  = ge ? steph : ih;
                s0  = ge ? pr[19+i] : s0;
                if (i <= 8) s1 = ge ? pr[20+i] : s1;
                f0  = ge ? 0.f : f0;
                if (i == 9) f9 = ge ? 1.f : 0.f;
            }
            cwp += stepw; chp += steph;
        }
        float d0 = (f0 != 0.f) ? 1.f : 0.001f + softplus_fast(s0);
        float d1 = (f9 != 0.f) ? 1.f : 0.001f + softplus_fast(s1);

        float rw    = __builtin_amdgcn_rcpf(iw);
        float dlt   = ih * rw;
        float theta = (xc - icw) * rw;
        float t1m   = theta * (1.f - theta);
        float den   = dlt + (d0 + d1 - 2.f*dlt) * t1m;
        float rden  = __builtin_amdgcn_rcpf(den);
        float num   = ih * (dlt*theta*theta + d0*t1m);
        float outv  = ich + num * rden;
        float omt   = 1.f - theta;
        float dnum  = dlt*dlt*(d1*theta*theta + 2.f*dlt*t1m + d0*omt*omt);
        float lad   = __logf(dnum * rden * rden);
        bool inside = (x1 >= -5.f) && (x1 <= 5.f);
        float xout  = inside ? outv : x1;
        float ladv  = inside ? lad : 0.f;
        outp[((size_t)b*NC + (NHALF-1 - c))*NT + tg] = xout * m;
        lsum += ladv * m;
    }

    // ---- wave-shuffle reduction, then 4-way cross-wave sum ----
    #pragma unroll
    for (int off = 32; off > 0; off >>= 1)
        lsum += __shfl_down(lsum, off, 64);
    if (lane == 0) red4[wid] = lsum;
    __syncthreads();
    if (tid == 0)
        partial[(size_t)b*384 + th*192 + blockIdx.y*16 + blockIdx.x] =
            red4[0] + red4[1] + red4[2] + red4[3];
}

__global__ __launch_bounds__(256) void logdet_reduce_kernel(
    const float* __restrict__ partial, float* __restrict__ outp)
{
    __shared__ float red[256];
    const int b = blockIdx.x;
    const int tid = threadIdx.x;
    float s = 0.f;
    for (int i = tid; i < 384; i += 256) s += partial[(size_t)b*384 + i];
    red[tid] = s;
    __syncthreads();
    for (int st = 128; st > 0; st >>= 1) {
        if (tid < st) red[tid] += red[tid + st];
        __syncthreads();
    }
    if (tid == 0) outp[(size_t)OUT_ELEMS + b] = red[0];
}

extern "C" void kernel_launch(void* const* d_in, const int* in_sizes, int n_in,
                              void* d_out, int out_size, void* d_ws, size_t ws_size,
                              hipStream_t stream) {
    const float* x     = (const float*)d_in[0];
    const float* cond  = (const float*)d_in[1];
    const float* masks = (const float*)d_in[2];
    const float* pw    = (const float*)d_in[3];
    const float* pb    = (const float*)d_in[4];
    const float* w1    = (const float*)d_in[5];
    const float* b1    = (const float*)d_in[6];
    const float* g1    = (const float*)d_in[7];
    const float* bb1   = (const float*)d_in[8];
    const float* m1    = (const float*)d_in[9];
    const float* v1    = (const float*)d_in[10];
    const float* w2    = (const float*)d_in[11];
    const float* b2    = (const float*)d_in[12];
    const float* g2    = (const float*)d_in[13];
    const float* bb2   = (const float*)d_in[14];
    const float* m2    = (const float*)d_in[15];
    const float* v2    = (const float*)d_in[16];
    const float* pjw   = (const float*)d_in[17];
    const float* pjb   = (const float*)d_in[18];

    float* out = (float*)d_out;
    char* wsb = (char*)d_ws;
    float* hidT    = (float*)wsb;                                  // 12,582,912 B
    u16*   wbf     = (u16*)(wsb + 12582912);                       //  2,101,248 B
    float* pjb_pad = (float*)(wsb + 12582912 + 2101248);           //     12,288 B
    float* partial = (float*)(wsb + 12582912 + 2101248 + 12288);   //     16,384 B
    u32*   hidB0   = (u32*)(wsb + 14712832);                       //  6,291,456 B
    u32*   hidB1   = (u32*)(wsb + 14712832 + 6291456);             //  6,291,456 B

    dim3 blk(256);

    wconv_kernel<<<dim3((WT2 + 3072 + 255)/256), blk, 0, stream>>>(
        w1, w2, pjw, pjb, pw, wbf, pjb_pad);

    const u16* preswz = wbf + W1N + W2N + PADN;
    prenet_mfma_kernel<<<dim3(64,1,8), blk, 0, stream>>>(
        x, cond, preswz, pb, masks, hidT, hidB0);

    dim3 grid_r(64, 1, 8);
    {
        resblock_kernel<1><<<grid_r, blk, 0, stream>>>(hidT, hidB0, hidB1, wbf, wbf + W1N, masks,
            b1, g1, bb1, m1, v1, b2, g2, bb2, m2, v2);
    }
    {
        const u16* w1l = wbf + (size_t)1*110592;
        const u16* w2l = wbf + W1N + (size_t)1*36864;
        resblock_kernel<3><<<grid_r, blk, 0, stream>>>(hidT, hidB1, hidB0, w1l, w2l, masks,
            b1+NC, g1+NC, bb1+NC, m1+NC, v1+NC, b2+NC, g2+NC, bb2+NC, m2+NC, v2+NC);
    }
    {
        const u16* w1l = wbf + (size_t)2*110592;
        const u16* w2l = wbf + W1N + (size_t)2*36864;
        resblock_kernel<9><<<grid_r, blk, 0, stream>>>(hidT, hidB0, hidB1, w1l, w2l, masks,
            b1+2*NC, g1+2*NC, bb1+2*NC, m1+2*NC, v1+2*NC,
            b2+2*NC, g2+2*NC, bb2+2*NC, m2+2*NC, v2+2*NC);
    }

    const u16* pjwpad = wbf + W1N + W2N;
    proj_spline_mfma_kernel<<<dim3(16,12,16), blk, 0, stream>>>(
        hidB1, pjwpad, pjb_pad, x, masks, out, partial);

    logdet_reduce_kernel<<<dim3(8), blk, 0, stream>>>(partial, out);
}

// Round 21
// 108.174 us; speedup vs baseline: 8.6886x; 1.0893x over previous
//
#include <hip/hip_runtime.h>
#include <math.h>

#define NB 8
#define NC 192
#define NT 2048
#define NHALF 96
#define NP 29
#define OUT_ELEMS (NB*NC*NT)
#define KP 100    // staging LDS row stride in dwords (200 bf16, 192 used)
#define PR 129    // P LDS row stride in dwords ([t][m] bf16, 256 m + pad)

typedef short bf16x8 __attribute__((ext_vector_type(8)));
typedef float f32x4 __attribute__((ext_vector_type(4)));
typedef unsigned int u32x2 __attribute__((ext_vector_type(2)));
typedef unsigned int u32x4 __attribute__((ext_vector_type(4)));
typedef unsigned short u16;
typedef unsigned int u32;

__device__ __forceinline__ u16 f2bf(float f) {
    u32 u = __builtin_bit_cast(u32, f);
    u += 0x7fffu + ((u >> 16) & 1u);
    return (u16)(u >> 16);
}
// packed f32 pair -> 2x bf16 in one instruction (RNE, same as f2bf)
__device__ __forceinline__ u32 pk_bf16(float lo, float hi) {
    u32 r;
    asm("v_cvt_pk_bf16_f32 %0, %1, %2" : "=v"(r) : "v"(lo), "v"(hi));
    return r;
}
__device__ __forceinline__ float bf_lo(u32 w) { return __builtin_bit_cast(float, w << 16); }
__device__ __forceinline__ float bf_hi(u32 w) { return __builtin_bit_cast(float, w & 0xffff0000u); }
__device__ __forceinline__ float softplus_fast(float v) {
    return (v > 20.0f) ? v : __logf(1.0f + __expf(v));
}
// mish(x) = x*tanh(softplus(x)) = x*(s^2-1)/(s^2+1), s = 1+e^x
__device__ __forceinline__ float mishf(float v) {
    if (v > 20.0f) return v;
    float s = 1.0f + __expf(v);
    float s2 = s * s;
    return v * (s2 - 1.0f) / (s2 + 1.0f);
}

// ---------- weight convert + fragment swizzle ----------
// swz[tile*512 + lane*8 + e] = W[m][k], m = mt*16+(lane&15), k = kk*32+(lane>>4)*8+e
#define W1N 331776   // 3*3*36864
#define W2N 110592   // 3*36864
#define PADN 589824  // 1152*512
#define PREN 18432   // 36*512
#define WT2 (W1N+W2N+PADN+PREN)
__global__ __launch_bounds__(256) void wconv_kernel(
    const float* __restrict__ w1, const float* __restrict__ w2,
    const float* __restrict__ pjw, const float* __restrict__ pjb,
    const float* __restrict__ pw,
    u16* __restrict__ outw, float* __restrict__ pjb_pad)
{
    int i = blockIdx.x*256 + threadIdx.x;
    if (i < WT2) {
        float v;
        if (i < W1N) {
            int s = i / 110592, r = i % 110592;
            int j = r / 36864, q = r % 36864;
            int tile = q >> 9, lane = (q >> 3) & 63, e = q & 7;
            int mt = tile / 6, kk = tile % 6;
            int m = mt*16 + (lane & 15);
            int k = kk*32 + (lane >> 4)*8 + e;
            v = w1[(((size_t)s*192 + m)*192 + k)*3 + j];
        } else if (i < W1N + W2N) {
            int q0 = i - W1N;
            int s = q0 / 36864, q = q0 % 36864;
            int tile = q >> 9, lane = (q >> 3) & 63, e = q & 7;
            int mt = tile / 6, kk = tile % 6;
            int m = mt*16 + (lane & 15);
            int k = kk*32 + (lane >> 4)*8 + e;
            v = w2[((size_t)s*192 + m)*192 + k];
        } else if (i < W1N + W2N + PADN) {
            int q = i - W1N - W2N;
            int tile = q >> 9, lane = (q >> 3) & 63, e = q & 7;
            int mt = tile / 6, kk = tile % 6;
            int m = mt*16 + (lane & 15);            // 0..3071
            int k = kk*32 + (lane >> 4)*8 + e;
            int c = m >> 5, p = m & 31;
            v = (p < NP) ? pjw[((size_t)(c*NP + p))*192 + k] : 0.f;
        } else {
            int q = i - W1N - W2N - PADN;
            int tile = q >> 9, lane = (q >> 3) & 63, e = q & 7;
            int mt = tile / 3, kk = tile % 3;
            int m = mt*16 + (lane & 15);            // 0..191
            int k = kk*32 + (lane >> 4)*8 + e;      // 0..95
            v = pw[(size_t)m*96 + k];
        }
        outw[i] = f2bf(v);
    } else if (i < WT2 + 3072) {
        int mp = i - WT2;
        int c = mp >> 5, p = mp & 31;
        pjb_pad[mp] = (p < NP) ? pjb[c*NP + p] : 0.f;
    }
}

// ---------- prenet MFMA: hidB = bf16((W x0 + bias + cond) * mask) ----------
__global__ __launch_bounds__(256) void prenet_mfma_kernel(
    const float* __restrict__ x, const float* __restrict__ cond,
    const u16* __restrict__ wps, const float* __restrict__ bias,
    const float* __restrict__ masks, u32* __restrict__ hidB)
{
    __shared__ u32 sm[32 * 52];
    const int tid = threadIdx.x, lane = tid & 63, wid = tid >> 6;
    const int b = blockIdx.z, tg0 = blockIdx.x * 32;
    const int l15 = lane & 15, kg = lane >> 4;

    for (int idx = tid; idx < 48*32; idx += 256) {
        int c2 = idx >> 5, tl = idx & 31;
        const float* p = x + ((size_t)b*NC + 2*c2)*NT + tg0 + tl;
        sm[tl*52 + c2] = pk_bf16(p[0], p[NT]);
    }
    __syncthreads();

    // bias-init accumulators (MFMA C-in carries bias)
    f32x4 acc[3][2];
    #pragma unroll
    for (int ot = 0; ot < 3; ++ot) {
        f32x4 bi = *(const f32x4*)(bias + (wid*3 + ot)*16 + (kg << 2));
        acc[ot][0] = bi; acc[ot][1] = bi;
    }
    const char* smb = (const char*)sm;

    for (int kk = 0; kk < 3; ++kk) {
        int k0 = kk*32 + kg*8;
        bf16x8 b0 = *(const bf16x8*)(smb + (size_t)l15*208 + k0*2);
        bf16x8 b1f = *(const bf16x8*)(smb + (size_t)(l15+16)*208 + k0*2);
        bf16x8 af[3];
        #pragma unroll
        for (int ot = 0; ot < 3; ++ot) {
            int mt = wid*3 + ot;
            af[ot] = *(const bf16x8*)(wps + ((size_t)(mt*3 + kk))*512 + lane*8);
        }
        #pragma unroll
        for (int ot = 0; ot < 3; ++ot) {
            acc[ot][0] = __builtin_amdgcn_mfma_f32_16x16x32_bf16(af[ot], b0, acc[ot][0], 0, 0, 0);
            acc[ot][1] = __builtin_amdgcn_mfma_f32_16x16x32_bf16(af[ot], b1f, acc[ot][1], 0, 0, 0);
        }
    }

    #pragma unroll
    for (int ot = 0; ot < 3; ++ot) {
        int m = (wid*3 + ot)*16 + (kg << 2);
        #pragma unroll
        for (int tt = 0; tt < 2; ++tt) {
            int t = tg0 + tt*16 + l15;
            float mv = masks[(size_t)b*NT + t];
            f32x4 A = acc[ot][tt];
            f32x4 o;
            #pragma unroll
            for (int r = 0; r < 4; ++r)
                o[r] = (A[r] + cond[((size_t)b*NC + m + r)*NT + t]) * mv;
            *(u32x2*)(hidB + ((size_t)b*NT + t)*96 + (m >> 1)) =
                u32x2{pk_bf16(o[0], o[1]), pk_bf16(o[2], o[3])};
        }
    }
}

// ---------- fused residual block (TT=32), bf16 masked trunk ----------
// hidM_new = hidM_old + mask * BN2(mish(conv2(BN1(mish(conv1(hidM))))))
// old value comes from sm1 (already staged) -- no global trunk RMW.
template<int DIL>
__global__ __launch_bounds__(256) void resblock_kernel(
    const u32* __restrict__ hidBin, u32* __restrict__ hidBout,
    const u16* __restrict__ w1s, const u16* __restrict__ w2s,
    const float* __restrict__ masks,
    const float* __restrict__ b1v, const float* __restrict__ g1v, const float* __restrict__ bb1v,
    const float* __restrict__ bm1v, const float* __restrict__ bv1v,
    const float* __restrict__ b2v, const float* __restrict__ g2v, const float* __restrict__ bb2v,
    const float* __restrict__ bm2v, const float* __restrict__ bv2v)
{
    constexpr int ROWS = 32 + 2*DIL;
    __shared__ u32 sm1[ROWS * KP];
    __shared__ u32 sm2[32 * KP];
    const int tid = threadIdx.x, lane = tid & 63, wid = tid >> 6;
    const int b = blockIdx.z, tg0 = blockIdx.x * 32;
    const int l15 = lane & 15, kg = lane >> 4;

    // stage pre-masked bf16 rows from hidBin: pure 16B copies
    for (int it = tid; it < ROWS*24; it += 256) {
        int row = it / 24, q = it - row*24;
        int t = tg0 + row - DIL;
        u32x4 v = u32x4{0,0,0,0};
        if (t >= 0 && t < NT)
            v = *(const u32x4*)(hidBin + ((size_t)b*NT + t)*96 + q*4);
        *(u32x4*)(&sm1[row*KP + q*4]) = v;
    }
    __syncthreads();

    // GEMM1 (bias-init acc), A-prefetch across 18 iters
    f32x4 acc[3][2];
    #pragma unroll
    for (int ot = 0; ot < 3; ++ot) {
        f32x4 bi = *(const f32x4*)(b1v + (wid*3 + ot)*16 + (kg << 2));
        acc[ot][0] = bi; acc[ot][1] = bi;
    }
    const char* smb1 = (const char*)sm1;

    bf16x8 afc[3], afn[3];
    #pragma unroll
    for (int ot = 0; ot < 3; ++ot)
        afc[ot] = *(const bf16x8*)(w1s + ((size_t)((wid*3 + ot)*6))*512 + lane*8);

    #pragma unroll
    for (int it = 0; it < 18; ++it) {
        const int j = it / 6, kk = it % 6;
        if (it + 1 < 18) {
            const int jn = (it + 1) / 6, kkn = (it + 1) % 6;
            const u16* wn = w1s + (size_t)jn * 36864;
            #pragma unroll
            for (int ot = 0; ot < 3; ++ot)
                afn[ot] = *(const bf16x8*)(wn + ((size_t)((wid*3 + ot)*6 + kkn))*512 + lane*8);
        }
        int k0 = kk*32 + kg*8;
        bf16x8 b0  = *(const bf16x8*)(smb1 + (size_t)(l15 + j*DIL)*400 + k0*2);
        bf16x8 b1f = *(const bf16x8*)(smb1 + (size_t)(l15 + 16 + j*DIL)*400 + k0*2);
        #pragma unroll
        for (int ot = 0; ot < 3; ++ot) {
            acc[ot][0] = __builtin_amdgcn_mfma_f32_16x16x32_bf16(afc[ot], b0,  acc[ot][0], 0, 0, 0);
            acc[ot][1] = __builtin_amdgcn_mfma_f32_16x16x32_bf16(afc[ot], b1f, acc[ot][1], 0, 0, 0);
        }
        #pragma unroll
        for (int ot = 0; ot < 3; ++ot) afc[ot] = afn[ot];
    }

    // epilogue1: tmp = BN1(mish(acc)) -> sm2 [t][k] bf16 pairs
    #pragma unroll
    for (int ot = 0; ot < 3; ++ot) {
        int m = (wid*3 + ot)*16 + (kg << 2);
        f32x4 g4 = *(const f32x4*)(g1v + m);
        f32x4 bb4 = *(const f32x4*)(bb1v + m);
        f32x4 bm4 = *(const f32x4*)(bm1v + m);
        f32x4 bv4 = *(const f32x4*)(bv1v + m);
        #pragma unroll
        for (int tt = 0; tt < 2; ++tt) {
            int tl = tt*16 + l15;
            f32x4 A = acc[ot][tt];
            float vr[4];
            #pragma unroll
            for (int r = 0; r < 4; ++r) {
                float v = mishf(A[r]);
                vr[r] = (v - bm4[r]) * (g4[r] * rsqrtf(bv4[r] + 1e-5f)) + bb4[r];
            }
            *(u32x2*)(&sm2[tl*KP + (m >> 1)]) = u32x2{pk_bf16(vr[0], vr[1]), pk_bf16(vr[2], vr[3])};
        }
    }
    __syncthreads();

    // GEMM2 (bias-init acc), A-prefetch across 6 iters
    f32x4 acc2[3][2];
    #pragma unroll
    for (int ot = 0; ot < 3; ++ot) {
        f32x4 bi = *(const f32x4*)(b2v + (wid*3 + ot)*16 + (kg << 2));
        acc2[ot][0] = bi; acc2[ot][1] = bi;
    }
    const char* smb2 = (const char*)sm2;

    #pragma unroll
    for (int ot = 0; ot < 3; ++ot)
        afc[ot] = *(const bf16x8*)(w2s + ((size_t)((wid*3 + ot)*6))*512 + lane*8);

    #pragma unroll
    for (int kk = 0; kk < 6; ++kk) {
        if (kk + 1 < 6) {
            #pragma unroll
            for (int ot = 0; ot < 3; ++ot)
                afn[ot] = *(const bf16x8*)(w2s + ((size_t)((wid*3 + ot)*6 + kk + 1))*512 + lane*8);
        }
        int k0 = kk*32 + kg*8;
        bf16x8 b0  = *(const bf16x8*)(smb2 + (size_t)l15*400 + k0*2);
        bf16x8 b1f = *(const bf16x8*)(smb2 + (size_t)(l15+16)*400 + k0*2);
        #pragma unroll
        for (int ot = 0; ot < 3; ++ot) {
            acc2[ot][0] = __builtin_amdgcn_mfma_f32_16x16x32_bf16(afc[ot], b0,  acc2[ot][0], 0, 0, 0);
            acc2[ot][1] = __builtin_amdgcn_mfma_f32_16x16x32_bf16(afc[ot], b1f, acc2[ot][1], 0, 0, 0);
        }
        #pragma unroll
        for (int ot = 0; ot < 3; ++ot) afc[ot] = afn[ot];
    }

    // epilogue2: hidBout = bf16(old(sm1) + mask * BN2(mish(acc2)))
    #pragma unroll
    for (int ot = 0; ot < 3; ++ot) {
        int m = (wid*3 + ot)*16 + (kg << 2);
        f32x4 g4 = *(const f32x4*)(g2v + m);
        f32x4 bb4 = *(const f32x4*)(bb2v + m);
        f32x4 bm4 = *(const f32x4*)(bm2v + m);
        f32x4 bv4 = *(const f32x4*)(bv2v + m);
        #pragma unroll
        for (int tt = 0; tt < 2; ++tt) {
            int tl = tt*16 + l15;
            int t = tg0 + tl;
            float mv = masks[(size_t)b*NT + t];
            f32x4 A = acc2[ot][tt];
            u32x2 ow = *(const u32x2*)(&sm1[(tl + DIL)*KP + (m >> 1)]);
            float old0 = bf_lo(ow[0]), old1 = bf_hi(ow[0]);
            float old2 = bf_lo(ow[1]), old3 = bf_hi(ow[1]);
            float nv[4];
            {
                float v0 = mishf(A[0]), v1 = mishf(A[1]), v2 = mishf(A[2]), v3 = mishf(A[3]);
                nv[0] = old0 + mv * ((v0 - bm4[0]) * (g4[0] * rsqrtf(bv4[0] + 1e-5f)) + bb4[0]);
                nv[1] = old1 + mv * ((v1 - bm4[1]) * (g4[1] * rsqrtf(bv4[1] + 1e-5f)) + bb4[1]);
                nv[2] = old2 + mv * ((v2 - bm4[2]) * (g4[2] * rsqrtf(bv4[2] + 1e-5f)) + bb4[2]);
                nv[3] = old3 + mv * ((v3 - bm4[3]) * (g4[3] * rsqrtf(bv4[3] + 1e-5f)) + bb4[3]);
            }
            *(u32x2*)(hidBout + ((size_t)b*NT + t)*96 + (m >> 1)) =
                u32x2{pk_bf16(nv[0], nv[1]), pk_bf16(nv[2], nv[3])};
        }
    }
}

// ---------- fused proj GEMM (M=256/block) + RQ spline + x0-flip + lad ----------
// grid (16 t-tiles, 12 m-blocks(=8c each), 16 units(b,th)), block 256
__global__ __launch_bounds__(256) void proj_spline_mfma_kernel(
    const u32* __restrict__ hidB, const u16* __restrict__ wpad,
    const float* __restrict__ pjb_pad, const float* __restrict__ x,
    const float* __restrict__ masks, float* __restrict__ outp,
    float* __restrict__ partial)
{
    __shared__ u32 uls[64*PR];   // union: staging [64][KP] then P [64 t][258 u16]
    __shared__ float red4[4];
    const int tid  = threadIdx.x;
    const int lane = tid & 63;
    const int wid  = tid >> 6;
    const int z  = blockIdx.z;
    const int b  = z >> 1, th = z & 1;
    const int tg0 = th*1024 + blockIdx.x*64;
    const int l15 = lane & 15;
    const int kg  = lane >> 4;

    // ---- stage B tile: pre-masked bf16 from hidB, pure 16B copies ----
    for (int it = tid; it < 64*24; it += 256) {
        int row = it / 24, q = it - row*24;
        u32x4 v = *(const u32x4*)(hidB + ((size_t)b*NT + tg0 + row)*96 + q*4);
        *(u32x4*)(&uls[row*KP + q*4]) = v;
    }
    __syncthreads();

    // ---- GEMM: 256 m x 64 t x 192 k, bias-init acc ----
    f32x4 acc[4][4];   // [ot][tt]
    const int mtb = blockIdx.y*16 + wid*4;
    #pragma unroll
    for (int ot = 0; ot < 4; ++ot) {
        f32x4 pb = *(const f32x4*)(pjb_pad + blockIdx.y*256 + (wid*4 + ot)*16 + (kg << 2));
        #pragma unroll
        for (int tt = 0; tt < 4; ++tt) acc[ot][tt] = pb;
    }
    const char* smb = (const char*)uls;

    for (int kk = 0; kk < 6; ++kk) {
        int k0 = kk*32 + kg*8;
        bf16x8 bt[4];
        #pragma unroll
        for (int tt = 0; tt < 4; ++tt)
            bt[tt] = *(const bf16x8*)(smb + (size_t)(tt*16 + l15)*400 + k0*2);
        bf16x8 af[4];
        #pragma unroll
        for (int ot = 0; ot < 4; ++ot)
            af[ot] = *(const bf16x8*)(wpad + ((size_t)((mtb + ot)*6 + kk))*512 + lane*8);
        #pragma unroll
        for (int ot = 0; ot < 4; ++ot)
            #pragma unroll
            for (int tt = 0; tt < 4; ++tt)
                acc[ot][tt] = __builtin_amdgcn_mfma_f32_16x16x32_bf16(af[ot], bt[tt], acc[ot][tt], 0, 0, 0);
    }
    __syncthreads();   // staging dead; reuse LDS as P [t][m] bf16

    // ---- P[t][mloc] = bf16(acc*mask), cvt_pk + u32x2 stores ----
    #pragma unroll
    for (int tt = 0; tt < 4; ++tt) {
        int t = tt*16 + l15;
        float mkv = masks[(size_t)b*NT + tg0 + t];
        #pragma unroll
        for (int ot = 0; ot < 4; ++ot) {
            int mloc = (wid*4 + ot)*16 + (kg << 2);
            f32x4 A = acc[ot][tt];
            *(u32x2*)(&uls[t*PR + (mloc >> 1)]) =
                u32x2{pk_bf16(A[0]*mkv, A[1]*mkv), pk_bf16(A[2]*mkv, A[3]*mkv)};
        }
    }
    __syncthreads();

    // ---- spline: 8 c-channels x 64 t = 512 items, exactly 2 per thread ----
    float lsum = 0.f;
    #pragma unroll
    for (int rep = 0; rep < 2; ++rep) {
        int item = tid + rep*256;
        int cl = item >> 6, t = item & 63;
        int c  = blockIdx.y*8 + cl;
        int tg = tg0 + t;
        float m = masks[(size_t)b*NT + tg];

        // x0 flip copy
        float x0v = x[((size_t)b*NC + c)*NT + tg];
        outp[((size_t)b*NC + (NC-1 - c))*NT + tg] = x0v * m;

        float pr[30];
        #pragma unroll
        for (int j = 0; j < 15; ++j) {
            u32 w = uls[t*PR + cl*16 + j];
            pr[2*j]   = bf_lo(w);
            pr[2*j+1] = bf_hi(w);
        }

        float x1 = x[((size_t)b*NC + NHALF + c)*NT + tg];
        float xc = fminf(fmaxf(x1, -5.f), 5.f);

        // exp2 constant-fold: exp(pr*invsq) = exp2(pr * invsq*log2e)
        const float C = 0.10412020934368074f;  // (1/sqrt(192)) * log2(e)
        float ew[10], eh[10], sw = 0.f, sh = 0.f;
        #pragma unroll
        for (int i = 0; i < 10; ++i) { ew[i] = __builtin_amdgcn_exp2f(pr[i]    * C); sw += ew[i]; }
        #pragma unroll
        for (int i = 0; i < 10; ++i) { eh[i] = __builtin_amdgcn_exp2f(pr[10+i] * C); sh += eh[i]; }
        float isw = __builtin_amdgcn_rcpf(sw) * 9.9f;   // step = 0.01 + 9.9*e*inv_s
        float ish = __builtin_amdgcn_rcpf(sh) * 9.9f;

        // fused cumsum + knot selection (forced endpoints preserved)
        float cwp = -5.f, chp = -5.f;
        float icw = -5.f, ich = -5.f, iw = 0.f, ih = 0.f;
        float s0 = 0.f, s1 = pr[20], f0 = 1.f, f9 = 0.f;
        #pragma unroll
        for (int i = 0; i < 10; ++i) {
            float stepw = 0.01f + ew[i]*isw;
            float steph = 0.01f + eh[i]*ish;
            if (i == 9) { stepw = 5.f - cwp; steph = 5.f - chp; }  // forced cw[10]=5
            if (i == 0) {
                iw = stepw; ih = steph;
            } else {
                bool ge = (xc >= cwp);
                icw = ge ? cwp   : icw;
                iw  = ge ? stepw : iw;
                ich = ge ? chp   : ich;
                ih  = ge ? steph : ih;
                s0  = ge ? pr[19+i] : s0;
                if (i <= 8) s1 = ge ? pr[20+i] : s1;
                f0  = ge ? 0.f : f0;
                if (i == 9) f9 = ge ? 1.f : 0.f;
            }
            cwp += stepw; chp += steph;
        }
        float d0 = (f0 != 0.f) ? 1.f : 0.001f + softplus_fast(s0);
        float d1 = (f9 != 0.f) ? 1.f : 0.001f + softplus_fast(s1);

        float rw    = __builtin_amdgcn_rcpf(iw);
        float dlt   = ih * rw;
        float theta = (xc - icw) * rw;
        float t1m   = theta * (1.f - theta);
        float den   = dlt + (d0 + d1 - 2.f*dlt) * t1m;
        float rden  = __builtin_amdgcn_rcpf(den);
        float num   = ih * (dlt*theta*theta + d0*t1m);
        float outv  = ich + num * rden;
        float omt   = 1.f - theta;
        float dnum  = dlt*dlt*(d1*theta*theta + 2.f*dlt*t1m + d0*omt*omt);
        float lad   = __logf(dnum * rden * rden);
        bool inside = (x1 >= -5.f) && (x1 <= 5.f);
        float xout  = inside ? outv : x1;
        float ladv  = inside ? lad : 0.f;
        outp[((size_t)b*NC + (NHALF-1 - c))*NT + tg] = xout * m;
        lsum += ladv * m;
    }

    // ---- wave-shuffle reduction, then 4-way cross-wave sum ----
    #pragma unroll
    for (int off = 32; off > 0; off >>= 1)
        lsum += __shfl_down(lsum, off, 64);
    if (lane == 0) red4[wid] = lsum;
    __syncthreads();
    if (tid == 0)
        partial[(size_t)b*384 + th*192 + blockIdx.y*16 + blockIdx.x] =
            red4[0] + red4[1] + red4[2] + red4[3];
}

__global__ __launch_bounds__(256) void logdet_reduce_kernel(
    const float* __restrict__ partial, float* __restrict__ outp)
{
    __shared__ float red[256];
    const int b = blockIdx.x;
    const int tid = threadIdx.x;
    float s = 0.f;
    for (int i = tid; i < 384; i += 256) s += partial[(size_t)b*384 + i];
    red[tid] = s;
    __syncthreads();
    for (int st = 128; st > 0; st >>= 1) {
        if (tid < st) red[tid] += red[tid + st];
        __syncthreads();
    }
    if (tid == 0) outp[(size_t)OUT_ELEMS + b] = red[0];
}

extern "C" void kernel_launch(void* const* d_in, const int* in_sizes, int n_in,
                              void* d_out, int out_size, void* d_ws, size_t ws_size,
                              hipStream_t stream) {
    const float* x     = (const float*)d_in[0];
    const float* cond  = (const float*)d_in[1];
    const float* masks = (const float*)d_in[2];
    const float* pw    = (const float*)d_in[3];
    const float* pb    = (const float*)d_in[4];
    const float* w1    = (const float*)d_in[5];
    const float* b1    = (const float*)d_in[6];
    const float* g1    = (const float*)d_in[7];
    const float* bb1   = (const float*)d_in[8];
    const float* m1    = (const float*)d_in[9];
    const float* v1    = (const float*)d_in[10];
    const float* w2    = (const float*)d_in[11];
    const float* b2    = (const float*)d_in[12];
    const float* g2    = (const float*)d_in[13];
    const float* bb2   = (const float*)d_in[14];
    const float* m2    = (const float*)d_in[15];
    const float* v2    = (const float*)d_in[16];
    const float* pjw   = (const float*)d_in[17];
    const float* pjb   = (const float*)d_in[18];

    float* out = (float*)d_out;
    char* wsb = (char*)d_ws;
    u32*   hidB0   = (u32*)wsb;                                    //  6,291,456 B
    u32*   hidB1   = (u32*)(wsb + 6291456);                        //  6,291,456 B
    u16*   wbf     = (u16*)(wsb + 12582912);                       //  2,101,248 B
    float* pjb_pad = (float*)(wsb + 12582912 + 2101248);           //     12,288 B
    float* partial = (float*)(wsb + 12582912 + 2101248 + 12288);   //     16,384 B

    dim3 blk(256);

    wconv_kernel<<<dim3((WT2 + 3072 + 255)/256), blk, 0, stream>>>(
        w1, w2, pjw, pjb, pw, wbf, pjb_pad);

    const u16* preswz = wbf + W1N + W2N + PADN;
    prenet_mfma_kernel<<<dim3(64,1,8), blk, 0, stream>>>(
        x, cond, preswz, pb, masks, hidB0);

    dim3 grid_r(64, 1, 8);
    {
        resblock_kernel<1><<<grid_r, blk, 0, stream>>>(hidB0, hidB1, wbf, wbf + W1N, masks,
            b1, g1, bb1, m1, v1, b2, g2, bb2, m2, v2);
    }
    {
        const u16* w1l = wbf + (size_t)1*110592;
        const u16* w2l = wbf + W1N + (size_t)1*36864;
        resblock_kernel<3><<<grid_r, blk, 0, stream>>>(hidB1, hidB0, w1l, w2l, masks,
            b1+NC, g1+NC, bb1+NC, m1+NC, v1+NC, b2+NC, g2+NC, bb2+NC, m2+NC, v2+NC);
    }
    {
        const u16* w1l = wbf + (size_t)2*110592;
        const u16* w2l = wbf + W1N + (size_t)2*36864;
        resblock_kernel<9><<<grid_r, blk, 0, stream>>>(hidB0, hidB1, w1l, w2l, masks,
            b1+2*NC, g1+2*NC, bb1+2*NC, m1+2*NC, v1+2*NC,
            b2+2*NC, g2+2*NC, bb2+2*NC, m2+2*NC, v2+2*NC);
    }

    const u16* pjwpad = wbf + W1N + W2N;
    proj_spline_mfma_kernel<<<dim3(16,12,16), blk, 0, stream>>>(
        hidB1, pjwpad, pjb_pad, x, masks, out, partial);

    logdet_reduce_kernel<<<dim3(8), blk, 0, stream>>>(partial, out);
}